// Round 4
// baseline (4523.730 us; speedup 1.0000x reference)
//
#include <hip/hip_runtime.h>

// Problem constants
#define NPTS 8192
#define NB   32
#define NG   256
#define NK   32
#define ND   384
#define NH   6
#define NLK  64
#define NF   1536
#define NHD  64
#define NL   12
#define MM   2048   // NB*NLK token rows

typedef unsigned short u16;

__device__ __forceinline__ float bf2f(u16 v){
  unsigned int u = ((unsigned int)v) << 16;
  float f; __builtin_memcpy(&f, &u, 4); return f;
}
// runtime-dtype input load: bf=true -> bf16 u16, else f32
__device__ __forceinline__ float ldf(const void* p, size_t i, bool bf){
  if(bf) return bf2f(((const u16*)p)[i]);
  return ((const float*)p)[i];
}
// f32 -> bf16 RNE
__device__ __forceinline__ u16 f2bf(float f){
  unsigned int x; __builtin_memcpy(&x, &f, 4);
  x += 0x7fffu + ((x >> 16) & 1u);
  return (u16)(x >> 16);
}

// ---------------------------------------------------------------- dtype detect
// bf16-encoded N(0,1) data: every u16 exponent field < 0x90 (|v| < 2^17).
// f32 data: even u16s are mantissa low-halves, uniform -> ~44% have field >= 0x90.
__global__ __launch_bounds__(256) void k_detect(const u16* __restrict__ pts,
                                                int* __restrict__ flag){
  __shared__ int bad;
  if(threadIdx.x==0) bad=0;
  __syncthreads();
  int hit=0;
  for(int i=threadIdx.x; i<4096; i+=256){
    unsigned e = (pts[i] >> 7) & 0xFFu;
    if(e >= 0x90u) hit=1;
  }
  if(hit) atomicOr(&bad, 1);
  __syncthreads();
  if(threadIdx.x==0) *flag = bad ? 0 : 1;   // 1 = bf16, 0 = f32
}

// ---------------------------------------------------------------- normalize
__device__ __forceinline__ float blockMax256(float v, float* sb, int tid){
  for(int off=32; off; off>>=1) v = fmaxf(v, __shfl_down(v, off));
  __syncthreads();
  if((tid&63)==0) sb[tid>>6] = v;
  __syncthreads();
  return fmaxf(fmaxf(sb[0],sb[1]), fmaxf(sb[2],sb[3]));
}

__global__ __launch_bounds__(256) void k_normalize(const void* __restrict__ pts,
                                                   float* __restrict__ xn,
                                                   const int* __restrict__ flag){
#pragma clang fp contract(off)
  int b = blockIdx.x, tid = threadIdx.x;
  const bool bf = flag[0] != 0;
  __shared__ float sb[4];
  const size_t base = (size_t)b*NPTS*3;
  float mn0=1e30f,mn1=1e30f,mn2=1e30f, mx0=-1e30f,mx1=-1e30f,mx2=-1e30f;
  for(int n=tid; n<NPTS; n+=256){
    float x0=ldf(pts,base+n*3,bf), x1=ldf(pts,base+n*3+1,bf), x2=ldf(pts,base+n*3+2,bf);
    mn0=fminf(mn0,x0); mx0=fmaxf(mx0,x0);
    mn1=fminf(mn1,x1); mx1=fmaxf(mx1,x1);
    mn2=fminf(mn2,x2); mx2=fmaxf(mx2,x2);
  }
  mx0=blockMax256(mx0,sb,tid); mn0=-blockMax256(-mn0,sb,tid);
  mx1=blockMax256(mx1,sb,tid); mn1=-blockMax256(-mn1,sb,tid);
  mx2=blockMax256(mx2,sb,tid); mn2=-blockMax256(-mn2,sb,tid);
  float c0=0.5f*(mn0+mx0), c1=0.5f*(mn1+mx1), c2=0.5f*(mn2+mx2);
  float mr=0.0f;
  for(int n=tid; n<NPTS; n+=256){
    float d0=ldf(pts,base+n*3,bf)-c0, d1=ldf(pts,base+n*3+1,bf)-c1, d2=ldf(pts,base+n*3+2,bf)-c2;
    float nr = sqrtf((d0*d0 + d1*d1) + d2*d2);
    mr = fmaxf(mr, nr);
  }
  float radius = blockMax256(mr, sb, tid);
  float* XO = xn + base;
  for(int n=tid; n<NPTS; n+=256){
    XO[n*3  ] = (ldf(pts,base+n*3  ,bf)-c0)/radius;
    XO[n*3+1] = (ldf(pts,base+n*3+1,bf)-c1)/radius;
    XO[n*3+2] = (ldf(pts,base+n*3+2,bf)-c2)/radius;
  }
}

// ---------------------------------------------------------------- keep (stable rank of noise, first 64)
__global__ __launch_bounds__(256) void k_keep(const void* __restrict__ noise,
                                              int* __restrict__ keep,
                                              const int* __restrict__ flag){
  int b = blockIdx.x, g = threadIdx.x;
  const bool bf = flag[0] != 0;
  __shared__ float nv[NG];
  nv[g] = ldf(noise, (size_t)b*NG+g, bf);
  __syncthreads();
  float v = nv[g]; int r = 0;
  for(int j=0; j<NG; j++){
    float u = nv[j];
    r += (u < v) || (u == v && j < g);
  }
  if(r < NLK) keep[b*NLK + r] = g;
}

// ---------------------------------------------------------------- FPS (512 thr, 16 pts/thr)
__global__ __launch_bounds__(512) void k_fps(const float* __restrict__ xn,
                                             float* __restrict__ centers){
#pragma clang fp contract(off)
  int b = blockIdx.x, tid = threadIdx.x;
  const float* X = xn + (size_t)b*NPTS*3;
  float px[16],py[16],pz[16],dd[16];
  for(int s=0;s<16;s++){
    int n = s*512 + tid;
    px[s]=X[n*3]; py[s]=X[n*3+1]; pz[s]=X[n*3+2];
    dd[s]=1e10f;
  }
  __shared__ float sv[8]; __shared__ int sn[8];
  __shared__ int ssel; __shared__ int sc[NG];
  if(tid==0) sc[0]=0;
  int last = 0;
  for(int i=1;i<NG;i++){
    float lx=X[last*3], ly=X[last*3+1], lz=X[last*3+2];
    float bv=-1.0f; int bn=0x7fffffff;
    for(int s=0;s<16;s++){
      float dx=px[s]-lx, dy=py[s]-ly, dz=pz[s]-lz;
      float d=(dx*dx + dy*dy) + dz*dz;
      d = fminf(dd[s], d); dd[s]=d;
      if(d > bv){ bv=d; bn=s*512+tid; }   // strict >: argmax keeps first index
    }
    for(int off=32;off;off>>=1){
      float ov=__shfl_down(bv,off); int on=__shfl_down(bn,off);
      if(ov>bv || (ov==bv && on<bn)){ bv=ov; bn=on; }
    }
    if((tid&63)==0){ sv[tid>>6]=bv; sn[tid>>6]=bn; }
    __syncthreads();
    if(tid==0){
      float v=sv[0]; int n=sn[0];
      for(int w=1;w<8;w++) if(sv[w]>v || (sv[w]==v && sn[w]<n)){ v=sv[w]; n=sn[w]; }
      n &= (NPTS-1);
      ssel=n; sc[i]=n;
    }
    __syncthreads();
    last = ssel;
  }
  if(tid < NG){
    int n = sc[tid] & (NPTS-1);
    centers[((size_t)b*NG+tid)*3  ] = X[n*3];
    centers[((size_t)b*NG+tid)*3+1] = X[n*3+1];
    centers[((size_t)b*NG+tid)*3+2] = X[n*3+2];
  }
}

// ---------------------------------------------------------------- group (kNN top-32) + patch embed + pos embed
__global__ __launch_bounds__(256) void k_group_embed(
    const float* __restrict__ xn, const float* __restrict__ centers,
    const int* __restrict__ keep,
    const void* __restrict__ w1, const void* __restrict__ b1,
    const void* __restrict__ w2, const void* __restrict__ b2,
    const void* __restrict__ w3, const void* __restrict__ b3,
    const void* __restrict__ pw1, const void* __restrict__ pb1,
    const void* __restrict__ pw2, const void* __restrict__ pb2,
    float* __restrict__ h0, const int* __restrict__ flag)
{
  int blk=blockIdx.x; int b=blk>>6; int j=blk&63; int tid=threadIdx.x;
  const bool bf = flag[0] != 0;
  __shared__ float sd[NPTS];        // d2, later f2 (32x256)
  __shared__ float f1s[NK*128];
  __shared__ float patch[NK][3];
  __shared__ int   sel[NK];
  __shared__ float rv[4]; __shared__ int rn[4];
  __shared__ int   sseln;
  __shared__ float maxf[256];
  __shared__ float ph[128];

  int g = keep[b*NLK + j] & (NG-1);
  const float* C = centers + ((size_t)b*NG + g)*3;
  float c0=C[0], c1=C[1], c2=C[2];
  const float* X = xn + (size_t)b*NPTS*3;
  {
#pragma clang fp contract(off)
    float cc = (c0*c0 + c1*c1) + c2*c2;
    for(int n=tid; n<NPTS; n+=256){
      float x0=X[n*3], x1=X[n*3+1], x2=X[n*3+2];
      float xx=(x0*x0 + x1*x1) + x2*x2;
      float dt=(c0*x0 + c1*x1) + c2*x2;
      sd[n] = (cc + xx) - 2.0f*dt;
    }
  }
  __syncthreads();
  float dl[32];
  for(int s=0;s<32;s++) dl[s] = sd[s*256 + tid];
  unsigned int alive = 0xffffffffu;
  for(int r=0; r<NK; r++){
    float bv=1e30f; int bn=0x7fffffff;
    for(int s=0;s<32;s++){
      if(alive & (1u<<s)){
        float v = dl[s];
        if(v < bv){ bv=v; bn=s*256+tid; }   // strict <: lowest index on tie
      }
    }
    for(int off=32;off;off>>=1){
      float ov=__shfl_down(bv,off); int on=__shfl_down(bn,off);
      if(ov<bv || (ov==bv && on<bn)){ bv=ov; bn=on; }
    }
    if((tid&63)==0){ rv[tid>>6]=bv; rn[tid>>6]=bn; }
    __syncthreads();
    if(tid==0){
      float v=rv[0]; int n=rn[0];
      for(int w=1;w<4;w++) if(rv[w]<v || (rv[w]==v && rn[w]<n)){ v=rv[w]; n=rn[w]; }
      n &= (NPTS-1);
      sseln=n; sel[r]=n;
    }
    __syncthreads();
    int n = sseln;
    if((n & 255) == tid) alive &= ~(1u << (n >> 8));
  }
  __syncthreads();
  if(tid < NK){
    int n = sel[tid] & (NPTS-1);
    patch[tid][0]=X[n*3  ]-c0;
    patch[tid][1]=X[n*3+1]-c1;
    patch[tid][2]=X[n*3+2]-c2;
  }
  __syncthreads();
  // f1 = relu(patch @ W1 + b1)   (32 x 128)
  for(int idx=tid; idx<NK*128; idx+=256){
    int k=idx>>7, m=idx&127;
    float v = ldf(b1,m,bf)
            + patch[k][0]*ldf(w1,        m,bf)
            + patch[k][1]*ldf(w1, 128 + m,bf)
            + patch[k][2]*ldf(w1, 256 + m,bf);
    f1s[idx] = fmaxf(v, 0.0f);
  }
  __syncthreads();
  // f2 = f1 @ W2 + b2   (32 x 256) -> sd
  {
    int m = tid;
    for(int k=0;k<NK;k++){
      float acc = ldf(b2, m, bf);
      const float* f1r = &f1s[k*128];
      for(int jj=0;jj<128;jj++) acc = fmaf(f1r[jj], ldf(w2, (size_t)jj*256+m, bf), acc);
      sd[k*256+m] = acc;
    }
  }
  __syncthreads();
  // maxpool over K
  {
    float mx = sd[tid];
    for(int k=1;k<NK;k++) mx = fmaxf(mx, sd[k*256+tid]);
    maxf[tid] = mx;
  }
  // pos hidden
  if(tid < 128){
    float v = ldf(pb1,tid,bf)
            + c0*ldf(pw1,        tid,bf)
            + c1*ldf(pw1, 128 + tid,bf)
            + c2*ldf(pw1, 256 + tid,bf);
    ph[tid] = fmaxf(v, 0.0f);
  }
  __syncthreads();
  // token = maxf @ W3 + b3 ; pos = ph @ PW2 + pb2 ; h0 = token + pos
  float* HO = h0 + ((size_t)b*NLK + j)*ND;
  for(int d=tid; d<ND; d+=256){
    float acc = ldf(b3, d, bf);
    for(int m=0;m<256;m++) acc = fmaf(maxf[m], ldf(w3, (size_t)m*ND+d, bf), acc);
    float acc2 = ldf(pb2, d, bf);
    for(int m=0;m<128;m++) acc2 = fmaf(ph[m], ldf(pw2, (size_t)m*ND+d, bf), acc2);
    HO[d] = acc + acc2;
  }
}

// ---------------------------------------------------------------- LayerNorm (gb sliced by element offset go)
template<bool FINAL>
__global__ __launch_bounds__(128) void k_ln(const float* __restrict__ X,
                                            const void* __restrict__ gb, size_t go,
                                            void* __restrict__ Y,
                                            const int* __restrict__ flag){
  int row=blockIdx.x, tid=threadIdx.x;
  const bool bf = flag[0] != 0;
  const float* x = X + (size_t)row*ND;
  __shared__ float sbuf[2];
  float v0=x[tid], v1=x[tid+128], v2=x[tid+256];
  float s = v0+v1+v2;
  for(int off=32;off;off>>=1) s += __shfl_down(s,off);
  if((tid&63)==0) sbuf[tid>>6]=s;
  __syncthreads();
  float mean = (sbuf[0]+sbuf[1]) * (1.0f/(float)ND);
  __syncthreads();
  float d0=v0-mean, d1=v1-mean, d2=v2-mean;
  s = d0*d0 + d1*d1 + d2*d2;
  for(int off=32;off;off>>=1) s += __shfl_down(s,off);
  if((tid&63)==0) sbuf[tid>>6]=s;
  __syncthreads();
  float var = (sbuf[0]+sbuf[1]) * (1.0f/(float)ND);
  float rstd = 1.0f / sqrtf(var + 1e-5f);
  float o0 = d0*rstd*ldf(gb,go+tid    ,bf) + ldf(gb,go+ND+tid    ,bf);
  float o1 = d1*rstd*ldf(gb,go+tid+128,bf) + ldf(gb,go+ND+tid+128,bf);
  float o2 = d2*rstd*ldf(gb,go+tid+256,bf) + ldf(gb,go+ND+tid+256,bf);
  if(FINAL && bf){
    u16* yo = (u16*)Y + (size_t)row*ND;
    yo[tid]=f2bf(o0); yo[tid+128]=f2bf(o1); yo[tid+256]=f2bf(o2);
  }else{
    float* yo = (float*)Y + (size_t)row*ND;
    yo[tid]=o0; yo[tid+128]=o1; yo[tid+256]=o2;
  }
}

// ---------------------------------------------------------------- GEMM: C = act(A @ W + bias) [+ res]
// A: f32 MxK; W: input-dtype KxN row-major sliced at element offset wo_; bias at bo_.
template<int ACT, bool RES>
__global__ __launch_bounds__(256) void k_gemm(const float* __restrict__ A,
    const void* __restrict__ W, size_t wo_, const void* __restrict__ bias, size_t bo_,
    const float* __restrict__ res, float* __restrict__ C,
    int M, int N, int K, const int* __restrict__ flag){
  __shared__ float As[16*68];
  __shared__ float Ws[16*64];
  int tid=threadIdx.x;
  const bool bf = flag[0] != 0;
  int bx=blockIdx.x, by=blockIdx.y;
  int tx=tid&15, ty=tid>>4;
  int ar = tid>>2, ak = (tid&3)*4;   // A-tile loader: row, k-start
  int wk = tid>>4, wn = (tid&15)*4;  // W-tile loader
  const float* Arow = A + (size_t)(by*64 + ar)*K;
  float acc[4][4] = {};
  for(int k0=0; k0<K; k0+=16){
    float4 av = *reinterpret_cast<const float4*>(Arow + k0 + ak);
    float4 wf;
    size_t we = wo_ + (size_t)(k0+wk)*N + bx*64 + wn;
    if(bf){
      ushort4 wv = *reinterpret_cast<const ushort4*>((const u16*)W + we);
      wf.x=bf2f(wv.x); wf.y=bf2f(wv.y); wf.z=bf2f(wv.z); wf.w=bf2f(wv.w);
    }else{
      wf = *reinterpret_cast<const float4*>((const float*)W + we);
    }
    __syncthreads();
    As[(ak+0)*68+ar]=av.x; As[(ak+1)*68+ar]=av.y;
    As[(ak+2)*68+ar]=av.z; As[(ak+3)*68+ar]=av.w;
    *reinterpret_cast<float4*>(&Ws[wk*64+wn]) = wf;
    __syncthreads();
#pragma unroll
    for(int k=0;k<16;k++){
      float4 a = *reinterpret_cast<const float4*>(&As[k*68 + ty*4]);
      float4 bb = *reinterpret_cast<const float4*>(&Ws[k*64 + tx*4]);
      acc[0][0]=fmaf(a.x,bb.x,acc[0][0]); acc[0][1]=fmaf(a.x,bb.y,acc[0][1]);
      acc[0][2]=fmaf(a.x,bb.z,acc[0][2]); acc[0][3]=fmaf(a.x,bb.w,acc[0][3]);
      acc[1][0]=fmaf(a.y,bb.x,acc[1][0]); acc[1][1]=fmaf(a.y,bb.y,acc[1][1]);
      acc[1][2]=fmaf(a.y,bb.z,acc[1][2]); acc[1][3]=fmaf(a.y,bb.w,acc[1][3]);
      acc[2][0]=fmaf(a.z,bb.x,acc[2][0]); acc[2][1]=fmaf(a.z,bb.y,acc[2][1]);
      acc[2][2]=fmaf(a.z,bb.z,acc[2][2]); acc[2][3]=fmaf(a.z,bb.w,acc[2][3]);
      acc[3][0]=fmaf(a.w,bb.x,acc[3][0]); acc[3][1]=fmaf(a.w,bb.y,acc[3][1]);
      acc[3][2]=fmaf(a.w,bb.z,acc[3][2]); acc[3][3]=fmaf(a.w,bb.w,acc[3][3]);
    }
  }
  int row0 = by*64, col0 = bx*64;
  for(int i=0;i<4;i++){
    int r = row0 + ty*4 + i;
    float4 o;
    float* op = &o.x;
    for(int jj=0;jj<4;jj++){
      int cn = col0 + tx*4 + jj;
      float v = acc[i][jj] + ldf(bias, bo_+cn, bf);
      if(ACT==1){
        float xx = v;
        v = 0.5f*xx*(1.0f + tanhf(0.7978845608028654f*(xx + 0.044715f*xx*xx*xx)));
      }
      if(RES) v += res[(size_t)r*N + cn];
      op[jj] = v;
    }
    *reinterpret_cast<float4*>(&C[(size_t)r*N + col0 + tx*4]) = o;
  }
}

// ---------------------------------------------------------------- attention (per b,h; S=64, HD=64)
__global__ __launch_bounds__(256) void k_attn(const float* __restrict__ qkv,
                                              float* __restrict__ out){
  __shared__ float Q[64*65];   // reused for scores after QK^T
  __shared__ float Kb[64*65];
  __shared__ float V[64*65];
  int blk=blockIdx.x; int b=blk/NH, h=blk%NH;
  int tid=threadIdx.x;
  for(int idx=tid; idx<4096; idx+=256){
    int s=idx>>6, d=idx&63;
    const float* r = qkv + ((size_t)(b*NLK+s))*1152 + h*NHD + d;
    Q [s*65+d]=r[0];
    Kb[s*65+d]=r[384];
    V [s*65+d]=r[768];
  }
  __syncthreads();
  float sc[16];
  for(int t=0;t<16;t++){
    int idx=t*256+tid; int i=idx>>6, jj=idx&63;
    float acc=0.0f;
    for(int d=0;d<64;d++) acc = fmaf(Q[i*65+d], Kb[jj*65+d], acc);
    sc[t]=acc*0.125f;
  }
  __syncthreads();
  for(int t=0;t<16;t++){
    int idx=t*256+tid; int i=idx>>6, jj=idx&63;
    Q[i*65+jj]=sc[t];
  }
  __syncthreads();
  if(tid<64){
    float* rowp=&Q[tid*65];
    float m=rowp[0];
    for(int j=1;j<64;j++) m=fmaxf(m,rowp[j]);
    float sum=0.0f;
    for(int j=0;j<64;j++){ float e=__expf(rowp[j]-m); rowp[j]=e; sum+=e; }
    for(int j=0;j<64;j++) rowp[j]/=sum;
  }
  __syncthreads();
  for(int idx=tid; idx<4096; idx+=256){
    int s=idx>>6, d=idx&63;
    float acc=0.0f;
    for(int t=0;t<64;t++) acc=fmaf(Q[s*65+t], V[t*65+d], acc);
    out[((size_t)(b*NLK+s))*ND + h*NHD + d]=acc;
  }
}

// ---------------------------------------------------------------- host
extern "C" void kernel_launch(void* const* d_in, const int* in_sizes, int n_in,
                              void* d_out, int out_size, void* d_ws, size_t ws_size,
                              hipStream_t stream){
  (void)in_sizes; (void)n_in; (void)out_size;
  const void* pts   = d_in[0];
  const void* noise = d_in[1];
  const void* pe_w1 = d_in[2];
  const void* pe_b1 = d_in[3];
  const void* pe_w2 = d_in[4];
  const void* pe_b2 = d_in[5];
  const void* pe_w3 = d_in[6];
  const void* pe_b3 = d_in[7];
  const void* pos_w1= d_in[8];
  const void* pos_b1= d_in[9];
  const void* pos_w2= d_in[10];
  const void* pos_b2= d_in[11];
  const void* ln1   = d_in[12];
  const void* wqkv  = d_in[13];
  const void* bqkv  = d_in[14];
  const void* wo    = d_in[15];
  const void* bo    = d_in[16];
  const void* ln2   = d_in[17];
  const void* wi    = d_in[18];
  const void* bi    = d_in[19];
  const void* wo2   = d_in[20];
  const void* bo2   = d_in[21];
  const void* lnf   = d_in[22];

  // ws layout (floats): h | y | big(qkvb+attb / ub / pre-loop xn+centers+keep) | flag
  const size_t needed = ((size_t)786432*2 + 3145728 + 16) * 4;
  if (ws_size < needed) return;   // diagnostic: clean absmax-3.70 fail instead of fault

  float* ws   = (float*)d_ws;
  float* h    = ws;
  float* y    = h + 786432;
  float* big  = y + 786432;
  float* qkvb = big;                       // 2359296
  float* attb = big + 2359296;             // 786432
  float* ub   = big;                       // 3145728 spans qkvb+attb
  float* xn      = big;                    // pre-loop
  float* centers = big + 786432;           // pre-loop
  int*   keep    = (int*)(centers + (size_t)NB*NG*3);  // pre-loop
  int*   flag    = (int*)(big + 3145728);

  k_detect   <<<1, 256, 0, stream>>>((const u16*)pts, flag);
  k_normalize<<<NB, 256, 0, stream>>>(pts, xn, flag);
  k_keep     <<<NB, 256, 0, stream>>>(noise, keep, flag);
  k_fps      <<<NB, 512, 0, stream>>>(xn, centers);
  k_group_embed<<<NB*NLK, 256, 0, stream>>>(xn, centers, keep,
      pe_w1, pe_b1, pe_w2, pe_b2, pe_w3, pe_b3,
      pos_w1, pos_b1, pos_w2, pos_b2, h, flag);

  for(int l=0; l<NL; l++){
    const size_t o_ln  = (size_t)l*2*ND;
    const size_t o_wq  = (size_t)l*ND*3*ND;
    const size_t o_bq  = (size_t)l*3*ND;
    const size_t o_wo  = (size_t)l*ND*ND;
    const size_t o_bo  = (size_t)l*ND;
    const size_t o_wi  = (size_t)l*ND*NF;
    const size_t o_bi  = (size_t)l*NF;
    const size_t o_wo2 = (size_t)l*NF*ND;
    const size_t o_bo2 = (size_t)l*ND;

    k_ln<false><<<MM, 128, 0, stream>>>(h, ln1, o_ln, (void*)y, flag);
    k_gemm<0,false><<<dim3(3*ND/64, MM/64), 256, 0, stream>>>(y, wqkv, o_wq, bqkv, o_bq, nullptr, qkvb, MM, 3*ND, ND, flag);
    k_attn<<<NB*NH, 256, 0, stream>>>(qkvb, attb);
    k_gemm<0,true ><<<dim3(ND/64, MM/64), 256, 0, stream>>>(attb, wo, o_wo, bo, o_bo, h, h, MM, ND, ND, flag);
    k_ln<false><<<MM, 128, 0, stream>>>(h, ln2, o_ln, (void*)y, flag);
    k_gemm<1,false><<<dim3(NF/64, MM/64), 256, 0, stream>>>(y, wi, o_wi, bi, o_bi, nullptr, ub, MM, NF, ND, flag);
    k_gemm<0,true ><<<dim3(ND/64, MM/64), 256, 0, stream>>>(ub, wo2, o_wo2, bo2, o_bo2, h, h, MM, ND, NF, flag);
  }
  k_ln<true><<<MM, 128, 0, stream>>>(h, lnf, 0, d_out, flag);
}

// Round 5
// 2523.632 us; speedup vs baseline: 1.7925x; 1.7925x over previous
//
#include <hip/hip_runtime.h>

// Problem constants
#define NPTS 8192
#define NB   32
#define NG   256
#define NK   32
#define ND   384
#define NH   6
#define NLK  64
#define NF   1536
#define NHD  64
#define NL   12
#define MM   2048   // NB*NLK token rows

typedef unsigned short u16;
typedef __attribute__((ext_vector_type(8))) short short8;   // bf16x8 MFMA frag
typedef __attribute__((ext_vector_type(4))) float f32x4;    // MFMA acc

__device__ __forceinline__ float bf2f(u16 v){
  unsigned int u = ((unsigned int)v) << 16;
  float f; __builtin_memcpy(&f, &u, 4); return f;
}
__device__ __forceinline__ float ldf(const void* p, size_t i, bool bf){
  if(bf) return bf2f(((const u16*)p)[i]);
  return ((const float*)p)[i];
}
__device__ __forceinline__ u16 f2bf(float f){
  unsigned int x; __builtin_memcpy(&x, &f, 4);
  x += 0x7fffu + ((x >> 16) & 1u);
  return (u16)(x >> 16);
}
// split f32 -> (hi, lo) bf16 planes; hi RNE, lo = RNE(residual)
__device__ __forceinline__ void split2(float v, u16& hi, u16& lo){
  hi = f2bf(v);
  lo = f2bf(v - bf2f(hi));
}

// ---------------------------------------------------------------- dtype detect
__global__ __launch_bounds__(256) void k_detect(const u16* __restrict__ pts,
                                                int* __restrict__ flag){
  __shared__ int bad;
  if(threadIdx.x==0) bad=0;
  __syncthreads();
  int hit=0;
  for(int i=threadIdx.x; i<4096; i+=256){
    unsigned e = (pts[i] >> 7) & 0xFFu;
    if(e >= 0x90u) hit=1;
  }
  if(hit) atomicOr(&bad, 1);
  __syncthreads();
  if(threadIdx.x==0) *flag = bad ? 0 : 1;   // 1 = bf16, 0 = f32
}

// ---------------------------------------------------------------- normalize
__device__ __forceinline__ float blockMax256(float v, float* sb, int tid){
  for(int off=32; off; off>>=1) v = fmaxf(v, __shfl_down(v, off));
  __syncthreads();
  if((tid&63)==0) sb[tid>>6] = v;
  __syncthreads();
  return fmaxf(fmaxf(sb[0],sb[1]), fmaxf(sb[2],sb[3]));
}

__global__ __launch_bounds__(256) void k_normalize(const void* __restrict__ pts,
                                                   float* __restrict__ xn,
                                                   const int* __restrict__ flag){
#pragma clang fp contract(off)
  int b = blockIdx.x, tid = threadIdx.x;
  const bool bf = flag[0] != 0;
  __shared__ float sb[4];
  const size_t base = (size_t)b*NPTS*3;
  float mn0=1e30f,mn1=1e30f,mn2=1e30f, mx0=-1e30f,mx1=-1e30f,mx2=-1e30f;
  for(int n=tid; n<NPTS; n+=256){
    float x0=ldf(pts,base+n*3,bf), x1=ldf(pts,base+n*3+1,bf), x2=ldf(pts,base+n*3+2,bf);
    mn0=fminf(mn0,x0); mx0=fmaxf(mx0,x0);
    mn1=fminf(mn1,x1); mx1=fmaxf(mx1,x1);
    mn2=fminf(mn2,x2); mx2=fmaxf(mx2,x2);
  }
  mx0=blockMax256(mx0,sb,tid); mn0=-blockMax256(-mn0,sb,tid);
  mx1=blockMax256(mx1,sb,tid); mn1=-blockMax256(-mn1,sb,tid);
  mx2=blockMax256(mx2,sb,tid); mn2=-blockMax256(-mn2,sb,tid);
  float c0=0.5f*(mn0+mx0), c1=0.5f*(mn1+mx1), c2=0.5f*(mn2+mx2);
  float mr=0.0f;
  for(int n=tid; n<NPTS; n+=256){
    float d0=ldf(pts,base+n*3,bf)-c0, d1=ldf(pts,base+n*3+1,bf)-c1, d2=ldf(pts,base+n*3+2,bf)-c2;
    float nr = sqrtf((d0*d0 + d1*d1) + d2*d2);
    mr = fmaxf(mr, nr);
  }
  float radius = blockMax256(mr, sb, tid);
  float* XO = xn + base;
  for(int n=tid; n<NPTS; n+=256){
    XO[n*3  ] = (ldf(pts,base+n*3  ,bf)-c0)/radius;
    XO[n*3+1] = (ldf(pts,base+n*3+1,bf)-c1)/radius;
    XO[n*3+2] = (ldf(pts,base+n*3+2,bf)-c2)/radius;
  }
}

// ---------------------------------------------------------------- keep
__global__ __launch_bounds__(256) void k_keep(const void* __restrict__ noise,
                                              int* __restrict__ keep,
                                              const int* __restrict__ flag){
  int b = blockIdx.x, g = threadIdx.x;
  const bool bf = flag[0] != 0;
  __shared__ float nv[NG];
  nv[g] = ldf(noise, (size_t)b*NG+g, bf);
  __syncthreads();
  float v = nv[g]; int r = 0;
  for(int j=0; j<NG; j++){
    float u = nv[j];
    r += (u < v) || (u == v && j < g);
  }
  if(r < NLK) keep[b*NLK + r] = g;
}

// ---------------------------------------------------------------- FPS
__global__ __launch_bounds__(512) void k_fps(const float* __restrict__ xn,
                                             float* __restrict__ centers){
#pragma clang fp contract(off)
  int b = blockIdx.x, tid = threadIdx.x;
  const float* X = xn + (size_t)b*NPTS*3;
  float px[16],py[16],pz[16],dd[16];
  for(int s=0;s<16;s++){
    int n = s*512 + tid;
    px[s]=X[n*3]; py[s]=X[n*3+1]; pz[s]=X[n*3+2];
    dd[s]=1e10f;
  }
  __shared__ float sv[8]; __shared__ int sn[8];
  __shared__ int ssel; __shared__ int sc[NG];
  if(tid==0) sc[0]=0;
  int last = 0;
  for(int i=1;i<NG;i++){
    float lx=X[last*3], ly=X[last*3+1], lz=X[last*3+2];
    float bv=-1.0f; int bn=0x7fffffff;
    for(int s=0;s<16;s++){
      float dx=px[s]-lx, dy=py[s]-ly, dz=pz[s]-lz;
      float d=(dx*dx + dy*dy) + dz*dz;
      d = fminf(dd[s], d); dd[s]=d;
      if(d > bv){ bv=d; bn=s*512+tid; }
    }
    for(int off=32;off;off>>=1){
      float ov=__shfl_down(bv,off); int on=__shfl_down(bn,off);
      if(ov>bv || (ov==bv && on<bn)){ bv=ov; bn=on; }
    }
    if((tid&63)==0){ sv[tid>>6]=bv; sn[tid>>6]=bn; }
    __syncthreads();
    if(tid==0){
      float v=sv[0]; int n=sn[0];
      for(int w=1;w<8;w++) if(sv[w]>v || (sv[w]==v && sn[w]<n)){ v=sv[w]; n=sn[w]; }
      n &= (NPTS-1);
      ssel=n; sc[i]=n;
    }
    __syncthreads();
    last = ssel;
  }
  if(tid < NG){
    int n = sc[tid] & (NPTS-1);
    centers[((size_t)b*NG+tid)*3  ] = X[n*3];
    centers[((size_t)b*NG+tid)*3+1] = X[n*3+1];
    centers[((size_t)b*NG+tid)*3+2] = X[n*3+2];
  }
}

// ---------------------------------------------------------------- kNN select only -> patches
__global__ __launch_bounds__(256) void k_knn(
    const float* __restrict__ xn, const float* __restrict__ centers,
    const int* __restrict__ keep, float* __restrict__ patches)
{
  int blk=blockIdx.x; int b=blk>>6; int j=blk&63; int tid=threadIdx.x;
  __shared__ float sd[NPTS];
  __shared__ int   sel[NK];
  __shared__ float rv[4]; __shared__ int rn[4];
  __shared__ int   sseln;
  int g = keep[b*NLK + j] & (NG-1);
  const float* C = centers + ((size_t)b*NG + g)*3;
  float c0=C[0], c1=C[1], c2=C[2];
  const float* X = xn + (size_t)b*NPTS*3;
  {
#pragma clang fp contract(off)
    float cc = (c0*c0 + c1*c1) + c2*c2;
    for(int n=tid; n<NPTS; n+=256){
      float x0=X[n*3], x1=X[n*3+1], x2=X[n*3+2];
      float xx=(x0*x0 + x1*x1) + x2*x2;
      float dt=(c0*x0 + c1*x1) + c2*x2;
      sd[n] = (cc + xx) - 2.0f*dt;
    }
  }
  __syncthreads();
  float dl[32];
  for(int s=0;s<32;s++) dl[s] = sd[s*256 + tid];
  unsigned int alive = 0xffffffffu;
  for(int r=0; r<NK; r++){
    float bv=1e30f; int bn=0x7fffffff;
    for(int s=0;s<32;s++){
      if(alive & (1u<<s)){
        float v = dl[s];
        if(v < bv){ bv=v; bn=s*256+tid; }
      }
    }
    for(int off=32;off;off>>=1){
      float ov=__shfl_down(bv,off); int on=__shfl_down(bn,off);
      if(ov<bv || (ov==bv && on<bn)){ bv=ov; bn=on; }
    }
    if((tid&63)==0){ rv[tid>>6]=bv; rn[tid>>6]=bn; }
    __syncthreads();
    if(tid==0){
      float v=rv[0]; int n=rn[0];
      for(int w=1;w<4;w++) if(rv[w]<v || (rv[w]==v && rn[w]<n)){ v=rv[w]; n=rn[w]; }
      n &= (NPTS-1);
      sseln=n; sel[r]=n;
    }
    __syncthreads();
    int n = sseln;
    if((n & 255) == tid) alive &= ~(1u << (n >> 8));
  }
  __syncthreads();
  if(tid < NK){
    int n = sel[tid] & (NPTS-1);
    float* P = patches + ((size_t)(b*NLK+j)*NK + tid)*3;
    P[0]=X[n*3  ]-c0;
    P[1]=X[n*3+1]-c1;
    P[2]=X[n*3+2]-c2;
  }
}

// ---------------------------------------------------------------- embed: f1,f2,maxpool + pos hidden -> bf16 planes
__global__ __launch_bounds__(256) void k_embed(
    const float* __restrict__ patches, const float* __restrict__ centers,
    const int* __restrict__ keep,
    const void* __restrict__ w1, const void* __restrict__ b1,
    const void* __restrict__ w2, const void* __restrict__ b2,
    const void* __restrict__ pw1, const void* __restrict__ pb1,
    u16* __restrict__ mfhi, u16* __restrict__ mflo,
    u16* __restrict__ phhi, u16* __restrict__ phlo,
    const int* __restrict__ flag)
{
  int blk=blockIdx.x; int b=blk>>6; int j=blk&63; int tid=threadIdx.x;
  const bool bf = flag[0] != 0;
  __shared__ float pat[NK*3];
  __shared__ __align__(16) float f1t[128*36];   // [jj][k], pitch 36 (16B-aligned rows)
  int row = b*NLK + j;
  if(tid < NK*3) pat[tid] = patches[(size_t)row*NK*3 + tid];
  __syncthreads();
  // f1[k][m] = relu(patch[k]@W1 + b1[m]) stored transposed f1t[m][k]
  for(int i=0;i<16;i++){
    int idx = tid + i*256;          // 4096 = 32k x 128m
    int k = idx>>7, m = idx&127;
    float v = ldf(b1,m,bf)
            + pat[k*3+0]*ldf(w1,        m,bf)
            + pat[k*3+1]*ldf(w1, 128 + m,bf)
            + pat[k*3+2]*ldf(w1, 256 + m,bf);
    f1t[m*36 + k] = fmaxf(v, 0.0f);
  }
  __syncthreads();
  // f2[k][tid] = b2[tid] + sum_jj f1[k][jj]*w2[jj][tid]; maxpool over k in regs
  float acc[NK];
  {
    float bv = ldf(b2, tid, bf);
#pragma unroll
    for(int k=0;k<NK;k++) acc[k]=bv;
  }
  for(int jj=0;jj<128;jj++){
    float wv = ldf(w2, (size_t)jj*256+tid, bf);
    const float* fr = &f1t[jj*36];
#pragma unroll
    for(int k8=0;k8<8;k8++){
      float4 fv = *reinterpret_cast<const float4*>(fr + k8*4);
      acc[k8*4+0] = fmaf(fv.x, wv, acc[k8*4+0]);
      acc[k8*4+1] = fmaf(fv.y, wv, acc[k8*4+1]);
      acc[k8*4+2] = fmaf(fv.z, wv, acc[k8*4+2]);
      acc[k8*4+3] = fmaf(fv.w, wv, acc[k8*4+3]);
    }
  }
  float mx = acc[0];
#pragma unroll
  for(int k=1;k<NK;k++) mx = fmaxf(mx, acc[k]);
  { u16 hi,lo; split2(mx,hi,lo);
    mfhi[(size_t)row*256 + tid]=hi; mflo[(size_t)row*256 + tid]=lo; }
  // pos hidden
  if(tid < 128){
    int g = keep[b*NLK + j] & (NG-1);
    const float* C = centers + ((size_t)b*NG + g)*3;
    float v = ldf(pb1,tid,bf)
            + C[0]*ldf(pw1,        tid,bf)
            + C[1]*ldf(pw1, 128 + tid,bf)
            + C[2]*ldf(pw1, 256 + tid,bf);
    v = fmaxf(v, 0.0f);
    u16 hi,lo; split2(v,hi,lo);
    phhi[(size_t)row*128 + tid]=hi; phlo[(size_t)row*128 + tid]=lo;
  }
}

// ---------------------------------------------------------------- weight transpose: [K][N] -> [N][K] hi/lo bf16 planes
__global__ __launch_bounds__(256) void k_transpose(const void* __restrict__ W, size_t woff,
    int Kd, int Nd, u16* __restrict__ dhi, u16* __restrict__ dlo, size_t doff,
    const int* __restrict__ flag){
  __shared__ float t[32][33];
  const bool bf = flag[0]!=0;
  int n0 = blockIdx.x*32, k0 = blockIdx.y*32;
  for(int i=0;i<4;i++){
    int idx = threadIdx.x + i*256; int kr = idx>>5, nc = idx&31;
    t[kr][nc] = ldf(W, woff + (size_t)(k0+kr)*Nd + n0+nc, bf);
  }
  __syncthreads();
  for(int i=0;i<4;i++){
    int idx = threadIdx.x + i*256; int nr = idx>>5, kc = idx&31;
    float v = t[kc][nr];
    u16 hi,lo; split2(v,hi,lo);
    size_t o = doff + (size_t)(n0+nr)*Kd + k0+kc;
    dhi[o]=hi; dlo[o]=lo;
  }
}

// ---------------------------------------------------------------- LayerNorm -> bf16 hi/lo planes
__global__ __launch_bounds__(128) void k_ln_split(const float* __restrict__ X,
                                                  const void* __restrict__ gb, size_t go,
                                                  u16* __restrict__ Yhi, u16* __restrict__ Ylo,
                                                  const int* __restrict__ flag){
  int row=blockIdx.x, tid=threadIdx.x;
  const bool bf = flag[0] != 0;
  const float* x = X + (size_t)row*ND;
  __shared__ float sbuf[2];
  float v0=x[tid], v1=x[tid+128], v2=x[tid+256];
  float s = v0+v1+v2;
  for(int off=32;off;off>>=1) s += __shfl_down(s,off);
  if((tid&63)==0) sbuf[tid>>6]=s;
  __syncthreads();
  float mean = (sbuf[0]+sbuf[1]) * (1.0f/(float)ND);
  __syncthreads();
  float d0=v0-mean, d1=v1-mean, d2=v2-mean;
  s = d0*d0 + d1*d1 + d2*d2;
  for(int off=32;off;off>>=1) s += __shfl_down(s,off);
  if((tid&63)==0) sbuf[tid>>6]=s;
  __syncthreads();
  float var = (sbuf[0]+sbuf[1]) * (1.0f/(float)ND);
  float rstd = 1.0f / sqrtf(var + 1e-5f);
  float o0 = d0*rstd*ldf(gb,go+tid    ,bf) + ldf(gb,go+ND+tid    ,bf);
  float o1 = d1*rstd*ldf(gb,go+tid+128,bf) + ldf(gb,go+ND+tid+128,bf);
  float o2 = d2*rstd*ldf(gb,go+tid+256,bf) + ldf(gb,go+ND+tid+256,bf);
  u16 hi,lo; size_t rb = (size_t)row*ND;
  split2(o0,hi,lo); Yhi[rb+tid    ]=hi; Ylo[rb+tid    ]=lo;
  split2(o1,hi,lo); Yhi[rb+tid+128]=hi; Ylo[rb+tid+128]=lo;
  split2(o2,hi,lo); Yhi[rb+tid+256]=hi; Ylo[rb+tid+256]=lo;
}

// ---------------------------------------------------------------- MFMA GEMM, bf16x3 split precision
// A planes: MxK u16 (hi/lo); W planes: pre-transposed [N][K] u16 at element offset wo.
// C = act(A@W + bias) [+res]; output f32 Cf or split planes Ohi/Olo.
template<int TM, int TN, int ACT, bool RES, bool OSPLIT>
__global__ __launch_bounds__(256) void k_gemm_mfma(
    const u16* __restrict__ Ahi, const u16* __restrict__ Alo,
    const u16* __restrict__ Whi, const u16* __restrict__ Wlo, size_t wo,
    const void* __restrict__ bias, size_t bo, const int* __restrict__ flag,
    const float* __restrict__ res, float* __restrict__ Cf,
    u16* __restrict__ Ohi, u16* __restrict__ Olo,
    int N, int K)
{
  constexpr int MT = TM/32, NT = TN/32;
  __shared__ __align__(16) u16 sAh[TM*40];
  __shared__ __align__(16) u16 sAl[TM*40];
  __shared__ __align__(16) u16 sBh[TN*40];
  __shared__ __align__(16) u16 sBl[TN*40];
  int tid = threadIdx.x;
  int wave = tid >> 6, lane = tid & 63;
  int wm = wave >> 1, wn = wave & 1;
  int q = lane >> 4, l15 = lane & 15;
  int row0 = blockIdx.y*TM, col0 = blockIdx.x*TN;
  const bool bf = flag[0] != 0;
  f32x4 acc[MT][NT];
#pragma unroll
  for(int m=0;m<MT;m++)
#pragma unroll
    for(int n=0;n<NT;n++){ acc[m][n][0]=0.f; acc[m][n][1]=0.f; acc[m][n][2]=0.f; acc[m][n][3]=0.f; }

  for(int k0=0; k0<K; k0+=32){
#pragma unroll
    for(int i=0;i<TM/32;i++){
      int idx = tid + i*256; int r = idx>>3, c = (idx&7)*4;
      size_t ga = (size_t)(row0+r)*K + k0 + c;
      *reinterpret_cast<uint2*>(&sAh[r*40+c]) = *reinterpret_cast<const uint2*>(&Ahi[ga]);
      *reinterpret_cast<uint2*>(&sAl[r*40+c]) = *reinterpret_cast<const uint2*>(&Alo[ga]);
    }
#pragma unroll
    for(int i=0;i<TN/32;i++){
      int idx = tid + i*256; int r = idx>>3, c = (idx&7)*4;
      size_t ga = wo + (size_t)(col0+r)*K + k0 + c;
      *reinterpret_cast<uint2*>(&sBh[r*40+c]) = *reinterpret_cast<const uint2*>(&Whi[ga]);
      *reinterpret_cast<uint2*>(&sBl[r*40+c]) = *reinterpret_cast<const uint2*>(&Wlo[ga]);
    }
    __syncthreads();
    short8 ah[MT], al[MT], bh[NT], bl[NT];
#pragma unroll
    for(int m=0;m<MT;m++){
      int r = wm*(TM/2) + m*16 + l15;
      ah[m] = *reinterpret_cast<const short8*>(&sAh[r*40 + q*8]);
      al[m] = *reinterpret_cast<const short8*>(&sAl[r*40 + q*8]);
    }
#pragma unroll
    for(int n=0;n<NT;n++){
      int r = wn*(TN/2) + n*16 + l15;
      bh[n] = *reinterpret_cast<const short8*>(&sBh[r*40 + q*8]);
      bl[n] = *reinterpret_cast<const short8*>(&sBl[r*40 + q*8]);
    }
#pragma unroll
    for(int m=0;m<MT;m++)
#pragma unroll
      for(int n=0;n<NT;n++){
        acc[m][n] = __builtin_amdgcn_mfma_f32_16x16x32_bf16(ah[m], bh[n], acc[m][n],0,0,0);
        acc[m][n] = __builtin_amdgcn_mfma_f32_16x16x32_bf16(ah[m], bl[n], acc[m][n],0,0,0);
        acc[m][n] = __builtin_amdgcn_mfma_f32_16x16x32_bf16(al[m], bh[n], acc[m][n],0,0,0);
      }
    __syncthreads();
  }
  // epilogue: C row = row0 + wm*(TM/2)+m*16 + q*4+r4 ; col = col0 + wn*(TN/2)+n*16 + l15
#pragma unroll
  for(int m=0;m<MT;m++){
    int rbase = row0 + wm*(TM/2) + m*16 + q*4;
#pragma unroll
    for(int n=0;n<NT;n++){
      int col = col0 + wn*(TN/2) + n*16 + l15;
      float bv = ldf(bias, bo+col, bf);
#pragma unroll
      for(int r4=0;r4<4;r4++){
        int rr = rbase + r4;
        float v = acc[m][n][r4] + bv;
        if(ACT==1){
          float xx = v;
          v = 0.5f*xx*(1.0f + tanhf(0.7978845608028654f*(xx + 0.044715f*xx*xx*xx)));
        }
        if(RES) v += res[(size_t)rr*N + col];
        if(OSPLIT){
          u16 hi,lo; split2(v,hi,lo);
          Ohi[(size_t)rr*N + col]=hi; Olo[(size_t)rr*N + col]=lo;
        }else{
          Cf[(size_t)rr*N + col]=v;
        }
      }
    }
  }
}

// ---------------------------------------------------------------- attention (f32 math) -> bf16 planes
__global__ __launch_bounds__(256) void k_attn_pl(const float* __restrict__ qkv,
                                                 u16* __restrict__ ohi,
                                                 u16* __restrict__ olo){
  __shared__ float Q[64*65];
  __shared__ float Kb[64*65];
  __shared__ float V[64*65];
  int blk=blockIdx.x; int b=blk/NH, h=blk%NH;
  int tid=threadIdx.x;
  for(int idx=tid; idx<4096; idx+=256){
    int s=idx>>6, d=idx&63;
    const float* r = qkv + ((size_t)(b*NLK+s))*1152 + h*NHD + d;
    Q [s*65+d]=r[0];
    Kb[s*65+d]=r[384];
    V [s*65+d]=r[768];
  }
  __syncthreads();
  float sc[16];
  for(int t=0;t<16;t++){
    int idx=t*256+tid; int i=idx>>6, jj=idx&63;
    float acc=0.0f;
    for(int d=0;d<64;d++) acc = fmaf(Q[i*65+d], Kb[jj*65+d], acc);
    sc[t]=acc*0.125f;
  }
  __syncthreads();
  for(int t=0;t<16;t++){
    int idx=t*256+tid; int i=idx>>6, jj=idx&63;
    Q[i*65+jj]=sc[t];
  }
  __syncthreads();
  if(tid<64){
    float* rowp=&Q[tid*65];
    float m=rowp[0];
    for(int j=1;j<64;j++) m=fmaxf(m,rowp[j]);
    float sum=0.0f;
    for(int j=0;j<64;j++){ float e=__expf(rowp[j]-m); rowp[j]=e; sum+=e; }
    for(int j=0;j<64;j++) rowp[j]/=sum;
  }
  __syncthreads();
  for(int idx=tid; idx<4096; idx+=256){
    int s=idx>>6, d=idx&63;
    float acc=0.0f;
    for(int t=0;t<64;t++) acc=fmaf(Q[s*65+t], V[t*65+d], acc);
    size_t o = ((size_t)(b*NLK+s))*ND + h*NHD + d;
    u16 hi,lo; split2(acc,hi,lo);
    ohi[o]=hi; olo[o]=lo;
  }
}

// ---------------------------------------------------------------- old fallback path kernels (R4, passing)
__global__ __launch_bounds__(256) void k_group_embed(
    const float* __restrict__ xn, const float* __restrict__ centers,
    const int* __restrict__ keep,
    const void* __restrict__ w1, const void* __restrict__ b1,
    const void* __restrict__ w2, const void* __restrict__ b2,
    const void* __restrict__ w3, const void* __restrict__ b3,
    const void* __restrict__ pw1, const void* __restrict__ pb1,
    const void* __restrict__ pw2, const void* __restrict__ pb2,
    float* __restrict__ h0, const int* __restrict__ flag)
{
  int blk=blockIdx.x; int b=blk>>6; int j=blk&63; int tid=threadIdx.x;
  const bool bf = flag[0] != 0;
  __shared__ float sd[NPTS];
  __shared__ float f1s[NK*128];
  __shared__ float patch[NK][3];
  __shared__ int   sel[NK];
  __shared__ float rv[4]; __shared__ int rn[4];
  __shared__ int   sseln;
  __shared__ float maxf[256];
  __shared__ float ph[128];
  int g = keep[b*NLK + j] & (NG-1);
  const float* C = centers + ((size_t)b*NG + g)*3;
  float c0=C[0], c1=C[1], c2=C[2];
  const float* X = xn + (size_t)b*NPTS*3;
  {
#pragma clang fp contract(off)
    float cc = (c0*c0 + c1*c1) + c2*c2;
    for(int n=tid; n<NPTS; n+=256){
      float x0=X[n*3], x1=X[n*3+1], x2=X[n*3+2];
      float xx=(x0*x0 + x1*x1) + x2*x2;
      float dt=(c0*x0 + c1*x1) + c2*x2;
      sd[n] = (cc + xx) - 2.0f*dt;
    }
  }
  __syncthreads();
  float dl[32];
  for(int s=0;s<32;s++) dl[s] = sd[s*256 + tid];
  unsigned int alive = 0xffffffffu;
  for(int r=0; r<NK; r++){
    float bv=1e30f; int bn=0x7fffffff;
    for(int s=0;s<32;s++){
      if(alive & (1u<<s)){
        float v = dl[s];
        if(v < bv){ bv=v; bn=s*256+tid; }
      }
    }
    for(int off=32;off;off>>=1){
      float ov=__shfl_down(bv,off); int on=__shfl_down(bn,off);
      if(ov<bv || (ov==bv && on<bn)){ bv=ov; bn=on; }
    }
    if((tid&63)==0){ rv[tid>>6]=bv; rn[tid>>6]=bn; }
    __syncthreads();
    if(tid==0){
      float v=rv[0]; int n=rn[0];
      for(int w=1;w<4;w++) if(rv[w]<v || (rv[w]==v && rn[w]<n)){ v=rv[w]; n=rn[w]; }
      n &= (NPTS-1);
      sseln=n; sel[r]=n;
    }
    __syncthreads();
    int n = sseln;
    if((n & 255) == tid) alive &= ~(1u << (n >> 8));
  }
  __syncthreads();
  if(tid < NK){
    int n = sel[tid] & (NPTS-1);
    patch[tid][0]=X[n*3  ]-c0;
    patch[tid][1]=X[n*3+1]-c1;
    patch[tid][2]=X[n*3+2]-c2;
  }
  __syncthreads();
  for(int idx=tid; idx<NK*128; idx+=256){
    int k=idx>>7, m=idx&127;
    float v = ldf(b1,m,bf)
            + patch[k][0]*ldf(w1,        m,bf)
            + patch[k][1]*ldf(w1, 128 + m,bf)
            + patch[k][2]*ldf(w1, 256 + m,bf);
    f1s[idx] = fmaxf(v, 0.0f);
  }
  __syncthreads();
  {
    int m = tid;
    for(int k=0;k<NK;k++){
      float acc = ldf(b2, m, bf);
      const float* f1r = &f1s[k*128];
      for(int jj=0;jj<128;jj++) acc = fmaf(f1r[jj], ldf(w2, (size_t)jj*256+m, bf), acc);
      sd[k*256+m] = acc;
    }
  }
  __syncthreads();
  {
    float mx = sd[tid];
    for(int k=1;k<NK;k++) mx = fmaxf(mx, sd[k*256+tid]);
    maxf[tid] = mx;
  }
  if(tid < 128){
    float v = ldf(pb1,tid,bf)
            + c0*ldf(pw1,        tid,bf)
            + c1*ldf(pw1, 128 + tid,bf)
            + c2*ldf(pw1, 256 + tid,bf);
    ph[tid] = fmaxf(v, 0.0f);
  }
  __syncthreads();
  float* HO = h0 + ((size_t)b*NLK + j)*ND;
  for(int d=tid; d<ND; d+=256){
    float acc = ldf(b3, d, bf);
    for(int m=0;m<256;m++) acc = fmaf(maxf[m], ldf(w3, (size_t)m*ND+d, bf), acc);
    float acc2 = ldf(pb2, d, bf);
    for(int m=0;m<128;m++) acc2 = fmaf(ph[m], ldf(pw2, (size_t)m*ND+d, bf), acc2);
    HO[d] = acc + acc2;
  }
}

template<bool FINAL>
__global__ __launch_bounds__(128) void k_ln(const float* __restrict__ X,
                                            const void* __restrict__ gb, size_t go,
                                            void* __restrict__ Y,
                                            const int* __restrict__ flag){
  int row=blockIdx.x, tid=threadIdx.x;
  const bool bf = flag[0] != 0;
  const float* x = X + (size_t)row*ND;
  __shared__ float sbuf[2];
  float v0=x[tid], v1=x[tid+128], v2=x[tid+256];
  float s = v0+v1+v2;
  for(int off=32;off;off>>=1) s += __shfl_down(s,off);
  if((tid&63)==0) sbuf[tid>>6]=s;
  __syncthreads();
  float mean = (sbuf[0]+sbuf[1]) * (1.0f/(float)ND);
  __syncthreads();
  float d0=v0-mean, d1=v1-mean, d2=v2-mean;
  s = d0*d0 + d1*d1 + d2*d2;
  for(int off=32;off;off>>=1) s += __shfl_down(s,off);
  if((tid&63)==0) sbuf[tid>>6]=s;
  __syncthreads();
  float var = (sbuf[0]+sbuf[1]) * (1.0f/(float)ND);
  float rstd = 1.0f / sqrtf(var + 1e-5f);
  float o0 = d0*rstd*ldf(gb,go+tid    ,bf) + ldf(gb,go+ND+tid    ,bf);
  float o1 = d1*rstd*ldf(gb,go+tid+128,bf) + ldf(gb,go+ND+tid+128,bf);
  float o2 = d2*rstd*ldf(gb,go+tid+256,bf) + ldf(gb,go+ND+tid+256,bf);
  if(FINAL && bf){
    u16* yo = (u16*)Y + (size_t)row*ND;
    yo[tid]=f2bf(o0); yo[tid+128]=f2bf(o1); yo[tid+256]=f2bf(o2);
  }else{
    float* yo = (float*)Y + (size_t)row*ND;
    yo[tid]=o0; yo[tid+128]=o1; yo[tid+256]=o2;
  }
}

template<int ACT, bool RES>
__global__ __launch_bounds__(256) void k_gemm(const float* __restrict__ A,
    const void* __restrict__ W, size_t wo_, const void* __restrict__ bias, size_t bo_,
    const float* __restrict__ res, float* __restrict__ C,
    int M, int N, int K, const int* __restrict__ flag){
  __shared__ float As[16*68];
  __shared__ float Ws[16*64];
  int tid=threadIdx.x;
  const bool bf = flag[0] != 0;
  int bx=blockIdx.x, by=blockIdx.y;
  int tx=tid&15, ty=tid>>4;
  int ar = tid>>2, ak = (tid&3)*4;
  int wk = tid>>4, wn = (tid&15)*4;
  const float* Arow = A + (size_t)(by*64 + ar)*K;
  float acc[4][4] = {};
  for(int k0=0; k0<K; k0+=16){
    float4 av = *reinterpret_cast<const float4*>(Arow + k0 + ak);
    float4 wf;
    size_t we = wo_ + (size_t)(k0+wk)*N + bx*64 + wn;
    if(bf){
      ushort4 wv = *reinterpret_cast<const ushort4*>((const u16*)W + we);
      wf.x=bf2f(wv.x); wf.y=bf2f(wv.y); wf.z=bf2f(wv.z); wf.w=bf2f(wv.w);
    }else{
      wf = *reinterpret_cast<const float4*>((const float*)W + we);
    }
    __syncthreads();
    As[(ak+0)*68+ar]=av.x; As[(ak+1)*68+ar]=av.y;
    As[(ak+2)*68+ar]=av.z; As[(ak+3)*68+ar]=av.w;
    *reinterpret_cast<float4*>(&Ws[wk*64+wn]) = wf;
    __syncthreads();
#pragma unroll
    for(int k=0;k<16;k++){
      float4 a = *reinterpret_cast<const float4*>(&As[k*68 + ty*4]);
      float4 bb = *reinterpret_cast<const float4*>(&Ws[k*64 + tx*4]);
      acc[0][0]=fmaf(a.x,bb.x,acc[0][0]); acc[0][1]=fmaf(a.x,bb.y,acc[0][1]);
      acc[0][2]=fmaf(a.x,bb.z,acc[0][2]); acc[0][3]=fmaf(a.x,bb.w,acc[0][3]);
      acc[1][0]=fmaf(a.y,bb.x,acc[1][0]); acc[1][1]=fmaf(a.y,bb.y,acc[1][1]);
      acc[1][2]=fmaf(a.y,bb.z,acc[1][2]); acc[1][3]=fmaf(a.y,bb.w,acc[1][3]);
      acc[2][0]=fmaf(a.z,bb.x,acc[2][0]); acc[2][1]=fmaf(a.z,bb.y,acc[2][1]);
      acc[2][2]=fmaf(a.z,bb.z,acc[2][2]); acc[2][3]=fmaf(a.z,bb.w,acc[2][3]);
      acc[3][0]=fmaf(a.w,bb.x,acc[3][0]); acc[3][1]=fmaf(a.w,bb.y,acc[3][1]);
      acc[3][2]=fmaf(a.w,bb.z,acc[3][2]); acc[3][3]=fmaf(a.w,bb.w,acc[3][3]);
    }
  }
  int row0 = by*64, col0 = bx*64;
  for(int i=0;i<4;i++){
    int r = row0 + ty*4 + i;
    float4 o;
    float* op = &o.x;
    for(int jj=0;jj<4;jj++){
      int cn = col0 + tx*4 + jj;
      float v = acc[i][jj] + ldf(bias, bo_+cn, bf);
      if(ACT==1){
        float xx = v;
        v = 0.5f*xx*(1.0f + tanhf(0.7978845608028654f*(xx + 0.044715f*xx*xx*xx)));
      }
      if(RES) v += res[(size_t)r*N + cn];
      op[jj] = v;
    }
    *reinterpret_cast<float4*>(&C[(size_t)r*N + col0 + tx*4]) = o;
  }
}

__global__ __launch_bounds__(256) void k_attn(const float* __restrict__ qkv,
                                              float* __restrict__ out){
  __shared__ float Q[64*65];
  __shared__ float Kb[64*65];
  __shared__ float V[64*65];
  int blk=blockIdx.x; int b=blk/NH, h=blk%NH;
  int tid=threadIdx.x;
  for(int idx=tid; idx<4096; idx+=256){
    int s=idx>>6, d=idx&63;
    const float* r = qkv + ((size_t)(b*NLK+s))*1152 + h*NHD + d;
    Q [s*65+d]=r[0];
    Kb[s*65+d]=r[384];
    V [s*65+d]=r[768];
  }
  __syncthreads();
  float sc[16];
  for(int t=0;t<16;t++){
    int idx=t*256+tid; int i=idx>>6, jj=idx&63;
    float acc=0.0f;
    for(int d=0;d<64;d++) acc = fmaf(Q[i*65+d], Kb[jj*65+d], acc);
    sc[t]=acc*0.125f;
  }
  __syncthreads();
  for(int t=0;t<16;t++){
    int idx=t*256+tid; int i=idx>>6, jj=idx&63;
    Q[i*65+jj]=sc[t];
  }
  __syncthreads();
  if(tid<64){
    float* rowp=&Q[tid*65];
    float m=rowp[0];
    for(int j=1;j<64;j++) m=fmaxf(m,rowp[j]);
    float sum=0.0f;
    for(int j=0;j<64;j++){ float e=__expf(rowp[j]-m); rowp[j]=e; sum+=e; }
    for(int j=0;j<64;j++) rowp[j]/=sum;
  }
  __syncthreads();
  for(int idx=tid; idx<4096; idx+=256){
    int s=idx>>6, d=idx&63;
    float acc=0.0f;
    for(int t=0;t<64;t++) acc=fmaf(Q[s*65+t], V[t*65+d], acc);
    out[((size_t)(b*NLK+s))*ND + h*NHD + d]=acc;
  }
}

// ---------------------------------------------------------------- host
extern "C" void kernel_launch(void* const* d_in, const int* in_sizes, int n_in,
                              void* d_out, int out_size, void* d_ws, size_t ws_size,
                              hipStream_t stream){
  (void)in_sizes; (void)n_in; (void)out_size;
  const void* pts   = d_in[0];
  const void* noise = d_in[1];
  const void* pe_w1 = d_in[2];
  const void* pe_b1 = d_in[3];
  const void* pe_w2 = d_in[4];
  const void* pe_b2 = d_in[5];
  const void* pe_w3 = d_in[6];
  const void* pe_b3 = d_in[7];
  const void* pos_w1= d_in[8];
  const void* pos_b1= d_in[9];
  const void* pos_w2= d_in[10];
  const void* pos_b2= d_in[11];
  const void* ln1   = d_in[12];
  const void* wqkv  = d_in[13];
  const void* bqkv  = d_in[14];
  const void* wo    = d_in[15];
  const void* bo    = d_in[16];
  const void* ln2   = d_in[17];
  const void* wi    = d_in[18];
  const void* bi    = d_in[19];
  const void* wo2   = d_in[20];
  const void* bo2   = d_in[21];
  const void* lnf   = d_in[22];

  const size_t needed_new = (6711296ull + 16) * 4;   // ~26.9 MB
  if (ws_size >= needed_new) {
    // ---------------- NEW PATH: MFMA bf16x3 ----------------
    float* ws   = (float*)d_ws;
    float* h    = ws;                                   // 786432
    u16*  yhi   = (u16*)(ws + 786432);                  // planes 2048x384
    u16*  ylo   = yhi + 786432;
    float* qkvb = ws + 1572864;                         // 2359296 f32
    u16*  athi  = (u16*)(ws + 3932160);                 // planes 2048x384
    u16*  atlo  = athi + 786432;
    u16*  ubhi  = (u16*)(ws + 1572864);                 // planes 2048x1536 (alias qkvb+attb, dead by then)
    u16*  ublo  = ubhi + 3145728;
    float* xn   = ws + 1572864;                         // pre-loop alias
    u16*  wthi  = (u16*)(ws + 4718592);                 // 1769472 u16 per plane
    u16*  wtlo  = wthi + 1769472;
    float* patches = ws + 6488064;                      // 196608
    float* centers = ws + 6684672;                      // 24576
    int*   keep    = (int*)(ws + 6709248);              // 2048
    u16*  mfhi  = yhi;            u16* mflo = yhi + 2048*256;   // alias ypl (pre-loop)
    u16*  phhi  = athi;           u16* phlo = athi + 2048*128;  // alias attb (pre-loop)
    int*   flag = (int*)(ws + 6711296);

    k_detect   <<<1, 256, 0, stream>>>((const u16*)pts, flag);
    k_normalize<<<NB, 256, 0, stream>>>(pts, xn, flag);
    k_keep     <<<NB, 256, 0, stream>>>(noise, keep, flag);
    k_fps      <<<NB, 512, 0, stream>>>(xn, centers);
    k_knn      <<<NB*NLK, 256, 0, stream>>>(xn, centers, keep, patches);
    k_embed    <<<NB*NLK, 256, 0, stream>>>(patches, centers, keep,
        pe_w1, pe_b1, pe_w2, pe_b2, pos_w1, pos_b1,
        mfhi, mflo, phhi, phlo, flag);
    // token = maxf @ W3 + b3 ; then += ph @ PW2 + pb2
    k_transpose<<<dim3(12, 8), 256, 0, stream>>>(pe_w3, 0, 256, 384, wthi, wtlo, 0, flag);
    k_transpose<<<dim3(12, 4), 256, 0, stream>>>(pos_w2, 0, 128, 384, wthi, wtlo, 98304, flag);
    k_gemm_mfma<64,64,0,false,false><<<dim3(6,32), 256, 0, stream>>>(
        mfhi, mflo, wthi, wtlo, 0, pe_b3, 0, flag, nullptr, h, nullptr, nullptr, 384, 256);
    k_gemm_mfma<64,64,0,true ,false><<<dim3(6,32), 256, 0, stream>>>(
        phhi, phlo, wthi, wtlo, 98304, pos_b2, 0, flag, h, h, nullptr, nullptr, 384, 128);

    for(int l=0; l<NL; l++){
      k_transpose<<<dim3(36,12), 256, 0, stream>>>(wqkv, (size_t)l*442368, 384, 1152, wthi, wtlo, 0,       flag);
      k_transpose<<<dim3(12,12), 256, 0, stream>>>(wo,   (size_t)l*147456, 384, 384,  wthi, wtlo, 442368,  flag);
      k_transpose<<<dim3(48,12), 256, 0, stream>>>(wi,   (size_t)l*589824, 384, 1536, wthi, wtlo, 589824,  flag);
      k_transpose<<<dim3(12,48), 256, 0, stream>>>(wo2,  (size_t)l*589824, 1536, 384, wthi, wtlo, 1179648, flag);

      k_ln_split<<<MM, 128, 0, stream>>>(h, ln1, (size_t)l*2*ND, yhi, ylo, flag);
      k_gemm_mfma<64,64,0,false,false><<<dim3(18,32), 256, 0, stream>>>(
          yhi, ylo, wthi, wtlo, 0, bqkv, (size_t)l*1152, flag, nullptr, qkvb, nullptr, nullptr, 1152, 384);
      k_attn_pl<<<NB*NH, 256, 0, stream>>>(qkvb, athi, atlo);
      k_gemm_mfma<64,64,0,true ,false><<<dim3(6,32), 256, 0, stream>>>(
          athi, atlo, wthi, wtlo, 442368, bo, (size_t)l*384, flag, h, h, nullptr, nullptr, 384, 384);
      k_ln_split<<<MM, 128, 0, stream>>>(h, ln2, (size_t)l*2*ND, yhi, ylo, flag);
      k_gemm_mfma<64,64,1,false,true ><<<dim3(24,32), 256, 0, stream>>>(
          yhi, ylo, wthi, wtlo, 589824, bi, (size_t)l*1536, flag, nullptr, nullptr, ubhi, ublo, 1536, 384);
      k_gemm_mfma<64,64,0,true ,false><<<dim3(6,32), 256, 0, stream>>>(
          ubhi, ublo, wthi, wtlo, 1179648, bo2, (size_t)l*384, flag, h, h, nullptr, nullptr, 384, 1536);
    }
    k_ln<true><<<MM, 128, 0, stream>>>(h, lnf, 0, d_out, flag);
    return;
  }

  // ---------------- OLD PATH (R4, passing) ----------------
  const size_t needed = ((size_t)786432*2 + 3145728 + 16) * 4;
  if (ws_size < needed) return;

  float* ws   = (float*)d_ws;
  float* h    = ws;
  float* y    = h + 786432;
  float* big  = y + 786432;
  float* qkvb = big;
  float* attb = big + 2359296;
  float* ub   = big;
  float* xn      = big;
  float* centers = big + 786432;
  int*   keep    = (int*)(centers + (size_t)NB*NG*3);
  int*   flag    = (int*)(big + 3145728);

  k_detect   <<<1, 256, 0, stream>>>((const u16*)pts, flag);
  k_normalize<<<NB, 256, 0, stream>>>(pts, xn, flag);
  k_keep     <<<NB, 256, 0, stream>>>(noise, keep, flag);
  k_fps      <<<NB, 512, 0, stream>>>(xn, centers);
  k_group_embed<<<NB*NLK, 256, 0, stream>>>(xn, centers, keep,
      pe_w1, pe_b1, pe_w2, pe_b2, pe_w3, pe_b3,
      pos_w1, pos_b1, pos_w2, pos_b2, h, flag);

  for(int l=0; l<NL; l++){
    const size_t o_ln  = (size_t)l*2*ND;
    const size_t o_wq  = (size_t)l*ND*3*ND;
    const size_t o_bq  = (size_t)l*3*ND;
    const size_t o_wo  = (size_t)l*ND*ND;
    const size_t o_bo  = (size_t)l*ND;
    const size_t o_wi  = (size_t)l*ND*NF;
    const size_t o_bi  = (size_t)l*NF;
    const size_t o_wo2 = (size_t)l*NF*ND;
    const size_t o_bo2 = (size_t)l*ND;

    k_ln<false><<<MM, 128, 0, stream>>>(h, ln1, o_ln, (void*)y, flag);
    k_gemm<0,false><<<dim3(3*ND/64, MM/64), 256, 0, stream>>>(y, wqkv, o_wq, bqkv, o_bq, nullptr, qkvb, MM, 3*ND, ND, flag);
    k_attn<<<NB*NH, 256, 0, stream>>>(qkvb, attb);
    k_gemm<0,true ><<<dim3(ND/64, MM/64), 256, 0, stream>>>(attb, wo, o_wo, bo, o_bo, h, h, MM, ND, ND, flag);
    k_ln<false><<<MM, 128, 0, stream>>>(h, ln2, o_ln, (void*)y, flag);
    k_gemm<1,false><<<dim3(NF/64, MM/64), 256, 0, stream>>>(y, wi, o_wi, bi, o_bi, nullptr, ub, MM, NF, ND, flag);
    k_gemm<0,true ><<<dim3(ND/64, MM/64), 256, 0, stream>>>(ub, wo2, o_wo2, bo2, o_bo2, h, h, MM, ND, NF, flag);
  }
  k_ln<true><<<MM, 128, 0, stream>>>(h, lnf, 0, d_out, flag);
}

// Round 6
// 2412.157 us; speedup vs baseline: 1.8754x; 1.0462x over previous
//
#include <hip/hip_runtime.h>

// Problem constants
#define NPTS 8192
#define NB   32
#define NG   256
#define NK   32
#define ND   384
#define NH   6
#define NLK  64
#define NF   1536
#define NHD  64
#define NL   12
#define MM   2048   // NB*NLK token rows

typedef unsigned short u16;
typedef __attribute__((ext_vector_type(8))) short short8;   // bf16x8 MFMA frag
typedef __attribute__((ext_vector_type(4))) float f32x4;    // MFMA acc

__device__ __forceinline__ float bf2f(u16 v){
  unsigned int u = ((unsigned int)v) << 16;
  float f; __builtin_memcpy(&f, &u, 4); return f;
}
__device__ __forceinline__ float ldf(const void* p, size_t i, bool bf){
  if(bf) return bf2f(((const u16*)p)[i]);
  return ((const float*)p)[i];
}
__device__ __forceinline__ u16 f2bf(float f){
  unsigned int x; __builtin_memcpy(&x, &f, 4);
  x += 0x7fffu + ((x >> 16) & 1u);
  return (u16)(x >> 16);
}
// split f32 -> (hi, lo) bf16 planes; hi RNE, lo = RNE(residual)
__device__ __forceinline__ void split2(float v, u16& hi, u16& lo){
  hi = f2bf(v);
  lo = f2bf(v - bf2f(hi));
}

// ---------------------------------------------------------------- dtype detect
__global__ __launch_bounds__(256) void k_detect(const u16* __restrict__ pts,
                                                int* __restrict__ flag){
  __shared__ int bad;
  if(threadIdx.x==0) bad=0;
  __syncthreads();
  int hit=0;
  for(int i=threadIdx.x; i<4096; i+=256){
    unsigned e = (pts[i] >> 7) & 0xFFu;
    if(e >= 0x90u) hit=1;
  }
  if(hit) atomicOr(&bad, 1);
  __syncthreads();
  if(threadIdx.x==0) *flag = bad ? 0 : 1;   // 1 = bf16, 0 = f32
}

// ---------------------------------------------------------------- normalize
__device__ __forceinline__ float blockMax256(float v, float* sb, int tid){
  for(int off=32; off; off>>=1) v = fmaxf(v, __shfl_down(v, off));
  __syncthreads();
  if((tid&63)==0) sb[tid>>6] = v;
  __syncthreads();
  return fmaxf(fmaxf(sb[0],sb[1]), fmaxf(sb[2],sb[3]));
}

__global__ __launch_bounds__(256) void k_normalize(const void* __restrict__ pts,
                                                   float* __restrict__ xn,
                                                   const int* __restrict__ flag){
#pragma clang fp contract(off)
  int b = blockIdx.x, tid = threadIdx.x;
  const bool bf = flag[0] != 0;
  __shared__ float sb[4];
  const size_t base = (size_t)b*NPTS*3;
  float mn0=1e30f,mn1=1e30f,mn2=1e30f, mx0=-1e30f,mx1=-1e30f,mx2=-1e30f;
  for(int n=tid; n<NPTS; n+=256){
    float x0=ldf(pts,base+n*3,bf), x1=ldf(pts,base+n*3+1,bf), x2=ldf(pts,base+n*3+2,bf);
    mn0=fminf(mn0,x0); mx0=fmaxf(mx0,x0);
    mn1=fminf(mn1,x1); mx1=fmaxf(mx1,x1);
    mn2=fminf(mn2,x2); mx2=fmaxf(mx2,x2);
  }
  mx0=blockMax256(mx0,sb,tid); mn0=-blockMax256(-mn0,sb,tid);
  mx1=blockMax256(mx1,sb,tid); mn1=-blockMax256(-mn1,sb,tid);
  mx2=blockMax256(mx2,sb,tid); mn2=-blockMax256(-mn2,sb,tid);
  float c0=0.5f*(mn0+mx0), c1=0.5f*(mn1+mx1), c2=0.5f*(mn2+mx2);
  float mr=0.0f;
  for(int n=tid; n<NPTS; n+=256){
    float d0=ldf(pts,base+n*3,bf)-c0, d1=ldf(pts,base+n*3+1,bf)-c1, d2=ldf(pts,base+n*3+2,bf)-c2;
    float nr = sqrtf((d0*d0 + d1*d1) + d2*d2);
    mr = fmaxf(mr, nr);
  }
  float radius = blockMax256(mr, sb, tid);
  float* XO = xn + base;
  for(int n=tid; n<NPTS; n+=256){
    XO[n*3  ] = (ldf(pts,base+n*3  ,bf)-c0)/radius;
    XO[n*3+1] = (ldf(pts,base+n*3+1,bf)-c1)/radius;
    XO[n*3+2] = (ldf(pts,base+n*3+2,bf)-c2)/radius;
  }
}

// ---------------------------------------------------------------- keep
__global__ __launch_bounds__(256) void k_keep(const void* __restrict__ noise,
                                              int* __restrict__ keep,
                                              const int* __restrict__ flag){
  int b = blockIdx.x, g = threadIdx.x;
  const bool bf = flag[0] != 0;
  __shared__ float nv[NG];
  nv[g] = ldf(noise, (size_t)b*NG+g, bf);
  __syncthreads();
  float v = nv[g]; int r = 0;
  for(int j=0; j<NG; j++){
    float u = nv[j];
    r += (u < v) || (u == v && j < g);
  }
  if(r < NLK) keep[b*NLK + r] = g;
}

// ---------------------------------------------------------------- FPS, low-latency per-iteration
// 2 barriers/iter; winner coords travel with the shuffle reduction (no global re-read);
// second-level reduce is a 3-step shuffle in wave 0 (no serial tid0 scan).
__global__ __launch_bounds__(512) void k_fps(const float* __restrict__ xn,
                                             float* __restrict__ centers){
#pragma clang fp contract(off)
  int b = blockIdx.x, tid = threadIdx.x;
  int lane = tid & 63, wave = tid >> 6;
  const float* X = xn + (size_t)b*NPTS*3;
  float px[16],py[16],pz[16],dd[16];
  for(int s=0;s<16;s++){
    int n = s*512 + tid;
    px[s]=X[n*3]; py[s]=X[n*3+1]; pz[s]=X[n*3+2];
    dd[s]=1e10f;
  }
  __shared__ float wv[8], wx[8], wy[8], wz[8]; __shared__ int wn_[8];
  __shared__ float fx, fy, fz;
  __shared__ int sc[NG];
  if(tid==0) sc[0]=0;
  // point 0 coords: same-address load -> broadcast
  float lx = X[0], ly = X[1], lz = X[2];
  for(int i=1;i<NG;i++){
    float bv=-1.0f; int bn=0x7fffffff; float bx=0.f,by=0.f,bz=0.f;
    for(int s=0;s<16;s++){
      float dx=px[s]-lx, dy=py[s]-ly, dz=pz[s]-lz;
      float d=(dx*dx + dy*dy) + dz*dz;
      d = fminf(dd[s], d); dd[s]=d;
      if(d > bv){ bv=d; bn=s*512+tid; bx=px[s]; by=py[s]; bz=pz[s]; }  // strict >: first index on ties
    }
    for(int off=32;off;off>>=1){
      float ov=__shfl_down(bv,off); int on=__shfl_down(bn,off);
      float ox=__shfl_down(bx,off), oy=__shfl_down(by,off), oz=__shfl_down(bz,off);
      if(ov>bv || (ov==bv && on<bn)){ bv=ov; bn=on; bx=ox; by=oy; bz=oz; }
    }
    if(lane==0){ wv[wave]=bv; wn_[wave]=bn; wx[wave]=bx; wy[wave]=by; wz[wave]=bz; }
    __syncthreads();
    if(wave==0){
      float v  = (lane<8)? wv[lane]  : -1.0f;
      int   n  = (lane<8)? wn_[lane] : 0x7fffffff;
      float cx = (lane<8)? wx[lane] : 0.f;
      float cy = (lane<8)? wy[lane] : 0.f;
      float cz = (lane<8)? wz[lane] : 0.f;
      for(int off=4;off;off>>=1){
        float ov=__shfl_down(v,off); int on=__shfl_down(n,off);
        float ox=__shfl_down(cx,off), oy=__shfl_down(cy,off), oz=__shfl_down(cz,off);
        if(ov>v || (ov==v && on<n)){ v=ov; n=on; cx=ox; cy=oy; cz=oz; }
      }
      if(lane==0){ n &= (NPTS-1); sc[i]=n; fx=cx; fy=cy; fz=cz; }
    }
    __syncthreads();
    lx=fx; ly=fy; lz=fz;
  }
  if(tid < NG){
    int n = sc[tid] & (NPTS-1);
    centers[((size_t)b*NG+tid)*3  ] = X[n*3];
    centers[((size_t)b*NG+tid)*3+1] = X[n*3+1];
    centers[((size_t)b*NG+tid)*3+2] = X[n*3+2];
  }
}

// ---------------------------------------------------------------- kNN select only -> patches
__global__ __launch_bounds__(256) void k_knn(
    const float* __restrict__ xn, const float* __restrict__ centers,
    const int* __restrict__ keep, float* __restrict__ patches)
{
  int blk=blockIdx.x; int b=blk>>6; int j=blk&63; int tid=threadIdx.x;
  __shared__ float sd[NPTS];
  __shared__ int   sel[NK];
  __shared__ float rv[4]; __shared__ int rn[4];
  __shared__ int   sseln;
  int g = keep[b*NLK + j] & (NG-1);
  const float* C = centers + ((size_t)b*NG + g)*3;
  float c0=C[0], c1=C[1], c2=C[2];
  const float* X = xn + (size_t)b*NPTS*3;
  {
#pragma clang fp contract(off)
    float cc = (c0*c0 + c1*c1) + c2*c2;
    for(int n=tid; n<NPTS; n+=256){
      float x0=X[n*3], x1=X[n*3+1], x2=X[n*3+2];
      float xx=(x0*x0 + x1*x1) + x2*x2;
      float dt=(c0*x0 + c1*x1) + c2*x2;
      sd[n] = (cc + xx) - 2.0f*dt;
    }
  }
  __syncthreads();
  float dl[32];
  for(int s=0;s<32;s++) dl[s] = sd[s*256 + tid];
  unsigned int alive = 0xffffffffu;
  for(int r=0; r<NK; r++){
    float bv=1e30f; int bn=0x7fffffff;
    for(int s=0;s<32;s++){
      if(alive & (1u<<s)){
        float v = dl[s];
        if(v < bv){ bv=v; bn=s*256+tid; }
      }
    }
    for(int off=32;off;off>>=1){
      float ov=__shfl_down(bv,off); int on=__shfl_down(bn,off);
      if(ov<bv || (ov==bv && on<bn)){ bv=ov; bn=on; }
    }
    if((tid&63)==0){ rv[tid>>6]=bv; rn[tid>>6]=bn; }
    __syncthreads();
    if(tid==0){
      float v=rv[0]; int n=rn[0];
      for(int w=1;w<4;w++) if(rv[w]<v || (rv[w]==v && rn[w]<n)){ v=rv[w]; n=rn[w]; }
      n &= (NPTS-1);
      sseln=n; sel[r]=n;
    }
    __syncthreads();
    int n = sseln;
    if((n & 255) == tid) alive &= ~(1u << (n >> 8));
  }
  __syncthreads();
  if(tid < NK){
    int n = sel[tid] & (NPTS-1);
    float* P = patches + ((size_t)(b*NLK+j)*NK + tid)*3;
    P[0]=X[n*3  ]-c0;
    P[1]=X[n*3+1]-c1;
    P[2]=X[n*3+2]-c2;
  }
}

// ---------------------------------------------------------------- embed: f1,f2,maxpool + pos hidden -> bf16 planes
__global__ __launch_bounds__(256) void k_embed(
    const float* __restrict__ patches, const float* __restrict__ centers,
    const int* __restrict__ keep,
    const void* __restrict__ w1, const void* __restrict__ b1,
    const void* __restrict__ w2, const void* __restrict__ b2,
    const void* __restrict__ pw1, const void* __restrict__ pb1,
    u16* __restrict__ mfhi, u16* __restrict__ mflo,
    u16* __restrict__ phhi, u16* __restrict__ phlo,
    const int* __restrict__ flag)
{
  int blk=blockIdx.x; int b=blk>>6; int j=blk&63; int tid=threadIdx.x;
  const bool bf = flag[0] != 0;
  __shared__ float pat[NK*3];
  __shared__ __align__(16) float f1t[128*36];   // [jj][k], pitch 36
  int row = b*NLK + j;
  if(tid < NK*3) pat[tid] = patches[(size_t)row*NK*3 + tid];
  __syncthreads();
  for(int i=0;i<16;i++){
    int idx = tid + i*256;
    int k = idx>>7, m = idx&127;
    float v = ldf(b1,m,bf)
            + pat[k*3+0]*ldf(w1,        m,bf)
            + pat[k*3+1]*ldf(w1, 128 + m,bf)
            + pat[k*3+2]*ldf(w1, 256 + m,bf);
    f1t[m*36 + k] = fmaxf(v, 0.0f);
  }
  __syncthreads();
  float acc[NK];
  {
    float bv = ldf(b2, tid, bf);
#pragma unroll
    for(int k=0;k<NK;k++) acc[k]=bv;
  }
  for(int jj=0;jj<128;jj++){
    float wv = ldf(w2, (size_t)jj*256+tid, bf);
    const float* fr = &f1t[jj*36];
#pragma unroll
    for(int k8=0;k8<8;k8++){
      float4 fv = *reinterpret_cast<const float4*>(fr + k8*4);
      acc[k8*4+0] = fmaf(fv.x, wv, acc[k8*4+0]);
      acc[k8*4+1] = fmaf(fv.y, wv, acc[k8*4+1]);
      acc[k8*4+2] = fmaf(fv.z, wv, acc[k8*4+2]);
      acc[k8*4+3] = fmaf(fv.w, wv, acc[k8*4+3]);
    }
  }
  float mx = acc[0];
#pragma unroll
  for(int k=1;k<NK;k++) mx = fmaxf(mx, acc[k]);
  { u16 hi,lo; split2(mx,hi,lo);
    mfhi[(size_t)row*256 + tid]=hi; mflo[(size_t)row*256 + tid]=lo; }
  if(tid < 128){
    int g = keep[b*NLK + j] & (NG-1);
    const float* C = centers + ((size_t)b*NG + g)*3;
    float v = ldf(pb1,tid,bf)
            + C[0]*ldf(pw1,        tid,bf)
            + C[1]*ldf(pw1, 128 + tid,bf)
            + C[2]*ldf(pw1, 256 + tid,bf);
    v = fmaxf(v, 0.0f);
    u16 hi,lo; split2(v,hi,lo);
    phhi[(size_t)row*128 + tid]=hi; phlo[(size_t)row*128 + tid]=lo;
  }
}

// ---------------------------------------------------------------- weight transpose: [K][N] -> [N][K] hi/lo bf16 planes
__global__ __launch_bounds__(256) void k_transpose(const void* __restrict__ W, size_t woff,
    int Kd, int Nd, u16* __restrict__ dhi, u16* __restrict__ dlo, size_t doff,
    const int* __restrict__ flag){
  __shared__ float t[32][33];
  const bool bf = flag[0]!=0;
  int n0 = blockIdx.x*32, k0 = blockIdx.y*32;
  for(int i=0;i<4;i++){
    int idx = threadIdx.x + i*256; int kr = idx>>5, nc = idx&31;
    t[kr][nc] = ldf(W, woff + (size_t)(k0+kr)*Nd + n0+nc, bf);
  }
  __syncthreads();
  for(int i=0;i<4;i++){
    int idx = threadIdx.x + i*256; int nr = idx>>5, kc = idx&31;
    float v = t[kc][nr];
    u16 hi,lo; split2(v,hi,lo);
    size_t o = doff + (size_t)(n0+nr)*Kd + k0+kc;
    dhi[o]=hi; dlo[o]=lo;
  }
}

// ---------------------------------------------------------------- batched per-layer transpose: wqkv|wo|wi|wo2 in one launch
__global__ __launch_bounds__(256) void k_transpose4(
    const void* __restrict__ wqkv, const void* __restrict__ wo,
    const void* __restrict__ wi,   const void* __restrict__ wo2,
    int l, u16* __restrict__ dhi, u16* __restrict__ dlo,
    const int* __restrict__ flag){
  __shared__ float t[32][33];
  const bool bf = flag[0]!=0;
  int id = blockIdx.x;
  const void* W; int Kd, Nd; size_t woff, doff; int local;
  if(id < 432){        W=wqkv; Kd=384;  Nd=1152; woff=(size_t)l*442368; doff=0;       local=id; }
  else if(id < 576){   W=wo;   Kd=384;  Nd=384;  woff=(size_t)l*147456; doff=442368;  local=id-432; }
  else if(id < 1152){  W=wi;   Kd=384;  Nd=1536; woff=(size_t)l*589824; doff=589824;  local=id-576; }
  else {               W=wo2;  Kd=1536; Nd=384;  woff=(size_t)l*589824; doff=1179648; local=id-1152; }
  int ntiles = Nd >> 5;
  int n0 = (local % ntiles)*32, k0 = (local / ntiles)*32;
  for(int i=0;i<4;i++){
    int idx = threadIdx.x + i*256; int kr = idx>>5, nc = idx&31;
    t[kr][nc] = ldf(W, woff + (size_t)(k0+kr)*Nd + n0+nc, bf);
  }
  __syncthreads();
  for(int i=0;i<4;i++){
    int idx = threadIdx.x + i*256; int nr = idx>>5, kc = idx&31;
    float v = t[kc][nr];
    u16 hi,lo; split2(v,hi,lo);
    size_t o = doff + (size_t)(n0+nr)*Kd + k0+kc;
    dhi[o]=hi; dlo[o]=lo;
  }
}

// ---------------------------------------------------------------- LayerNorm -> bf16 hi/lo planes
__global__ __launch_bounds__(128) void k_ln_split(const float* __restrict__ X,
                                                  const void* __restrict__ gb, size_t go,
                                                  u16* __restrict__ Yhi, u16* __restrict__ Ylo,
                                                  const int* __restrict__ flag){
  int row=blockIdx.x, tid=threadIdx.x;
  const bool bf = flag[0] != 0;
  const float* x = X + (size_t)row*ND;
  __shared__ float sbuf[2];
  float v0=x[tid], v1=x[tid+128], v2=x[tid+256];
  float s = v0+v1+v2;
  for(int off=32;off;off>>=1) s += __shfl_down(s,off);
  if((tid&63)==0) sbuf[tid>>6]=s;
  __syncthreads();
  float mean = (sbuf[0]+sbuf[1]) * (1.0f/(float)ND);
  __syncthreads();
  float d0=v0-mean, d1=v1-mean, d2=v2-mean;
  s = d0*d0 + d1*d1 + d2*d2;
  for(int off=32;off;off>>=1) s += __shfl_down(s,off);
  if((tid&63)==0) sbuf[tid>>6]=s;
  __syncthreads();
  float var = (sbuf[0]+sbuf[1]) * (1.0f/(float)ND);
  float rstd = 1.0f / sqrtf(var + 1e-5f);
  float o0 = d0*rstd*ldf(gb,go+tid    ,bf) + ldf(gb,go+ND+tid    ,bf);
  float o1 = d1*rstd*ldf(gb,go+tid+128,bf) + ldf(gb,go+ND+tid+128,bf);
  float o2 = d2*rstd*ldf(gb,go+tid+256,bf) + ldf(gb,go+ND+tid+256,bf);
  u16 hi,lo; size_t rb = (size_t)row*ND;
  split2(o0,hi,lo); Yhi[rb+tid    ]=hi; Ylo[rb+tid    ]=lo;
  split2(o1,hi,lo); Yhi[rb+tid+128]=hi; Ylo[rb+tid+128]=lo;
  split2(o2,hi,lo); Yhi[rb+tid+256]=hi; Ylo[rb+tid+256]=lo;
}

// ---------------------------------------------------------------- MFMA GEMM, bf16x3 split precision
template<int TM, int TN, int ACT, bool RES, bool OSPLIT>
__global__ __launch_bounds__(256) void k_gemm_mfma(
    const u16* __restrict__ Ahi, const u16* __restrict__ Alo,
    const u16* __restrict__ Whi, const u16* __restrict__ Wlo, size_t wo,
    const void* __restrict__ bias, size_t bo, const int* __restrict__ flag,
    const float* __restrict__ res, float* __restrict__ Cf,
    u16* __restrict__ Ohi, u16* __restrict__ Olo,
    int N, int K)
{
  constexpr int MT = TM/32, NT = TN/32;
  __shared__ __align__(16) u16 sAh[TM*40];
  __shared__ __align__(16) u16 sAl[TM*40];
  __shared__ __align__(16) u16 sBh[TN*40];
  __shared__ __align__(16) u16 sBl[TN*40];
  int tid = threadIdx.x;
  int wave = tid >> 6, lane = tid & 63;
  int wm = wave >> 1, wn = wave & 1;
  int q = lane >> 4, l15 = lane & 15;
  int row0 = blockIdx.y*TM, col0 = blockIdx.x*TN;
  const bool bf = flag[0] != 0;
  f32x4 acc[MT][NT];
#pragma unroll
  for(int m=0;m<MT;m++)
#pragma unroll
    for(int n=0;n<NT;n++){ acc[m][n][0]=0.f; acc[m][n][1]=0.f; acc[m][n][2]=0.f; acc[m][n][3]=0.f; }

  for(int k0=0; k0<K; k0+=32){
#pragma unroll
    for(int i=0;i<TM/32;i++){
      int idx = tid + i*256; int r = idx>>3, c = (idx&7)*4;
      size_t ga = (size_t)(row0+r)*K + k0 + c;
      *reinterpret_cast<uint2*>(&sAh[r*40+c]) = *reinterpret_cast<const uint2*>(&Ahi[ga]);
      *reinterpret_cast<uint2*>(&sAl[r*40+c]) = *reinterpret_cast<const uint2*>(&Alo[ga]);
    }
#pragma unroll
    for(int i=0;i<TN/32;i++){
      int idx = tid + i*256; int r = idx>>3, c = (idx&7)*4;
      size_t ga = wo + (size_t)(col0+r)*K + k0 + c;
      *reinterpret_cast<uint2*>(&sBh[r*40+c]) = *reinterpret_cast<const uint2*>(&Whi[ga]);
      *reinterpret_cast<uint2*>(&sBl[r*40+c]) = *reinterpret_cast<const uint2*>(&Wlo[ga]);
    }
    __syncthreads();
    short8 ah[MT], al[MT], bh[NT], bl[NT];
#pragma unroll
    for(int m=0;m<MT;m++){
      int r = wm*(TM/2) + m*16 + l15;
      ah[m] = *reinterpret_cast<const short8*>(&sAh[r*40 + q*8]);
      al[m] = *reinterpret_cast<const short8*>(&sAl[r*40 + q*8]);
    }
#pragma unroll
    for(int n=0;n<NT;n++){
      int r = wn*(TN/2) + n*16 + l15;
      bh[n] = *reinterpret_cast<const short8*>(&sBh[r*40 + q*8]);
      bl[n] = *reinterpret_cast<const short8*>(&sBl[r*40 + q*8]);
    }
#pragma unroll
    for(int m=0;m<MT;m++)
#pragma unroll
      for(int n=0;n<NT;n++){
        acc[m][n] = __builtin_amdgcn_mfma_f32_16x16x32_bf16(ah[m], bh[n], acc[m][n],0,0,0);
        acc[m][n] = __builtin_amdgcn_mfma_f32_16x16x32_bf16(ah[m], bl[n], acc[m][n],0,0,0);
        acc[m][n] = __builtin_amdgcn_mfma_f32_16x16x32_bf16(al[m], bh[n], acc[m][n],0,0,0);
      }
    __syncthreads();
  }
#pragma unroll
  for(int m=0;m<MT;m++){
    int rbase = row0 + wm*(TM/2) + m*16 + q*4;
#pragma unroll
    for(int n=0;n<NT;n++){
      int col = col0 + wn*(TN/2) + n*16 + l15;
      float bv = ldf(bias, bo+col, bf);
#pragma unroll
      for(int r4=0;r4<4;r4++){
        int rr = rbase + r4;
        float v = acc[m][n][r4] + bv;
        if(ACT==1){
          float xx = v;
          v = 0.5f*xx*(1.0f + tanhf(0.7978845608028654f*(xx + 0.044715f*xx*xx*xx)));
        }
        if(RES) v += res[(size_t)rr*N + col];
        if(OSPLIT){
          u16 hi,lo; split2(v,hi,lo);
          Ohi[(size_t)rr*N + col]=hi; Olo[(size_t)rr*N + col]=lo;
        }else{
          Cf[(size_t)rr*N + col]=v;
        }
      }
    }
  }
}

// ---------------------------------------------------------------- attention (f32 math) -> bf16 planes
__global__ __launch_bounds__(256) void k_attn_pl(const float* __restrict__ qkv,
                                                 u16* __restrict__ ohi,
                                                 u16* __restrict__ olo){
  __shared__ float Q[64*65];
  __shared__ float Kb[64*65];
  __shared__ float V[64*65];
  int blk=blockIdx.x; int b=blk/NH, h=blk%NH;
  int tid=threadIdx.x;
  for(int idx=tid; idx<4096; idx+=256){
    int s=idx>>6, d=idx&63;
    const float* r = qkv + ((size_t)(b*NLK+s))*1152 + h*NHD + d;
    Q [s*65+d]=r[0];
    Kb[s*65+d]=r[384];
    V [s*65+d]=r[768];
  }
  __syncthreads();
  float sc[16];
  for(int t=0;t<16;t++){
    int idx=t*256+tid; int i=idx>>6, jj=idx&63;
    float acc=0.0f;
    for(int d=0;d<64;d++) acc = fmaf(Q[i*65+d], Kb[jj*65+d], acc);
    sc[t]=acc*0.125f;
  }
  __syncthreads();
  for(int t=0;t<16;t++){
    int idx=t*256+tid; int i=idx>>6, jj=idx&63;
    Q[i*65+jj]=sc[t];
  }
  __syncthreads();
  if(tid<64){
    float* rowp=&Q[tid*65];
    float m=rowp[0];
    for(int j=1;j<64;j++) m=fmaxf(m,rowp[j]);
    float sum=0.0f;
    for(int j=0;j<64;j++){ float e=__expf(rowp[j]-m); rowp[j]=e; sum+=e; }
    for(int j=0;j<64;j++) rowp[j]/=sum;
  }
  __syncthreads();
  for(int idx=tid; idx<4096; idx+=256){
    int s=idx>>6, d=idx&63;
    float acc=0.0f;
    for(int t=0;t<64;t++) acc=fmaf(Q[s*65+t], V[t*65+d], acc);
    size_t o = ((size_t)(b*NLK+s))*ND + h*NHD + d;
    u16 hi,lo; split2(acc,hi,lo);
    ohi[o]=hi; olo[o]=lo;
  }
}

// ---------------------------------------------------------------- final LayerNorm (output)
template<bool FINAL>
__global__ __launch_bounds__(128) void k_ln(const float* __restrict__ X,
                                            const void* __restrict__ gb, size_t go,
                                            void* __restrict__ Y,
                                            const int* __restrict__ flag){
  int row=blockIdx.x, tid=threadIdx.x;
  const bool bf = flag[0] != 0;
  const float* x = X + (size_t)row*ND;
  __shared__ float sbuf[2];
  float v0=x[tid], v1=x[tid+128], v2=x[tid+256];
  float s = v0+v1+v2;
  for(int off=32;off;off>>=1) s += __shfl_down(s,off);
  if((tid&63)==0) sbuf[tid>>6]=s;
  __syncthreads();
  float mean = (sbuf[0]+sbuf[1]) * (1.0f/(float)ND);
  __syncthreads();
  float d0=v0-mean, d1=v1-mean, d2=v2-mean;
  s = d0*d0 + d1*d1 + d2*d2;
  for(int off=32;off;off>>=1) s += __shfl_down(s,off);
  if((tid&63)==0) sbuf[tid>>6]=s;
  __syncthreads();
  float var = (sbuf[0]+sbuf[1]) * (1.0f/(float)ND);
  float rstd = 1.0f / sqrtf(var + 1e-5f);
  float o0 = d0*rstd*ldf(gb,go+tid    ,bf) + ldf(gb,go+ND+tid    ,bf);
  float o1 = d1*rstd*ldf(gb,go+tid+128,bf) + ldf(gb,go+ND+tid+128,bf);
  float o2 = d2*rstd*ldf(gb,go+tid+256,bf) + ldf(gb,go+ND+tid+256,bf);
  if(FINAL && bf){
    u16* yo = (u16*)Y + (size_t)row*ND;
    yo[tid]=f2bf(o0); yo[tid+128]=f2bf(o1); yo[tid+256]=f2bf(o2);
  }else{
    float* yo = (float*)Y + (size_t)row*ND;
    yo[tid]=o0; yo[tid+128]=o1; yo[tid+256]=o2;
  }
}

// ---------------------------------------------------------------- host
extern "C" void kernel_launch(void* const* d_in, const int* in_sizes, int n_in,
                              void* d_out, int out_size, void* d_ws, size_t ws_size,
                              hipStream_t stream){
  (void)in_sizes; (void)n_in; (void)out_size;
  const void* pts   = d_in[0];
  const void* noise = d_in[1];
  const void* pe_w1 = d_in[2];
  const void* pe_b1 = d_in[3];
  const void* pe_w2 = d_in[4];
  const void* pe_b2 = d_in[5];
  const void* pe_w3 = d_in[6];
  const void* pe_b3 = d_in[7];
  const void* pos_w1= d_in[8];
  const void* pos_b1= d_in[9];
  const void* pos_w2= d_in[10];
  const void* pos_b2= d_in[11];
  const void* ln1   = d_in[12];
  const void* wqkv  = d_in[13];
  const void* bqkv  = d_in[14];
  const void* wo    = d_in[15];
  const void* bo    = d_in[16];
  const void* ln2   = d_in[17];
  const void* wi    = d_in[18];
  const void* bi    = d_in[19];
  const void* wo2   = d_in[20];
  const void* bo2   = d_in[21];
  const void* lnf   = d_in[22];

  const size_t needed_new = (6711296ull + 16) * 4;   // ~26.9 MB
  if (ws_size < needed_new) return;   // (R4 fallback removed; ws known >= this from R5)

  float* ws   = (float*)d_ws;
  float* h    = ws;                                   // 786432
  u16*  yhi   = (u16*)(ws + 786432);                  // planes 2048x384
  u16*  ylo   = yhi + 786432;
  float* qkvb = ws + 1572864;                         // 2359296 f32
  u16*  athi  = (u16*)(ws + 3932160);                 // planes 2048x384
  u16*  atlo  = athi + 786432;
  u16*  ubhi  = (u16*)(ws + 1572864);                 // planes 2048x1536 (alias qkvb+attb)
  u16*  ublo  = ubhi + 3145728;
  float* xn   = ws + 1572864;                         // pre-loop alias
  u16*  wthi  = (u16*)(ws + 4718592);                 // 1769472 u16 per plane
  u16*  wtlo  = wthi + 1769472;
  float* patches = ws + 6488064;                      // 196608
  float* centers = ws + 6684672;                      // 24576
  int*   keep    = (int*)(ws + 6709248);              // 2048
  u16*  mfhi  = yhi;            u16* mflo = yhi + 2048*256;   // pre-loop alias
  u16*  phhi  = athi;           u16* phlo = athi + 2048*128;  // pre-loop alias
  int*   flag = (int*)(ws + 6711296);

  k_detect   <<<1, 256, 0, stream>>>((const u16*)pts, flag);
  k_normalize<<<NB, 256, 0, stream>>>(pts, xn, flag);
  k_keep     <<<NB, 256, 0, stream>>>(noise, keep, flag);
  k_fps      <<<NB, 512, 0, stream>>>(xn, centers);
  k_knn      <<<NB*NLK, 256, 0, stream>>>(xn, centers, keep, patches);
  k_embed    <<<NB*NLK, 256, 0, stream>>>(patches, centers, keep,
      pe_w1, pe_b1, pe_w2, pe_b2, pos_w1, pos_b1,
      mfhi, mflo, phhi, phlo, flag);
  k_transpose<<<dim3(12, 8), 256, 0, stream>>>(pe_w3, 0, 256, 384, wthi, wtlo, 0, flag);
  k_transpose<<<dim3(12, 4), 256, 0, stream>>>(pos_w2, 0, 128, 384, wthi, wtlo, 98304, flag);
  k_gemm_mfma<64,64,0,false,false><<<dim3(6,32), 256, 0, stream>>>(
      mfhi, mflo, wthi, wtlo, 0, pe_b3, 0, flag, nullptr, h, nullptr, nullptr, 384, 256);
  k_gemm_mfma<64,64,0,true ,false><<<dim3(6,32), 256, 0, stream>>>(
      phhi, phlo, wthi, wtlo, 98304, pos_b2, 0, flag, h, h, nullptr, nullptr, 384, 128);

  for(int l=0; l<NL; l++){
    k_transpose4<<<1728, 256, 0, stream>>>(wqkv, wo, wi, wo2, l, wthi, wtlo, flag);

    k_ln_split<<<MM, 128, 0, stream>>>(h, ln1, (size_t)l*2*ND, yhi, ylo, flag);
    k_gemm_mfma<64,64,0,false,false><<<dim3(18,32), 256, 0, stream>>>(
        yhi, ylo, wthi, wtlo, 0, bqkv, (size_t)l*1152, flag, nullptr, qkvb, nullptr, nullptr, 1152, 384);
    k_attn_pl<<<NB*NH, 256, 0, stream>>>(qkvb, athi, atlo);
    k_gemm_mfma<64,64,0,true ,false><<<dim3(6,32), 256, 0, stream>>>(
        athi, atlo, wthi, wtlo, 442368, bo, (size_t)l*384, flag, h, h, nullptr, nullptr, 384, 384);
    k_ln_split<<<MM, 128, 0, stream>>>(h, ln2, (size_t)l*2*ND, yhi, ylo, flag);
    k_gemm_mfma<64,64,1,false,true ><<<dim3(24,32), 256, 0, stream>>>(
        yhi, ylo, wthi, wtlo, 589824, bi, (size_t)l*1536, flag, nullptr, nullptr, ubhi, ublo, 1536, 384);
    k_gemm_mfma<64,64,0,true ,false><<<dim3(6,32), 256, 0, stream>>>(
        ubhi, ublo, wthi, wtlo, 1179648, bo2, (size_t)l*384, flag, h, h, nullptr, nullptr, 384, 1536);
  }
  k_ln<true><<<MM, 128, 0, stream>>>(h, lnf, 0, d_out, flag);
}

// Round 7
// 2315.810 us; speedup vs baseline: 1.9534x; 1.0416x over previous
//
#include <hip/hip_runtime.h>

// Problem constants
#define NPTS 8192
#define NB   32
#define NG   256
#define NK   32
#define ND   384
#define NH   6
#define NLK  64
#define NF   1536
#define NHD  64
#define NL   12
#define MM   2048   // NB*NLK token rows

typedef unsigned short u16;
typedef unsigned long long u64;
typedef __attribute__((ext_vector_type(8))) short short8;   // bf16x8 MFMA frag
typedef __attribute__((ext_vector_type(4))) float f32x4;    // MFMA acc

__device__ __forceinline__ float bf2f(u16 v){
  unsigned int u = ((unsigned int)v) << 16;
  float f; __builtin_memcpy(&f, &u, 4); return f;
}
__device__ __forceinline__ float ldf(const void* p, size_t i, bool bf){
  if(bf) return bf2f(((const u16*)p)[i]);
  return ((const float*)p)[i];
}
__device__ __forceinline__ u16 f2bf(float f){
  unsigned int x; __builtin_memcpy(&x, &f, 4);
  x += 0x7fffu + ((x >> 16) & 1u);
  return (u16)(x >> 16);
}
// split f32 -> (hi, lo) bf16 planes; hi RNE, lo = RNE(residual)
__device__ __forceinline__ void split2(float v, u16& hi, u16& lo){
  hi = f2bf(v);
  lo = f2bf(v - bf2f(hi));
}

// ---------------------------------------------------------------- dtype detect
__global__ __launch_bounds__(256) void k_detect(const u16* __restrict__ pts,
                                                int* __restrict__ flag){
  __shared__ int bad;
  if(threadIdx.x==0) bad=0;
  __syncthreads();
  int hit=0;
  for(int i=threadIdx.x; i<4096; i+=256){
    unsigned e = (pts[i] >> 7) & 0xFFu;
    if(e >= 0x90u) hit=1;
  }
  if(hit) atomicOr(&bad, 1);
  __syncthreads();
  if(threadIdx.x==0) *flag = bad ? 0 : 1;   // 1 = bf16, 0 = f32
}

// ---------------------------------------------------------------- normalize
__device__ __forceinline__ float blockMax256(float v, float* sb, int tid){
  for(int off=32; off; off>>=1) v = fmaxf(v, __shfl_down(v, off));
  __syncthreads();
  if((tid&63)==0) sb[tid>>6] = v;
  __syncthreads();
  return fmaxf(fmaxf(sb[0],sb[1]), fmaxf(sb[2],sb[3]));
}

__global__ __launch_bounds__(256) void k_normalize(const void* __restrict__ pts,
                                                   float* __restrict__ xn,
                                                   const int* __restrict__ flag){
#pragma clang fp contract(off)
  int b = blockIdx.x, tid = threadIdx.x;
  const bool bf = flag[0] != 0;
  __shared__ float sb[4];
  const size_t base = (size_t)b*NPTS*3;
  float mn0=1e30f,mn1=1e30f,mn2=1e30f, mx0=-1e30f,mx1=-1e30f,mx2=-1e30f;
  for(int n=tid; n<NPTS; n+=256){
    float x0=ldf(pts,base+n*3,bf), x1=ldf(pts,base+n*3+1,bf), x2=ldf(pts,base+n*3+2,bf);
    mn0=fminf(mn0,x0); mx0=fmaxf(mx0,x0);
    mn1=fminf(mn1,x1); mx1=fmaxf(mx1,x1);
    mn2=fminf(mn2,x2); mx2=fmaxf(mx2,x2);
  }
  mx0=blockMax256(mx0,sb,tid); mn0=-blockMax256(-mn0,sb,tid);
  mx1=blockMax256(mx1,sb,tid); mn1=-blockMax256(-mn1,sb,tid);
  mx2=blockMax256(mx2,sb,tid); mn2=-blockMax256(-mn2,sb,tid);
  float c0=0.5f*(mn0+mx0), c1=0.5f*(mn1+mx1), c2=0.5f*(mn2+mx2);
  float mr=0.0f;
  for(int n=tid; n<NPTS; n+=256){
    float d0=ldf(pts,base+n*3,bf)-c0, d1=ldf(pts,base+n*3+1,bf)-c1, d2=ldf(pts,base+n*3+2,bf)-c2;
    float nr = sqrtf((d0*d0 + d1*d1) + d2*d2);
    mr = fmaxf(mr, nr);
  }
  float radius = blockMax256(mr, sb, tid);
  float* XO = xn + base;
  for(int n=tid; n<NPTS; n+=256){
    XO[n*3  ] = (ldf(pts,base+n*3  ,bf)-c0)/radius;
    XO[n*3+1] = (ldf(pts,base+n*3+1,bf)-c1)/radius;
    XO[n*3+2] = (ldf(pts,base+n*3+2,bf)-c2)/radius;
  }
}

// ---------------------------------------------------------------- keep
__global__ __launch_bounds__(256) void k_keep(const void* __restrict__ noise,
                                              int* __restrict__ keep,
                                              const int* __restrict__ flag){
  int b = blockIdx.x, g = threadIdx.x;
  const bool bf = flag[0] != 0;
  __shared__ float nv[NG];
  nv[g] = ldf(noise, (size_t)b*NG+g, bf);
  __syncthreads();
  float v = nv[g]; int r = 0;
  for(int j=0; j<NG; j++){
    float u = nv[j];
    r += (u < v) || (u == v && j < g);
  }
  if(r < NLK) keep[b*NLK + r] = g;
}

// ---------------------------------------------------------------- FPS, lean per-iteration
// Inner loop tracks (val,idx) only; cross-wave combine via one packed 64-bit LDS
// atomicMax (key = dist_bits<<32 | (8191-idx): positive-float bit order == value
// order, low field = np argmax first-index tie-break). Winner thread publishes
// coords from registers. 2 barriers/iter.
__global__ __launch_bounds__(512) void k_fps(const float* __restrict__ xn,
                                             float* __restrict__ centers){
#pragma clang fp contract(off)
  int b = blockIdx.x, tid = threadIdx.x;
  int lane = tid & 63;
  const float* X = xn + (size_t)b*NPTS*3;
  float px[16],py[16],pz[16],dd[16];
  for(int s=0;s<16;s++){
    int n = s*512 + tid;
    px[s]=X[n*3]; py[s]=X[n*3+1]; pz[s]=X[n*3+2];
    dd[s]=1e10f;
  }
  __shared__ u64 skey[2];
  __shared__ float fxyz[3];
  __shared__ int sc[NG];
  if(tid==0){ skey[0]=0ull; skey[1]=0ull; sc[0]=0; }
  __syncthreads();
  float lx = X[0], ly = X[1], lz = X[2];   // same-address -> broadcast
  for(int i=1;i<NG;i++){
    int c = i & 1;
    float bv=-1.0f; int bn=0;
    for(int s=0;s<16;s++){
      float dx=px[s]-lx, dy=py[s]-ly, dz=pz[s]-lz;
      float d=(dx*dx + dy*dy) + dz*dz;
      d = fminf(dd[s], d); dd[s]=d;
      if(d > bv){ bv=d; bn=s*512+tid; }   // strict >: first index on ties
    }
    for(int off=32;off;off>>=1){
      float ov=__shfl_down(bv,off); int on=__shfl_down(bn,off);
      if(ov>bv || (ov==bv && on<bn)){ bv=ov; bn=on; }
    }
    if(lane==0){
      unsigned int db; __builtin_memcpy(&db,&bv,4);
      u64 key = ((u64)db << 32) | (u64)(unsigned)(NPTS-1-bn);
      atomicMax(&skey[c], key);
    }
    __syncthreads();
    u64 k64 = skey[c];
    int n = (NPTS-1) - (int)(k64 & 0xFFFFFFFFull);
    if((n & 511) == tid){
      int s = n >> 9;
      fxyz[0]=px[s]; fxyz[1]=py[s]; fxyz[2]=pz[s];
      sc[i]=n;
    }
    if(tid==0) skey[1-c]=0ull;
    __syncthreads();
    lx=fxyz[0]; ly=fxyz[1]; lz=fxyz[2];
  }
  if(tid < NG){
    int n = sc[tid] & (NPTS-1);
    centers[((size_t)b*NG+tid)*3  ] = X[n*3];
    centers[((size_t)b*NG+tid)*3+1] = X[n*3+1];
    centers[((size_t)b*NG+tid)*3+2] = X[n*3+2];
  }
}

// ---------------------------------------------------------------- kNN select only -> patches
__global__ __launch_bounds__(256) void k_knn(
    const float* __restrict__ xn, const float* __restrict__ centers,
    const int* __restrict__ keep, float* __restrict__ patches)
{
  int blk=blockIdx.x; int b=blk>>6; int j=blk&63; int tid=threadIdx.x;
  __shared__ float sd[NPTS];
  __shared__ int   sel[NK];
  __shared__ float rv[4]; __shared__ int rn[4];
  __shared__ int   sseln;
  int g = keep[b*NLK + j] & (NG-1);
  const float* C = centers + ((size_t)b*NG + g)*3;
  float c0=C[0], c1=C[1], c2=C[2];
  const float* X = xn + (size_t)b*NPTS*3;
  {
#pragma clang fp contract(off)
    float cc = (c0*c0 + c1*c1) + c2*c2;
    for(int n=tid; n<NPTS; n+=256){
      float x0=X[n*3], x1=X[n*3+1], x2=X[n*3+2];
      float xx=(x0*x0 + x1*x1) + x2*x2;
      float dt=(c0*x0 + c1*x1) + c2*x2;
      sd[n] = (cc + xx) - 2.0f*dt;
    }
  }
  __syncthreads();
  float dl[32];
  for(int s=0;s<32;s++) dl[s] = sd[s*256 + tid];
  unsigned int alive = 0xffffffffu;
  for(int r=0; r<NK; r++){
    float bv=1e30f; int bn=0x7fffffff;
    for(int s=0;s<32;s++){
      if(alive & (1u<<s)){
        float v = dl[s];
        if(v < bv){ bv=v; bn=s*256+tid; }
      }
    }
    for(int off=32;off;off>>=1){
      float ov=__shfl_down(bv,off); int on=__shfl_down(bn,off);
      if(ov<bv || (ov==bv && on<bn)){ bv=ov; bn=on; }
    }
    if((tid&63)==0){ rv[tid>>6]=bv; rn[tid>>6]=bn; }
    __syncthreads();
    if(tid==0){
      float v=rv[0]; int n=rn[0];
      for(int w=1;w<4;w++) if(rv[w]<v || (rv[w]==v && rn[w]<n)){ v=rv[w]; n=rn[w]; }
      n &= (NPTS-1);
      sseln=n; sel[r]=n;
    }
    __syncthreads();
    int n = sseln;
    if((n & 255) == tid) alive &= ~(1u << (n >> 8));
  }
  __syncthreads();
  if(tid < NK){
    int n = sel[tid] & (NPTS-1);
    float* P = patches + ((size_t)(b*NLK+j)*NK + tid)*3;
    P[0]=X[n*3  ]-c0;
    P[1]=X[n*3+1]-c1;
    P[2]=X[n*3+2]-c2;
  }
}

// ---------------------------------------------------------------- embed: f1,f2,maxpool + pos hidden -> bf16 planes
__global__ __launch_bounds__(256) void k_embed(
    const float* __restrict__ patches, const float* __restrict__ centers,
    const int* __restrict__ keep,
    const void* __restrict__ w1, const void* __restrict__ b1,
    const void* __restrict__ w2, const void* __restrict__ b2,
    const void* __restrict__ pw1, const void* __restrict__ pb1,
    u16* __restrict__ mfhi, u16* __restrict__ mflo,
    u16* __restrict__ phhi, u16* __restrict__ phlo,
    const int* __restrict__ flag)
{
  int blk=blockIdx.x; int b=blk>>6; int j=blk&63; int tid=threadIdx.x;
  const bool bf = flag[0] != 0;
  __shared__ float pat[NK*3];
  __shared__ __align__(16) float f1t[128*36];   // [jj][k], pitch 36
  int row = b*NLK + j;
  if(tid < NK*3) pat[tid] = patches[(size_t)row*NK*3 + tid];
  __syncthreads();
  for(int i=0;i<16;i++){
    int idx = tid + i*256;
    int k = idx>>7, m = idx&127;
    float v = ldf(b1,m,bf)
            + pat[k*3+0]*ldf(w1,        m,bf)
            + pat[k*3+1]*ldf(w1, 128 + m,bf)
            + pat[k*3+2]*ldf(w1, 256 + m,bf);
    f1t[m*36 + k] = fmaxf(v, 0.0f);
  }
  __syncthreads();
  float acc[NK];
  {
    float bv = ldf(b2, tid, bf);
#pragma unroll
    for(int k=0;k<NK;k++) acc[k]=bv;
  }
  for(int jj=0;jj<128;jj++){
    float wv = ldf(w2, (size_t)jj*256+tid, bf);
    const float* fr = &f1t[jj*36];
#pragma unroll
    for(int k8=0;k8<8;k8++){
      float4 fv = *reinterpret_cast<const float4*>(fr + k8*4);
      acc[k8*4+0] = fmaf(fv.x, wv, acc[k8*4+0]);
      acc[k8*4+1] = fmaf(fv.y, wv, acc[k8*4+1]);
      acc[k8*4+2] = fmaf(fv.z, wv, acc[k8*4+2]);
      acc[k8*4+3] = fmaf(fv.w, wv, acc[k8*4+3]);
    }
  }
  float mx = acc[0];
#pragma unroll
  for(int k=1;k<NK;k++) mx = fmaxf(mx, acc[k]);
  { u16 hi,lo; split2(mx,hi,lo);
    mfhi[(size_t)row*256 + tid]=hi; mflo[(size_t)row*256 + tid]=lo; }
  if(tid < 128){
    int g = keep[b*NLK + j] & (NG-1);
    const float* C = centers + ((size_t)b*NG + g)*3;
    float v = ldf(pb1,tid,bf)
            + C[0]*ldf(pw1,        tid,bf)
            + C[1]*ldf(pw1, 128 + tid,bf)
            + C[2]*ldf(pw1, 256 + tid,bf);
    v = fmaxf(v, 0.0f);
    u16 hi,lo; split2(v,hi,lo);
    phhi[(size_t)row*128 + tid]=hi; phlo[(size_t)row*128 + tid]=lo;
  }
}

// ---------------------------------------------------------------- weight transpose: [K][N] -> [N][K] hi/lo bf16 planes
__global__ __launch_bounds__(256) void k_transpose(const void* __restrict__ W, size_t woff,
    int Kd, int Nd, u16* __restrict__ dhi, u16* __restrict__ dlo, size_t doff,
    const int* __restrict__ flag){
  __shared__ float t[32][33];
  const bool bf = flag[0]!=0;
  int n0 = blockIdx.x*32, k0 = blockIdx.y*32;
  for(int i=0;i<4;i++){
    int idx = threadIdx.x + i*256; int kr = idx>>5, nc = idx&31;
    t[kr][nc] = ldf(W, woff + (size_t)(k0+kr)*Nd + n0+nc, bf);
  }
  __syncthreads();
  for(int i=0;i<4;i++){
    int idx = threadIdx.x + i*256; int nr = idx>>5, kc = idx&31;
    float v = t[kc][nr];
    u16 hi,lo; split2(v,hi,lo);
    size_t o = doff + (size_t)(n0+nr)*Kd + k0+kc;
    dhi[o]=hi; dlo[o]=lo;
  }
}

// ---------------------------------------------------------------- batched per-layer transpose: wqkv|wo|wi|wo2 in one launch
__global__ __launch_bounds__(256) void k_transpose4(
    const void* __restrict__ wqkv, const void* __restrict__ wo,
    const void* __restrict__ wi,   const void* __restrict__ wo2,
    int l, u16* __restrict__ dhi, u16* __restrict__ dlo,
    const int* __restrict__ flag){
  __shared__ float t[32][33];
  const bool bf = flag[0]!=0;
  int id = blockIdx.x;
  const void* W; int Kd, Nd; size_t woff, doff; int local;
  if(id < 432){        W=wqkv; Kd=384;  Nd=1152; woff=(size_t)l*442368; doff=0;       local=id; }
  else if(id < 576){   W=wo;   Kd=384;  Nd=384;  woff=(size_t)l*147456; doff=442368;  local=id-432; }
  else if(id < 1152){  W=wi;   Kd=384;  Nd=1536; woff=(size_t)l*589824; doff=589824;  local=id-576; }
  else {               W=wo2;  Kd=1536; Nd=384;  woff=(size_t)l*589824; doff=1179648; local=id-1152; }
  int ntiles = Nd >> 5;
  int n0 = (local % ntiles)*32, k0 = (local / ntiles)*32;
  for(int i=0;i<4;i++){
    int idx = threadIdx.x + i*256; int kr = idx>>5, nc = idx&31;
    t[kr][nc] = ldf(W, woff + (size_t)(k0+kr)*Nd + n0+nc, bf);
  }
  __syncthreads();
  for(int i=0;i<4;i++){
    int idx = threadIdx.x + i*256; int nr = idx>>5, kc = idx&31;
    float v = t[kc][nr];
    u16 hi,lo; split2(v,hi,lo);
    size_t o = doff + (size_t)(n0+nr)*Kd + k0+kc;
    dhi[o]=hi; dlo[o]=lo;
  }
}

// ---------------------------------------------------------------- LayerNorm -> bf16 hi/lo planes
__global__ __launch_bounds__(128) void k_ln_split(const float* __restrict__ X,
                                                  const void* __restrict__ gb, size_t go,
                                                  u16* __restrict__ Yhi, u16* __restrict__ Ylo,
                                                  const int* __restrict__ flag){
  int row=blockIdx.x, tid=threadIdx.x;
  const bool bf = flag[0] != 0;
  const float* x = X + (size_t)row*ND;
  __shared__ float sbuf[2];
  float v0=x[tid], v1=x[tid+128], v2=x[tid+256];
  float s = v0+v1+v2;
  for(int off=32;off;off>>=1) s += __shfl_down(s,off);
  if((tid&63)==0) sbuf[tid>>6]=s;
  __syncthreads();
  float mean = (sbuf[0]+sbuf[1]) * (1.0f/(float)ND);
  __syncthreads();
  float d0=v0-mean, d1=v1-mean, d2=v2-mean;
  s = d0*d0 + d1*d1 + d2*d2;
  for(int off=32;off;off>>=1) s += __shfl_down(s,off);
  if((tid&63)==0) sbuf[tid>>6]=s;
  __syncthreads();
  float var = (sbuf[0]+sbuf[1]) * (1.0f/(float)ND);
  float rstd = 1.0f / sqrtf(var + 1e-5f);
  float o0 = d0*rstd*ldf(gb,go+tid    ,bf) + ldf(gb,go+ND+tid    ,bf);
  float o1 = d1*rstd*ldf(gb,go+tid+128,bf) + ldf(gb,go+ND+tid+128,bf);
  float o2 = d2*rstd*ldf(gb,go+tid+256,bf) + ldf(gb,go+ND+tid+256,bf);
  u16 hi,lo; size_t rb = (size_t)row*ND;
  split2(o0,hi,lo); Yhi[rb+tid    ]=hi; Ylo[rb+tid    ]=lo;
  split2(o1,hi,lo); Yhi[rb+tid+128]=hi; Ylo[rb+tid+128]=lo;
  split2(o2,hi,lo); Yhi[rb+tid+256]=hi; Ylo[rb+tid+256]=lo;
}

// ---------------------------------------------------------------- MFMA GEMM, bf16x3 split precision
template<int TM, int TN, int ACT, bool RES, bool OSPLIT>
__global__ __launch_bounds__(256) void k_gemm_mfma(
    const u16* __restrict__ Ahi, const u16* __restrict__ Alo,
    const u16* __restrict__ Whi, const u16* __restrict__ Wlo, size_t wo,
    const void* __restrict__ bias, size_t bo, const int* __restrict__ flag,
    const float* __restrict__ res, float* __restrict__ Cf,
    u16* __restrict__ Ohi, u16* __restrict__ Olo,
    int N, int K)
{
  constexpr int MT = TM/32, NT = TN/32;
  __shared__ __align__(16) u16 sAh[TM*40];
  __shared__ __align__(16) u16 sAl[TM*40];
  __shared__ __align__(16) u16 sBh[TN*40];
  __shared__ __align__(16) u16 sBl[TN*40];
  int tid = threadIdx.x;
  int wave = tid >> 6, lane = tid & 63;
  int wm = wave >> 1, wn = wave & 1;
  int q = lane >> 4, l15 = lane & 15;
  int row0 = blockIdx.y*TM, col0 = blockIdx.x*TN;
  const bool bf = flag[0] != 0;
  f32x4 acc[MT][NT];
#pragma unroll
  for(int m=0;m<MT;m++)
#pragma unroll
    for(int n=0;n<NT;n++){ acc[m][n][0]=0.f; acc[m][n][1]=0.f; acc[m][n][2]=0.f; acc[m][n][3]=0.f; }

  for(int k0=0; k0<K; k0+=32){
#pragma unroll
    for(int i=0;i<TM/32;i++){
      int idx = tid + i*256; int r = idx>>3, c = (idx&7)*4;
      size_t ga = (size_t)(row0+r)*K + k0 + c;
      *reinterpret_cast<uint2*>(&sAh[r*40+c]) = *reinterpret_cast<const uint2*>(&Ahi[ga]);
      *reinterpret_cast<uint2*>(&sAl[r*40+c]) = *reinterpret_cast<const uint2*>(&Alo[ga]);
    }
#pragma unroll
    for(int i=0;i<TN/32;i++){
      int idx = tid + i*256; int r = idx>>3, c = (idx&7)*4;
      size_t ga = wo + (size_t)(col0+r)*K + k0 + c;
      *reinterpret_cast<uint2*>(&sBh[r*40+c]) = *reinterpret_cast<const uint2*>(&Whi[ga]);
      *reinterpret_cast<uint2*>(&sBl[r*40+c]) = *reinterpret_cast<const uint2*>(&Wlo[ga]);
    }
    __syncthreads();
    short8 ah[MT], al[MT], bh[NT], bl[NT];
#pragma unroll
    for(int m=0;m<MT;m++){
      int r = wm*(TM/2) + m*16 + l15;
      ah[m] = *reinterpret_cast<const short8*>(&sAh[r*40 + q*8]);
      al[m] = *reinterpret_cast<const short8*>(&sAl[r*40 + q*8]);
    }
#pragma unroll
    for(int n=0;n<NT;n++){
      int r = wn*(TN/2) + n*16 + l15;
      bh[n] = *reinterpret_cast<const short8*>(&sBh[r*40 + q*8]);
      bl[n] = *reinterpret_cast<const short8*>(&sBl[r*40 + q*8]);
    }
#pragma unroll
    for(int m=0;m<MT;m++)
#pragma unroll
      for(int n=0;n<NT;n++){
        acc[m][n] = __builtin_amdgcn_mfma_f32_16x16x32_bf16(ah[m], bh[n], acc[m][n],0,0,0);
        acc[m][n] = __builtin_amdgcn_mfma_f32_16x16x32_bf16(ah[m], bl[n], acc[m][n],0,0,0);
        acc[m][n] = __builtin_amdgcn_mfma_f32_16x16x32_bf16(al[m], bh[n], acc[m][n],0,0,0);
      }
    __syncthreads();
  }
#pragma unroll
  for(int m=0;m<MT;m++){
    int rbase = row0 + wm*(TM/2) + m*16 + q*4;
#pragma unroll
    for(int n=0;n<NT;n++){
      int col = col0 + wn*(TN/2) + n*16 + l15;
      float bv = ldf(bias, bo+col, bf);
#pragma unroll
      for(int r4=0;r4<4;r4++){
        int rr = rbase + r4;
        float v = acc[m][n][r4] + bv;
        if(ACT==1){
          float xx = v;
          v = 0.5f*xx*(1.0f + tanhf(0.7978845608028654f*(xx + 0.044715f*xx*xx*xx)));
        }
        if(RES) v += res[(size_t)rr*N + col];
        if(OSPLIT){
          u16 hi,lo; split2(v,hi,lo);
          Ohi[(size_t)rr*N + col]=hi; Olo[(size_t)rr*N + col]=lo;
        }else{
          Cf[(size_t)rr*N + col]=v;
        }
      }
    }
  }
}

// ---------------------------------------------------------------- attention (f32 math) -> bf16 planes
__global__ __launch_bounds__(256) void k_attn_pl(const float* __restrict__ qkv,
                                                 u16* __restrict__ ohi,
                                                 u16* __restrict__ olo){
  __shared__ float Q[64*65];
  __shared__ float Kb[64*65];
  __shared__ float V[64*65];
  int blk=blockIdx.x; int b=blk/NH, h=blk%NH;
  int tid=threadIdx.x;
  for(int idx=tid; idx<4096; idx+=256){
    int s=idx>>6, d=idx&63;
    const float* r = qkv + ((size_t)(b*NLK+s))*1152 + h*NHD + d;
    Q [s*65+d]=r[0];
    Kb[s*65+d]=r[384];
    V [s*65+d]=r[768];
  }
  __syncthreads();
  float sc[16];
  for(int t=0;t<16;t++){
    int idx=t*256+tid; int i=idx>>6, jj=idx&63;
    float acc=0.0f;
    for(int d=0;d<64;d++) acc = fmaf(Q[i*65+d], Kb[jj*65+d], acc);
    sc[t]=acc*0.125f;
  }
  __syncthreads();
  for(int t=0;t<16;t++){
    int idx=t*256+tid; int i=idx>>6, jj=idx&63;
    Q[i*65+jj]=sc[t];
  }
  __syncthreads();
  if(tid<64){
    float* rowp=&Q[tid*65];
    float m=rowp[0];
    for(int j=1;j<64;j++) m=fmaxf(m,rowp[j]);
    float sum=0.0f;
    for(int j=0;j<64;j++){ float e=__expf(rowp[j]-m); rowp[j]=e; sum+=e; }
    for(int j=0;j<64;j++) rowp[j]/=sum;
  }
  __syncthreads();
  for(int idx=tid; idx<4096; idx+=256){
    int s=idx>>6, d=idx&63;
    float acc=0.0f;
    for(int t=0;t<64;t++) acc=fmaf(Q[s*65+t], V[t*65+d], acc);
    size_t o = ((size_t)(b*NLK+s))*ND + h*NHD + d;
    u16 hi,lo; split2(acc,hi,lo);
    ohi[o]=hi; olo[o]=lo;
  }
}

// ---------------------------------------------------------------- final LayerNorm (output)
template<bool FINAL>
__global__ __launch_bounds__(128) void k_ln(const float* __restrict__ X,
                                            const void* __restrict__ gb, size_t go,
                                            void* __restrict__ Y,
                                            const int* __restrict__ flag){
  int row=blockIdx.x, tid=threadIdx.x;
  const bool bf = flag[0] != 0;
  const float* x = X + (size_t)row*ND;
  __shared__ float sbuf[2];
  float v0=x[tid], v1=x[tid+128], v2=x[tid+256];
  float s = v0+v1+v2;
  for(int off=32;off;off>>=1) s += __shfl_down(s,off);
  if((tid&63)==0) sbuf[tid>>6]=s;
  __syncthreads();
  float mean = (sbuf[0]+sbuf[1]) * (1.0f/(float)ND);
  __syncthreads();
  float d0=v0-mean, d1=v1-mean, d2=v2-mean;
  s = d0*d0 + d1*d1 + d2*d2;
  for(int off=32;off;off>>=1) s += __shfl_down(s,off);
  if((tid&63)==0) sbuf[tid>>6]=s;
  __syncthreads();
  float var = (sbuf[0]+sbuf[1]) * (1.0f/(float)ND);
  float rstd = 1.0f / sqrtf(var + 1e-5f);
  float o0 = d0*rstd*ldf(gb,go+tid    ,bf) + ldf(gb,go+ND+tid    ,bf);
  float o1 = d1*rstd*ldf(gb,go+tid+128,bf) + ldf(gb,go+ND+tid+128,bf);
  float o2 = d2*rstd*ldf(gb,go+tid+256,bf) + ldf(gb,go+ND+tid+256,bf);
  if(FINAL && bf){
    u16* yo = (u16*)Y + (size_t)row*ND;
    yo[tid]=f2bf(o0); yo[tid+128]=f2bf(o1); yo[tid+256]=f2bf(o2);
  }else{
    float* yo = (float*)Y + (size_t)row*ND;
    yo[tid]=o0; yo[tid+128]=o1; yo[tid+256]=o2;
  }
}

// ---------------------------------------------------------------- host
extern "C" void kernel_launch(void* const* d_in, const int* in_sizes, int n_in,
                              void* d_out, int out_size, void* d_ws, size_t ws_size,
                              hipStream_t stream){
  (void)in_sizes; (void)n_in; (void)out_size;
  const void* pts   = d_in[0];
  const void* noise = d_in[1];
  const void* pe_w1 = d_in[2];
  const void* pe_b1 = d_in[3];
  const void* pe_w2 = d_in[4];
  const void* pe_b2 = d_in[5];
  const void* pe_w3 = d_in[6];
  const void* pe_b3 = d_in[7];
  const void* pos_w1= d_in[8];
  const void* pos_b1= d_in[9];
  const void* pos_w2= d_in[10];
  const void* pos_b2= d_in[11];
  const void* ln1   = d_in[12];
  const void* wqkv  = d_in[13];
  const void* bqkv  = d_in[14];
  const void* wo    = d_in[15];
  const void* bo    = d_in[16];
  const void* ln2   = d_in[17];
  const void* wi    = d_in[18];
  const void* bi    = d_in[19];
  const void* wo2   = d_in[20];
  const void* bo2   = d_in[21];
  const void* lnf   = d_in[22];

  const size_t needed_new = (6711296ull + 16) * 4;   // ~26.9 MB
  if (ws_size < needed_new) return;

  float* ws   = (float*)d_ws;
  float* h    = ws;                                   // 786432
  u16*  yhi   = (u16*)(ws + 786432);                  // planes 2048x384
  u16*  ylo   = yhi + 786432;
  float* qkvb = ws + 1572864;                         // 2359296 f32
  u16*  athi  = (u16*)(ws + 3932160);                 // planes 2048x384
  u16*  atlo  = athi + 786432;
  u16*  ubhi  = (u16*)(ws + 1572864);                 // planes 2048x1536 (alias qkvb+attb)
  u16*  ublo  = ubhi + 3145728;
  float* xn   = ws + 1572864;                         // pre-loop alias
  u16*  wthi  = (u16*)(ws + 4718592);                 // 1769472 u16 per plane
  u16*  wtlo  = wthi + 1769472;
  float* patches = ws + 6488064;                      // 196608
  float* centers = ws + 6684672;                      // 24576
  int*   keep    = (int*)(ws + 6709248);              // 2048
  u16*  mfhi  = yhi;            u16* mflo = yhi + 2048*256;   // pre-loop alias
  u16*  phhi  = athi;           u16* phlo = athi + 2048*128;  // pre-loop alias
  int*   flag = (int*)(ws + 6711296);

  k_detect   <<<1, 256, 0, stream>>>((const u16*)pts, flag);
  k_normalize<<<NB, 256, 0, stream>>>(pts, xn, flag);
  k_keep     <<<NB, 256, 0, stream>>>(noise, keep, flag);
  k_fps      <<<NB, 512, 0, stream>>>(xn, centers);
  k_knn      <<<NB*NLK, 256, 0, stream>>>(xn, centers, keep, patches);
  k_embed    <<<NB*NLK, 256, 0, stream>>>(patches, centers, keep,
      pe_w1, pe_b1, pe_w2, pe_b2, pos_w1, pos_b1,
      mfhi, mflo, phhi, phlo, flag);
  k_transpose<<<dim3(12, 8), 256, 0, stream>>>(pe_w3, 0, 256, 384, wthi, wtlo, 0, flag);
  k_transpose<<<dim3(12, 4), 256, 0, stream>>>(pos_w2, 0, 128, 384, wthi, wtlo, 98304, flag);
  k_gemm_mfma<64,64,0,false,false><<<dim3(6,32), 256, 0, stream>>>(
      mfhi, mflo, wthi, wtlo, 0, pe_b3, 0, flag, nullptr, h, nullptr, nullptr, 384, 256);
  k_gemm_mfma<64,64,0,true ,false><<<dim3(6,32), 256, 0, stream>>>(
      phhi, phlo, wthi, wtlo, 98304, pos_b2, 0, flag, h, h, nullptr, nullptr, 384, 128);

  for(int l=0; l<NL; l++){
    k_transpose4<<<1728, 256, 0, stream>>>(wqkv, wo, wi, wo2, l, wthi, wtlo, flag);

    k_ln_split<<<MM, 128, 0, stream>>>(h, ln1, (size_t)l*2*ND, yhi, ylo, flag);
    k_gemm_mfma<64,64,0,false,false><<<dim3(18,32), 256, 0, stream>>>(
        yhi, ylo, wthi, wtlo, 0, bqkv, (size_t)l*1152, flag, nullptr, qkvb, nullptr, nullptr, 1152, 384);
    k_attn_pl<<<NB*NH, 256, 0, stream>>>(qkvb, athi, atlo);
    k_gemm_mfma<64,64,0,true ,false><<<dim3(6,32), 256, 0, stream>>>(
        athi, atlo, wthi, wtlo, 442368, bo, (size_t)l*384, flag, h, h, nullptr, nullptr, 384, 384);
    k_ln_split<<<MM, 128, 0, stream>>>(h, ln2, (size_t)l*2*ND, yhi, ylo, flag);
    k_gemm_mfma<64,64,1,false,true ><<<dim3(24,32), 256, 0, stream>>>(
        yhi, ylo, wthi, wtlo, 589824, bi, (size_t)l*1536, flag, nullptr, nullptr, ubhi, ublo, 1536, 384);
    k_gemm_mfma<64,64,0,true ,false><<<dim3(6,32), 256, 0, stream>>>(
        ubhi, ublo, wthi, wtlo, 1179648, bo2, (size_t)l*384, flag, h, h, nullptr, nullptr, 384, 1536);
  }
  k_ln<true><<<MM, 128, 0, stream>>>(h, lnf, 0, d_out, flag);
}

// Round 8
// 2217.112 us; speedup vs baseline: 2.0404x; 1.0445x over previous
//
#include <hip/hip_runtime.h>

// Problem constants
#define NPTS 8192
#define NB   32
#define NG   256
#define NK   32
#define ND   384
#define NH   6
#define NLK  64
#define NF   1536
#define NHD  64
#define NL   12
#define MM   2048   // NB*NLK token rows

typedef unsigned short u16;
typedef unsigned long long u64;
typedef __attribute__((ext_vector_type(8))) short short8;   // bf16x8 MFMA frag
typedef __attribute__((ext_vector_type(4))) float f32x4;    // MFMA acc

__device__ __forceinline__ float bf2f(u16 v){
  unsigned int u = ((unsigned int)v) << 16;
  float f; __builtin_memcpy(&f, &u, 4); return f;
}
__device__ __forceinline__ float ldf(const void* p, size_t i, bool bf){
  if(bf) return bf2f(((const u16*)p)[i]);
  return ((const float*)p)[i];
}
__device__ __forceinline__ u16 f2bf(float f){
  unsigned int x; __builtin_memcpy(&x, &f, 4);
  x += 0x7fffu + ((x >> 16) & 1u);
  return (u16)(x >> 16);
}
// split f32 -> (hi, lo) bf16 planes; hi RNE, lo = RNE(residual)
__device__ __forceinline__ void split2(float v, u16& hi, u16& lo){
  hi = f2bf(v);
  lo = f2bf(v - bf2f(hi));
}

// ---------------------------------------------------------------- dtype detect
__global__ __launch_bounds__(256) void k_detect(const u16* __restrict__ pts,
                                                int* __restrict__ flag){
  __shared__ int bad;
  if(threadIdx.x==0) bad=0;
  __syncthreads();
  int hit=0;
  for(int i=threadIdx.x; i<4096; i+=256){
    unsigned e = (pts[i] >> 7) & 0xFFu;
    if(e >= 0x90u) hit=1;
  }
  if(hit) atomicOr(&bad, 1);
  __syncthreads();
  if(threadIdx.x==0) *flag = bad ? 0 : 1;   // 1 = bf16, 0 = f32
}

// ---------------------------------------------------------------- normalize
__device__ __forceinline__ float blockMax256(float v, float* sb, int tid){
  for(int off=32; off; off>>=1) v = fmaxf(v, __shfl_down(v, off));
  __syncthreads();
  if((tid&63)==0) sb[tid>>6] = v;
  __syncthreads();
  return fmaxf(fmaxf(sb[0],sb[1]), fmaxf(sb[2],sb[3]));
}

__global__ __launch_bounds__(256) void k_normalize(const void* __restrict__ pts,
                                                   float* __restrict__ xn,
                                                   const int* __restrict__ flag){
#pragma clang fp contract(off)
  int b = blockIdx.x, tid = threadIdx.x;
  const bool bf = flag[0] != 0;
  __shared__ float sb[4];
  const size_t base = (size_t)b*NPTS*3;
  float mn0=1e30f,mn1=1e30f,mn2=1e30f, mx0=-1e30f,mx1=-1e30f,mx2=-1e30f;
  for(int n=tid; n<NPTS; n+=256){
    float x0=ldf(pts,base+n*3,bf), x1=ldf(pts,base+n*3+1,bf), x2=ldf(pts,base+n*3+2,bf);
    mn0=fminf(mn0,x0); mx0=fmaxf(mx0,x0);
    mn1=fminf(mn1,x1); mx1=fmaxf(mx1,x1);
    mn2=fminf(mn2,x2); mx2=fmaxf(mx2,x2);
  }
  mx0=blockMax256(mx0,sb,tid); mn0=-blockMax256(-mn0,sb,tid);
  mx1=blockMax256(mx1,sb,tid); mn1=-blockMax256(-mn1,sb,tid);
  mx2=blockMax256(mx2,sb,tid); mn2=-blockMax256(-mn2,sb,tid);
  float c0=0.5f*(mn0+mx0), c1=0.5f*(mn1+mx1), c2=0.5f*(mn2+mx2);
  float mr=0.0f;
  for(int n=tid; n<NPTS; n+=256){
    float d0=ldf(pts,base+n*3,bf)-c0, d1=ldf(pts,base+n*3+1,bf)-c1, d2=ldf(pts,base+n*3+2,bf)-c2;
    float nr = sqrtf((d0*d0 + d1*d1) + d2*d2);
    mr = fmaxf(mr, nr);
  }
  float radius = blockMax256(mr, sb, tid);
  float* XO = xn + base;
  for(int n=tid; n<NPTS; n+=256){
    XO[n*3  ] = (ldf(pts,base+n*3  ,bf)-c0)/radius;
    XO[n*3+1] = (ldf(pts,base+n*3+1,bf)-c1)/radius;
    XO[n*3+2] = (ldf(pts,base+n*3+2,bf)-c2)/radius;
  }
}

// ---------------------------------------------------------------- keep
__global__ __launch_bounds__(256) void k_keep(const void* __restrict__ noise,
                                              int* __restrict__ keep,
                                              const int* __restrict__ flag){
  int b = blockIdx.x, g = threadIdx.x;
  const bool bf = flag[0] != 0;
  __shared__ float nv[NG];
  nv[g] = ldf(noise, (size_t)b*NG+g, bf);
  __syncthreads();
  float v = nv[g]; int r = 0;
  for(int j=0; j<NG; j++){
    float u = nv[j];
    r += (u < v) || (u == v && j < g);
  }
  if(r < NLK) keep[b*NLK + r] = g;
}

// ---------------------------------------------------------------- FPS
// DPP wave64 max-reduce on packed (dist_bits<<32 | 8191-idx) keys (VALU-pipe
// cross-lane, replaces the ds_bpermute shuffle chain), one LDS atomicMax per
// wave, ONE barrier/iter with a 3-slot rotating key buffer, coords read from
// an LDS mirror (same-address broadcast). Selection math bit-identical to np.
__device__ __forceinline__ void kmax_dpp_step(unsigned& hi, unsigned& lo, unsigned oh, unsigned ol){
  bool g = (oh > hi) || (oh == hi && ol > lo);
  hi = g ? oh : hi; lo = g ? ol : lo;
}
#define KMAX_DPP(CTRL) { \
  unsigned oh=(unsigned)__builtin_amdgcn_update_dpp(0,(int)kh,(CTRL),0xf,0xf,true); \
  unsigned ol=(unsigned)__builtin_amdgcn_update_dpp(0,(int)kl,(CTRL),0xf,0xf,true); \
  kmax_dpp_step(kh,kl,oh,ol); }

__global__ __launch_bounds__(512) void k_fps(const float* __restrict__ xn,
                                             float* __restrict__ centers){
#pragma clang fp contract(off)
  int b = blockIdx.x, tid = threadIdx.x;
  int lane = tid & 63;
  const float* X = xn + (size_t)b*NPTS*3;
  __shared__ float xs[NPTS*3];   // 96 KB coord mirror
  __shared__ u64 skey[3];
  __shared__ int sc[NG];
  float px[16],py[16],pz[16],dd[16];
#pragma unroll
  for(int s=0;s<16;s++){
    int n = s*512 + tid;
    px[s]=X[n*3]; py[s]=X[n*3+1]; pz[s]=X[n*3+2];
    dd[s]=1e10f;
  }
  for(int i=tid; i<NPTS*3; i+=512) xs[i] = X[i];
  if(tid==0){ skey[0]=0ull; skey[1]=0ull; skey[2]=0ull; sc[0]=0; }
  __syncthreads();
  float lx = xs[0], ly = xs[1], lz = xs[2];
  for(int i=1;i<NG;i++){
    int c = i % 3;
    float bv=-1.0f; int bs=0;
#pragma unroll
    for(int s=0;s<16;s++){
      float dx=px[s]-lx, dy=py[s]-ly, dz=pz[s]-lz;
      float d=(dx*dx + dy*dy) + dz*dz;
      d = fminf(dd[s], d); dd[s]=d;
      if(d > bv){ bv=d; bs=s; }   // strict >: first index on ties (s ascending = idx ascending)
    }
    int bn = bs*512 + tid;
    unsigned kh; __builtin_memcpy(&kh,&bv,4);
    unsigned kl = (unsigned)(NPTS-1-bn);
    KMAX_DPP(0x111)   // row_shr:1
    KMAX_DPP(0x112)   // row_shr:2
    KMAX_DPP(0x114)   // row_shr:4
    KMAX_DPP(0x118)   // row_shr:8
    KMAX_DPP(0x142)   // row_bcast:15
    KMAX_DPP(0x143)   // row_bcast:31  -> lane 63 has wave max
    if(lane==63) atomicMax(&skey[c], ((u64)kh<<32) | (u64)kl);
    __syncthreads();
    u64 k64 = skey[c];
    int n = (NPTS-1) - (int)(k64 & 0xFFFFFFFFull);
    n &= (NPTS-1);
    if(tid==0){ sc[i]=n; skey[(i+2)%3]=0ull; }
    lx = xs[n*3]; ly = xs[n*3+1]; lz = xs[n*3+2];
  }
  __syncthreads();
  if(tid < NG){
    int n = sc[tid] & (NPTS-1);
    centers[((size_t)b*NG+tid)*3  ] = xs[n*3];
    centers[((size_t)b*NG+tid)*3+1] = xs[n*3+1];
    centers[((size_t)b*NG+tid)*3+2] = xs[n*3+2];
  }
}

// ---------------------------------------------------------------- kNN select only -> patches
__global__ __launch_bounds__(256) void k_knn(
    const float* __restrict__ xn, const float* __restrict__ centers,
    const int* __restrict__ keep, float* __restrict__ patches)
{
  int blk=blockIdx.x; int b=blk>>6; int j=blk&63; int tid=threadIdx.x;
  __shared__ float sd[NPTS];
  __shared__ int   sel[NK];
  __shared__ float rv[4]; __shared__ int rn[4];
  __shared__ int   sseln;
  int g = keep[b*NLK + j] & (NG-1);
  const float* C = centers + ((size_t)b*NG + g)*3;
  float c0=C[0], c1=C[1], c2=C[2];
  const float* X = xn + (size_t)b*NPTS*3;
  {
#pragma clang fp contract(off)
    float cc = (c0*c0 + c1*c1) + c2*c2;
    for(int n=tid; n<NPTS; n+=256){
      float x0=X[n*3], x1=X[n*3+1], x2=X[n*3+2];
      float xx=(x0*x0 + x1*x1) + x2*x2;
      float dt=(c0*x0 + c1*x1) + c2*x2;
      sd[n] = (cc + xx) - 2.0f*dt;
    }
  }
  __syncthreads();
  float dl[32];
  for(int s=0;s<32;s++) dl[s] = sd[s*256 + tid];
  unsigned int alive = 0xffffffffu;
  for(int r=0; r<NK; r++){
    float bv=1e30f; int bn=0x7fffffff;
    for(int s=0;s<32;s++){
      if(alive & (1u<<s)){
        float v = dl[s];
        if(v < bv){ bv=v; bn=s*256+tid; }
      }
    }
    for(int off=32;off;off>>=1){
      float ov=__shfl_down(bv,off); int on=__shfl_down(bn,off);
      if(ov<bv || (ov==bv && on<bn)){ bv=ov; bn=on; }
    }
    if((tid&63)==0){ rv[tid>>6]=bv; rn[tid>>6]=bn; }
    __syncthreads();
    if(tid==0){
      float v=rv[0]; int n=rn[0];
      for(int w=1;w<4;w++) if(rv[w]<v || (rv[w]==v && rn[w]<n)){ v=rv[w]; n=rn[w]; }
      n &= (NPTS-1);
      sseln=n; sel[r]=n;
    }
    __syncthreads();
    int n = sseln;
    if((n & 255) == tid) alive &= ~(1u << (n >> 8));
  }
  __syncthreads();
  if(tid < NK){
    int n = sel[tid] & (NPTS-1);
    float* P = patches + ((size_t)(b*NLK+j)*NK + tid)*3;
    P[0]=X[n*3  ]-c0;
    P[1]=X[n*3+1]-c1;
    P[2]=X[n*3+2]-c2;
  }
}

// ---------------------------------------------------------------- embed: f1,f2,maxpool + pos hidden -> bf16 planes
__global__ __launch_bounds__(256) void k_embed(
    const float* __restrict__ patches, const float* __restrict__ centers,
    const int* __restrict__ keep,
    const void* __restrict__ w1, const void* __restrict__ b1,
    const void* __restrict__ w2, const void* __restrict__ b2,
    const void* __restrict__ pw1, const void* __restrict__ pb1,
    u16* __restrict__ mfhi, u16* __restrict__ mflo,
    u16* __restrict__ phhi, u16* __restrict__ phlo,
    const int* __restrict__ flag)
{
  int blk=blockIdx.x; int b=blk>>6; int j=blk&63; int tid=threadIdx.x;
  const bool bf = flag[0] != 0;
  __shared__ float pat[NK*3];
  __shared__ __align__(16) float f1t[128*36];   // [jj][k], pitch 36
  int row = b*NLK + j;
  if(tid < NK*3) pat[tid] = patches[(size_t)row*NK*3 + tid];
  __syncthreads();
  for(int i=0;i<16;i++){
    int idx = tid + i*256;
    int k = idx>>7, m = idx&127;
    float v = ldf(b1,m,bf)
            + pat[k*3+0]*ldf(w1,        m,bf)
            + pat[k*3+1]*ldf(w1, 128 + m,bf)
            + pat[k*3+2]*ldf(w1, 256 + m,bf);
    f1t[m*36 + k] = fmaxf(v, 0.0f);
  }
  __syncthreads();
  float acc[NK];
  {
    float bv = ldf(b2, tid, bf);
#pragma unroll
    for(int k=0;k<NK;k++) acc[k]=bv;
  }
  for(int jj=0;jj<128;jj++){
    float wv = ldf(w2, (size_t)jj*256+tid, bf);
    const float* fr = &f1t[jj*36];
#pragma unroll
    for(int k8=0;k8<8;k8++){
      float4 fv = *reinterpret_cast<const float4*>(fr + k8*4);
      acc[k8*4+0] = fmaf(fv.x, wv, acc[k8*4+0]);
      acc[k8*4+1] = fmaf(fv.y, wv, acc[k8*4+1]);
      acc[k8*4+2] = fmaf(fv.z, wv, acc[k8*4+2]);
      acc[k8*4+3] = fmaf(fv.w, wv, acc[k8*4+3]);
    }
  }
  float mx = acc[0];
#pragma unroll
  for(int k=1;k<NK;k++) mx = fmaxf(mx, acc[k]);
  { u16 hi,lo; split2(mx,hi,lo);
    mfhi[(size_t)row*256 + tid]=hi; mflo[(size_t)row*256 + tid]=lo; }
  if(tid < 128){
    int g = keep[b*NLK + j] & (NG-1);
    const float* C = centers + ((size_t)b*NG + g)*3;
    float v = ldf(pb1,tid,bf)
            + C[0]*ldf(pw1,        tid,bf)
            + C[1]*ldf(pw1, 128 + tid,bf)
            + C[2]*ldf(pw1, 256 + tid,bf);
    v = fmaxf(v, 0.0f);
    u16 hi,lo; split2(v,hi,lo);
    phhi[(size_t)row*128 + tid]=hi; phlo[(size_t)row*128 + tid]=lo;
  }
}

// ---------------------------------------------------------------- weight transpose: [K][N] -> [N][K] hi/lo bf16 planes
__global__ __launch_bounds__(256) void k_transpose(const void* __restrict__ W, size_t woff,
    int Kd, int Nd, u16* __restrict__ dhi, u16* __restrict__ dlo, size_t doff,
    const int* __restrict__ flag){
  __shared__ float t[32][33];
  const bool bf = flag[0]!=0;
  int n0 = blockIdx.x*32, k0 = blockIdx.y*32;
  for(int i=0;i<4;i++){
    int idx = threadIdx.x + i*256; int kr = idx>>5, nc = idx&31;
    t[kr][nc] = ldf(W, woff + (size_t)(k0+kr)*Nd + n0+nc, bf);
  }
  __syncthreads();
  for(int i=0;i<4;i++){
    int idx = threadIdx.x + i*256; int nr = idx>>5, kc = idx&31;
    float v = t[kc][nr];
    u16 hi,lo; split2(v,hi,lo);
    size_t o = doff + (size_t)(n0+nr)*Kd + k0+kc;
    dhi[o]=hi; dlo[o]=lo;
  }
}

// ---------------------------------------------------------------- batched per-layer transpose: wqkv|wo|wi|wo2 in one launch
__global__ __launch_bounds__(256) void k_transpose4(
    const void* __restrict__ wqkv, const void* __restrict__ wo,
    const void* __restrict__ wi,   const void* __restrict__ wo2,
    int l, u16* __restrict__ dhi, u16* __restrict__ dlo,
    const int* __restrict__ flag){
  __shared__ float t[32][33];
  const bool bf = flag[0]!=0;
  int id = blockIdx.x;
  const void* W; int Kd, Nd; size_t woff, doff; int local;
  if(id < 432){        W=wqkv; Kd=384;  Nd=1152; woff=(size_t)l*442368; doff=0;       local=id; }
  else if(id < 576){   W=wo;   Kd=384;  Nd=384;  woff=(size_t)l*147456; doff=442368;  local=id-432; }
  else if(id < 1152){  W=wi;   Kd=384;  Nd=1536; woff=(size_t)l*589824; doff=589824;  local=id-576; }
  else {               W=wo2;  Kd=1536; Nd=384;  woff=(size_t)l*589824; doff=1179648; local=id-1152; }
  int ntiles = Nd >> 5;
  int n0 = (local % ntiles)*32, k0 = (local / ntiles)*32;
  for(int i=0;i<4;i++){
    int idx = threadIdx.x + i*256; int kr = idx>>5, nc = idx&31;
    t[kr][nc] = ldf(W, woff + (size_t)(k0+kr)*Nd + n0+nc, bf);
  }
  __syncthreads();
  for(int i=0;i<4;i++){
    int idx = threadIdx.x + i*256; int nr = idx>>5, kc = idx&31;
    float v = t[kc][nr];
    u16 hi,lo; split2(v,hi,lo);
    size_t o = doff + (size_t)(n0+nr)*Kd + k0+kc;
    dhi[o]=hi; dlo[o]=lo;
  }
}

// ---------------------------------------------------------------- LayerNorm -> bf16 hi/lo planes
__global__ __launch_bounds__(128) void k_ln_split(const float* __restrict__ X,
                                                  const void* __restrict__ gb, size_t go,
                                                  u16* __restrict__ Yhi, u16* __restrict__ Ylo,
                                                  const int* __restrict__ flag){
  int row=blockIdx.x, tid=threadIdx.x;
  const bool bf = flag[0] != 0;
  const float* x = X + (size_t)row*ND;
  __shared__ float sbuf[2];
  float v0=x[tid], v1=x[tid+128], v2=x[tid+256];
  float s = v0+v1+v2;
  for(int off=32;off;off>>=1) s += __shfl_down(s,off);
  if((tid&63)==0) sbuf[tid>>6]=s;
  __syncthreads();
  float mean = (sbuf[0]+sbuf[1]) * (1.0f/(float)ND);
  __syncthreads();
  float d0=v0-mean, d1=v1-mean, d2=v2-mean;
  s = d0*d0 + d1*d1 + d2*d2;
  for(int off=32;off;off>>=1) s += __shfl_down(s,off);
  if((tid&63)==0) sbuf[tid>>6]=s;
  __syncthreads();
  float var = (sbuf[0]+sbuf[1]) * (1.0f/(float)ND);
  float rstd = 1.0f / sqrtf(var + 1e-5f);
  float o0 = d0*rstd*ldf(gb,go+tid    ,bf) + ldf(gb,go+ND+tid    ,bf);
  float o1 = d1*rstd*ldf(gb,go+tid+128,bf) + ldf(gb,go+ND+tid+128,bf);
  float o2 = d2*rstd*ldf(gb,go+tid+256,bf) + ldf(gb,go+ND+tid+256,bf);
  u16 hi,lo; size_t rb = (size_t)row*ND;
  split2(o0,hi,lo); Yhi[rb+tid    ]=hi; Ylo[rb+tid    ]=lo;
  split2(o1,hi,lo); Yhi[rb+tid+128]=hi; Ylo[rb+tid+128]=lo;
  split2(o2,hi,lo); Yhi[rb+tid+256]=hi; Ylo[rb+tid+256]=lo;
}

// ---------------------------------------------------------------- MFMA GEMM, bf16x3 split precision
template<int TM, int TN, int ACT, bool RES, bool OSPLIT>
__global__ __launch_bounds__(256) void k_gemm_mfma(
    const u16* __restrict__ Ahi, const u16* __restrict__ Alo,
    const u16* __restrict__ Whi, const u16* __restrict__ Wlo, size_t wo,
    const void* __restrict__ bias, size_t bo, const int* __restrict__ flag,
    const float* __restrict__ res, float* __restrict__ Cf,
    u16* __restrict__ Ohi, u16* __restrict__ Olo,
    int N, int K)
{
  constexpr int MT = TM/32, NT = TN/32;
  __shared__ __align__(16) u16 sAh[TM*40];
  __shared__ __align__(16) u16 sAl[TM*40];
  __shared__ __align__(16) u16 sBh[TN*40];
  __shared__ __align__(16) u16 sBl[TN*40];
  int tid = threadIdx.x;
  int wave = tid >> 6, lane = tid & 63;
  int wm = wave >> 1, wn = wave & 1;
  int q = lane >> 4, l15 = lane & 15;
  int row0 = blockIdx.y*TM, col0 = blockIdx.x*TN;
  const bool bf = flag[0] != 0;
  f32x4 acc[MT][NT];
#pragma unroll
  for(int m=0;m<MT;m++)
#pragma unroll
    for(int n=0;n<NT;n++){ acc[m][n][0]=0.f; acc[m][n][1]=0.f; acc[m][n][2]=0.f; acc[m][n][3]=0.f; }

  for(int k0=0; k0<K; k0+=32){
#pragma unroll
    for(int i=0;i<TM/32;i++){
      int idx = tid + i*256; int r = idx>>3, c = (idx&7)*4;
      size_t ga = (size_t)(row0+r)*K + k0 + c;
      *reinterpret_cast<uint2*>(&sAh[r*40+c]) = *reinterpret_cast<const uint2*>(&Ahi[ga]);
      *reinterpret_cast<uint2*>(&sAl[r*40+c]) = *reinterpret_cast<const uint2*>(&Alo[ga]);
    }
#pragma unroll
    for(int i=0;i<TN/32;i++){
      int idx = tid + i*256; int r = idx>>3, c = (idx&7)*4;
      size_t ga = wo + (size_t)(col0+r)*K + k0 + c;
      *reinterpret_cast<uint2*>(&sBh[r*40+c]) = *reinterpret_cast<const uint2*>(&Whi[ga]);
      *reinterpret_cast<uint2*>(&sBl[r*40+c]) = *reinterpret_cast<const uint2*>(&Wlo[ga]);
    }
    __syncthreads();
    short8 ah[MT], al[MT], bh[NT], bl[NT];
#pragma unroll
    for(int m=0;m<MT;m++){
      int r = wm*(TM/2) + m*16 + l15;
      ah[m] = *reinterpret_cast<const short8*>(&sAh[r*40 + q*8]);
      al[m] = *reinterpret_cast<const short8*>(&sAl[r*40 + q*8]);
    }
#pragma unroll
    for(int n=0;n<NT;n++){
      int r = wn*(TN/2) + n*16 + l15;
      bh[n] = *reinterpret_cast<const short8*>(&sBh[r*40 + q*8]);
      bl[n] = *reinterpret_cast<const short8*>(&sBl[r*40 + q*8]);
    }
#pragma unroll
    for(int m=0;m<MT;m++)
#pragma unroll
      for(int n=0;n<NT;n++){
        acc[m][n] = __builtin_amdgcn_mfma_f32_16x16x32_bf16(ah[m], bh[n], acc[m][n],0,0,0);
        acc[m][n] = __builtin_amdgcn_mfma_f32_16x16x32_bf16(ah[m], bl[n], acc[m][n],0,0,0);
        acc[m][n] = __builtin_amdgcn_mfma_f32_16x16x32_bf16(al[m], bh[n], acc[m][n],0,0,0);
      }
    __syncthreads();
  }
#pragma unroll
  for(int m=0;m<MT;m++){
    int rbase = row0 + wm*(TM/2) + m*16 + q*4;
#pragma unroll
    for(int n=0;n<NT;n++){
      int col = col0 + wn*(TN/2) + n*16 + l15;
      float bv = ldf(bias, bo+col, bf);
#pragma unroll
      for(int r4=0;r4<4;r4++){
        int rr = rbase + r4;
        float v = acc[m][n][r4] + bv;
        if(ACT==1){
          float xx = v;
          v = 0.5f*xx*(1.0f + tanhf(0.7978845608028654f*(xx + 0.044715f*xx*xx*xx)));
        }
        if(RES) v += res[(size_t)rr*N + col];
        if(OSPLIT){
          u16 hi,lo; split2(v,hi,lo);
          Ohi[(size_t)rr*N + col]=hi; Olo[(size_t)rr*N + col]=lo;
        }else{
          Cf[(size_t)rr*N + col]=v;
        }
      }
    }
  }
}

// ---------------------------------------------------------------- attention (f32 math) -> bf16 planes
__global__ __launch_bounds__(256) void k_attn_pl(const float* __restrict__ qkv,
                                                 u16* __restrict__ ohi,
                                                 u16* __restrict__ olo){
  __shared__ float Q[64*65];
  __shared__ float Kb[64*65];
  __shared__ float V[64*65];
  int blk=blockIdx.x; int b=blk/NH, h=blk%NH;
  int tid=threadIdx.x;
  for(int idx=tid; idx<4096; idx+=256){
    int s=idx>>6, d=idx&63;
    const float* r = qkv + ((size_t)(b*NLK+s))*1152 + h*NHD + d;
    Q [s*65+d]=r[0];
    Kb[s*65+d]=r[384];
    V [s*65+d]=r[768];
  }
  __syncthreads();
  float sc[16];
  for(int t=0;t<16;t++){
    int idx=t*256+tid; int i=idx>>6, jj=idx&63;
    float acc=0.0f;
    for(int d=0;d<64;d++) acc = fmaf(Q[i*65+d], Kb[jj*65+d], acc);
    sc[t]=acc*0.125f;
  }
  __syncthreads();
  for(int t=0;t<16;t++){
    int idx=t*256+tid; int i=idx>>6, jj=idx&63;
    Q[i*65+jj]=sc[t];
  }
  __syncthreads();
  if(tid<64){
    float* rowp=&Q[tid*65];
    float m=rowp[0];
    for(int j=1;j<64;j++) m=fmaxf(m,rowp[j]);
    float sum=0.0f;
    for(int j=0;j<64;j++){ float e=__expf(rowp[j]-m); rowp[j]=e; sum+=e; }
    for(int j=0;j<64;j++) rowp[j]/=sum;
  }
  __syncthreads();
  for(int idx=tid; idx<4096; idx+=256){
    int s=idx>>6, d=idx&63;
    float acc=0.0f;
    for(int t=0;t<64;t++) acc=fmaf(Q[s*65+t], V[t*65+d], acc);
    size_t o = ((size_t)(b*NLK+s))*ND + h*NHD + d;
    u16 hi,lo; split2(acc,hi,lo);
    ohi[o]=hi; olo[o]=lo;
  }
}

// ---------------------------------------------------------------- final LayerNorm (output)
template<bool FINAL>
__global__ __launch_bounds__(128) void k_ln(const float* __restrict__ X,
                                            const void* __restrict__ gb, size_t go,
                                            void* __restrict__ Y,
                                            const int* __restrict__ flag){
  int row=blockIdx.x, tid=threadIdx.x;
  const bool bf = flag[0] != 0;
  const float* x = X + (size_t)row*ND;
  __shared__ float sbuf[2];
  float v0=x[tid], v1=x[tid+128], v2=x[tid+256];
  float s = v0+v1+v2;
  for(int off=32;off;off>>=1) s += __shfl_down(s,off);
  if((tid&63)==0) sbuf[tid>>6]=s;
  __syncthreads();
  float mean = (sbuf[0]+sbuf[1]) * (1.0f/(float)ND);
  __syncthreads();
  float d0=v0-mean, d1=v1-mean, d2=v2-mean;
  s = d0*d0 + d1*d1 + d2*d2;
  for(int off=32;off;off>>=1) s += __shfl_down(s,off);
  if((tid&63)==0) sbuf[tid>>6]=s;
  __syncthreads();
  float var = (sbuf[0]+sbuf[1]) * (1.0f/(float)ND);
  float rstd = 1.0f / sqrtf(var + 1e-5f);
  float o0 = d0*rstd*ldf(gb,go+tid    ,bf) + ldf(gb,go+ND+tid    ,bf);
  float o1 = d1*rstd*ldf(gb,go+tid+128,bf) + ldf(gb,go+ND+tid+128,bf);
  float o2 = d2*rstd*ldf(gb,go+tid+256,bf) + ldf(gb,go+ND+tid+256,bf);
  if(FINAL && bf){
    u16* yo = (u16*)Y + (size_t)row*ND;
    yo[tid]=f2bf(o0); yo[tid+128]=f2bf(o1); yo[tid+256]=f2bf(o2);
  }else{
    float* yo = (float*)Y + (size_t)row*ND;
    yo[tid]=o0; yo[tid+128]=o1; yo[tid+256]=o2;
  }
}

// ---------------------------------------------------------------- host
extern "C" void kernel_launch(void* const* d_in, const int* in_sizes, int n_in,
                              void* d_out, int out_size, void* d_ws, size_t ws_size,
                              hipStream_t stream){
  (void)in_sizes; (void)n_in; (void)out_size;
  const void* pts   = d_in[0];
  const void* noise = d_in[1];
  const void* pe_w1 = d_in[2];
  const void* pe_b1 = d_in[3];
  const void* pe_w2 = d_in[4];
  const void* pe_b2 = d_in[5];
  const void* pe_w3 = d_in[6];
  const void* pe_b3 = d_in[7];
  const void* pos_w1= d_in[8];
  const void* pos_b1= d_in[9];
  const void* pos_w2= d_in[10];
  const void* pos_b2= d_in[11];
  const void* ln1   = d_in[12];
  const void* wqkv  = d_in[13];
  const void* bqkv  = d_in[14];
  const void* wo    = d_in[15];
  const void* bo    = d_in[16];
  const void* ln2   = d_in[17];
  const void* wi    = d_in[18];
  const void* bi    = d_in[19];
  const void* wo2   = d_in[20];
  const void* bo2   = d_in[21];
  const void* lnf   = d_in[22];

  const size_t needed_new = (6711296ull + 16) * 4;   // ~26.9 MB
  if (ws_size < needed_new) return;

  float* ws   = (float*)d_ws;
  float* h    = ws;                                   // 786432
  u16*  yhi   = (u16*)(ws + 786432);                  // planes 2048x384
  u16*  ylo   = yhi + 786432;
  float* qkvb = ws + 1572864;                         // 2359296 f32
  u16*  athi  = (u16*)(ws + 3932160);                 // planes 2048x384
  u16*  atlo  = athi + 786432;
  u16*  ubhi  = (u16*)(ws + 1572864);                 // planes 2048x1536 (alias qkvb+attb)
  u16*  ublo  = ubhi + 3145728;
  float* xn   = ws + 1572864;                         // pre-loop alias
  u16*  wthi  = (u16*)(ws + 4718592);                 // 1769472 u16 per plane
  u16*  wtlo  = wthi + 1769472;
  float* patches = ws + 6488064;                      // 196608
  float* centers = ws + 6684672;                      // 24576
  int*   keep    = (int*)(ws + 6709248);              // 2048
  u16*  mfhi  = yhi;            u16* mflo = yhi + 2048*256;   // pre-loop alias
  u16*  phhi  = athi;           u16* phlo = athi + 2048*128;  // pre-loop alias
  int*   flag = (int*)(ws + 6711296);

  k_detect   <<<1, 256, 0, stream>>>((const u16*)pts, flag);
  k_normalize<<<NB, 256, 0, stream>>>(pts, xn, flag);
  k_keep     <<<NB, 256, 0, stream>>>(noise, keep, flag);
  k_fps      <<<NB, 512, 0, stream>>>(xn, centers);
  k_knn      <<<NB*NLK, 256, 0, stream>>>(xn, centers, keep, patches);
  k_embed    <<<NB*NLK, 256, 0, stream>>>(patches, centers, keep,
      pe_w1, pe_b1, pe_w2, pe_b2, pos_w1, pos_b1,
      mfhi, mflo, phhi, phlo, flag);
  k_transpose<<<dim3(12, 8), 256, 0, stream>>>(pe_w3, 0, 256, 384, wthi, wtlo, 0, flag);
  k_transpose<<<dim3(12, 4), 256, 0, stream>>>(pos_w2, 0, 128, 384, wthi, wtlo, 98304, flag);
  k_gemm_mfma<64,64,0,false,false><<<dim3(6,32), 256, 0, stream>>>(
      mfhi, mflo, wthi, wtlo, 0, pe_b3, 0, flag, nullptr, h, nullptr, nullptr, 384, 256);
  k_gemm_mfma<64,64,0,true ,false><<<dim3(6,32), 256, 0, stream>>>(
      phhi, phlo, wthi, wtlo, 98304, pos_b2, 0, flag, h, h, nullptr, nullptr, 384, 128);

  for(int l=0; l<NL; l++){
    k_transpose4<<<1728, 256, 0, stream>>>(wqkv, wo, wi, wo2, l, wthi, wtlo, flag);

    k_ln_split<<<MM, 128, 0, stream>>>(h, ln1, (size_t)l*2*ND, yhi, ylo, flag);
    k_gemm_mfma<64,64,0,false,false><<<dim3(18,32), 256, 0, stream>>>(
        yhi, ylo, wthi, wtlo, 0, bqkv, (size_t)l*1152, flag, nullptr, qkvb, nullptr, nullptr, 1152, 384);
    k_attn_pl<<<NB*NH, 256, 0, stream>>>(qkvb, athi, atlo);
    k_gemm_mfma<64,64,0,true ,false><<<dim3(6,32), 256, 0, stream>>>(
        athi, atlo, wthi, wtlo, 442368, bo, (size_t)l*384, flag, h, h, nullptr, nullptr, 384, 384);
    k_ln_split<<<MM, 128, 0, stream>>>(h, ln2, (size_t)l*2*ND, yhi, ylo, flag);
    k_gemm_mfma<64,64,1,false,true ><<<dim3(24,32), 256, 0, stream>>>(
        yhi, ylo, wthi, wtlo, 589824, bi, (size_t)l*1536, flag, nullptr, nullptr, ubhi, ublo, 1536, 384);
    k_gemm_mfma<64,64,0,true ,false><<<dim3(6,32), 256, 0, stream>>>(
        ubhi, ublo, wthi, wtlo, 1179648, bo2, (size_t)l*384, flag, h, h, nullptr, nullptr, 384, 1536);
  }
  k_ln<true><<<MM, 128, 0, stream>>>(h, lnf, 0, d_out, flag);
}

// Round 9
// 2148.503 us; speedup vs baseline: 2.1055x; 1.0319x over previous
//
#include <hip/hip_runtime.h>

// Problem constants
#define NPTS 8192
#define NB   32
#define NG   256
#define NK   32
#define ND   384
#define NH   6
#define NLK  64
#define NF   1536
#define NHD  64
#define NL   12
#define MM   2048   // NB*NLK token rows

typedef unsigned short u16;
typedef unsigned long long u64;
typedef __attribute__((ext_vector_type(8))) short short8;    // bf16x8 MFMA frag
typedef __attribute__((ext_vector_type(16))) float f32x16;   // 32x32 MFMA acc

__device__ __forceinline__ float bf2f(u16 v){
  unsigned int u = ((unsigned int)v) << 16;
  float f; __builtin_memcpy(&f, &u, 4); return f;
}
__device__ __forceinline__ float ldf(const void* p, size_t i, bool bf){
  if(bf) return bf2f(((const u16*)p)[i]);
  return ((const float*)p)[i];
}
__device__ __forceinline__ u16 f2bf(float f){
  unsigned int x; __builtin_memcpy(&x, &f, 4);
  x += 0x7fffu + ((x >> 16) & 1u);
  return (u16)(x >> 16);
}
// split f32 -> (hi, lo) bf16 planes; hi RNE, lo = RNE(residual)
__device__ __forceinline__ void split2(float v, u16& hi, u16& lo){
  hi = f2bf(v);
  lo = f2bf(v - bf2f(hi));
}

// ---------------------------------------------------------------- dtype detect
__global__ __launch_bounds__(256) void k_detect(const u16* __restrict__ pts,
                                                int* __restrict__ flag){
  __shared__ int bad;
  if(threadIdx.x==0) bad=0;
  __syncthreads();
  int hit=0;
  for(int i=threadIdx.x; i<4096; i+=256){
    unsigned e = (pts[i] >> 7) & 0xFFu;
    if(e >= 0x90u) hit=1;
  }
  if(hit) atomicOr(&bad, 1);
  __syncthreads();
  if(threadIdx.x==0) *flag = bad ? 0 : 1;   // 1 = bf16, 0 = f32
}

// ---------------------------------------------------------------- normalize
__device__ __forceinline__ float blockMax256(float v, float* sb, int tid){
  for(int off=32; off; off>>=1) v = fmaxf(v, __shfl_down(v, off));
  __syncthreads();
  if((tid&63)==0) sb[tid>>6] = v;
  __syncthreads();
  return fmaxf(fmaxf(sb[0],sb[1]), fmaxf(sb[2],sb[3]));
}

__global__ __launch_bounds__(256) void k_normalize(const void* __restrict__ pts,
                                                   float* __restrict__ xn,
                                                   const int* __restrict__ flag){
#pragma clang fp contract(off)
  int b = blockIdx.x, tid = threadIdx.x;
  const bool bf = flag[0] != 0;
  __shared__ float sb[4];
  const size_t base = (size_t)b*NPTS*3;
  float mn0=1e30f,mn1=1e30f,mn2=1e30f, mx0=-1e30f,mx1=-1e30f,mx2=-1e30f;
  for(int n=tid; n<NPTS; n+=256){
    float x0=ldf(pts,base+n*3,bf), x1=ldf(pts,base+n*3+1,bf), x2=ldf(pts,base+n*3+2,bf);
    mn0=fminf(mn0,x0); mx0=fmaxf(mx0,x0);
    mn1=fminf(mn1,x1); mx1=fmaxf(mx1,x1);
    mn2=fminf(mn2,x2); mx2=fmaxf(mx2,x2);
  }
  mx0=blockMax256(mx0,sb,tid); mn0=-blockMax256(-mn0,sb,tid);
  mx1=blockMax256(mx1,sb,tid); mn1=-blockMax256(-mn1,sb,tid);
  mx2=blockMax256(mx2,sb,tid); mn2=-blockMax256(-mn2,sb,tid);
  float c0=0.5f*(mn0+mx0), c1=0.5f*(mn1+mx1), c2=0.5f*(mn2+mx2);
  float mr=0.0f;
  for(int n=tid; n<NPTS; n+=256){
    float d0=ldf(pts,base+n*3,bf)-c0, d1=ldf(pts,base+n*3+1,bf)-c1, d2=ldf(pts,base+n*3+2,bf)-c2;
    float nr = sqrtf((d0*d0 + d1*d1) + d2*d2);
    mr = fmaxf(mr, nr);
  }
  float radius = blockMax256(mr, sb, tid);
  float* XO = xn + base;
  for(int n=tid; n<NPTS; n+=256){
    XO[n*3  ] = (ldf(pts,base+n*3  ,bf)-c0)/radius;
    XO[n*3+1] = (ldf(pts,base+n*3+1,bf)-c1)/radius;
    XO[n*3+2] = (ldf(pts,base+n*3+2,bf)-c2)/radius;
  }
}

// ---------------------------------------------------------------- keep
__global__ __launch_bounds__(256) void k_keep(const void* __restrict__ noise,
                                              int* __restrict__ keep,
                                              const int* __restrict__ flag){
  int b = blockIdx.x, g = threadIdx.x;
  const bool bf = flag[0] != 0;
  __shared__ float nv[NG];
  nv[g] = ldf(noise, (size_t)b*NG+g, bf);
  __syncthreads();
  float v = nv[g]; int r = 0;
  for(int j=0; j<NG; j++){
    float u = nv[j];
    r += (u < v) || (u == v && j < g);
  }
  if(r < NLK) keep[b*NLK + r] = g;
}

// ---------------------------------------------------------------- FPS (R8: DPP reduce + 1 barrier/iter)
__device__ __forceinline__ void kmax_dpp_step(unsigned& hi, unsigned& lo, unsigned oh, unsigned ol){
  bool g = (oh > hi) || (oh == hi && ol > lo);
  hi = g ? oh : hi; lo = g ? ol : lo;
}
#define KMAX_DPP(CTRL) { \
  unsigned oh=(unsigned)__builtin_amdgcn_update_dpp(0,(int)kh,(CTRL),0xf,0xf,true); \
  unsigned ol=(unsigned)__builtin_amdgcn_update_dpp(0,(int)kl,(CTRL),0xf,0xf,true); \
  kmax_dpp_step(kh,kl,oh,ol); }

__global__ __launch_bounds__(512) void k_fps(const float* __restrict__ xn,
                                             float* __restrict__ centers){
#pragma clang fp contract(off)
  int b = blockIdx.x, tid = threadIdx.x;
  int lane = tid & 63;
  const float* X = xn + (size_t)b*NPTS*3;
  __shared__ float xs[NPTS*3];   // 96 KB coord mirror
  __shared__ u64 skey[3];
  __shared__ int sc[NG];
  float px[16],py[16],pz[16],dd[16];
#pragma unroll
  for(int s=0;s<16;s++){
    int n = s*512 + tid;
    px[s]=X[n*3]; py[s]=X[n*3+1]; pz[s]=X[n*3+2];
    dd[s]=1e10f;
  }
  for(int i=tid; i<NPTS*3; i+=512) xs[i] = X[i];
  if(tid==0){ skey[0]=0ull; skey[1]=0ull; skey[2]=0ull; sc[0]=0; }
  __syncthreads();
  float lx = xs[0], ly = xs[1], lz = xs[2];
  for(int i=1;i<NG;i++){
    int c = i % 3;
    float bv=-1.0f; int bs=0;
#pragma unroll
    for(int s=0;s<16;s++){
      float dx=px[s]-lx, dy=py[s]-ly, dz=pz[s]-lz;
      float d=(dx*dx + dy*dy) + dz*dz;
      d = fminf(dd[s], d); dd[s]=d;
      if(d > bv){ bv=d; bs=s; }   // strict >: first index on ties
    }
    int bn = bs*512 + tid;
    unsigned kh; __builtin_memcpy(&kh,&bv,4);
    unsigned kl = (unsigned)(NPTS-1-bn);
    KMAX_DPP(0x111)
    KMAX_DPP(0x112)
    KMAX_DPP(0x114)
    KMAX_DPP(0x118)
    KMAX_DPP(0x142)
    KMAX_DPP(0x143)
    if(lane==63) atomicMax(&skey[c], ((u64)kh<<32) | (u64)kl);
    __syncthreads();
    u64 k64 = skey[c];
    int n = (NPTS-1) - (int)(k64 & 0xFFFFFFFFull);
    n &= (NPTS-1);
    if(tid==0){ sc[i]=n; skey[(i+2)%3]=0ull; }
    lx = xs[n*3]; ly = xs[n*3+1]; lz = xs[n*3+2];
  }
  __syncthreads();
  if(tid < NG){
    int n = sc[tid] & (NPTS-1);
    centers[((size_t)b*NG+tid)*3  ] = xs[n*3];
    centers[((size_t)b*NG+tid)*3+1] = xs[n*3+1];
    centers[((size_t)b*NG+tid)*3+2] = xs[n*3+2];
  }
}

// ---------------------------------------------------------------- kNN select only -> patches
__global__ __launch_bounds__(256) void k_knn(
    const float* __restrict__ xn, const float* __restrict__ centers,
    const int* __restrict__ keep, float* __restrict__ patches)
{
  int blk=blockIdx.x; int b=blk>>6; int j=blk&63; int tid=threadIdx.x;
  __shared__ float sd[NPTS];
  __shared__ int   sel[NK];
  __shared__ float rv[4]; __shared__ int rn[4];
  __shared__ int   sseln;
  int g = keep[b*NLK + j] & (NG-1);
  const float* C = centers + ((size_t)b*NG + g)*3;
  float c0=C[0], c1=C[1], c2=C[2];
  const float* X = xn + (size_t)b*NPTS*3;
  {
#pragma clang fp contract(off)
    float cc = (c0*c0 + c1*c1) + c2*c2;
    for(int n=tid; n<NPTS; n+=256){
      float x0=X[n*3], x1=X[n*3+1], x2=X[n*3+2];
      float xx=(x0*x0 + x1*x1) + x2*x2;
      float dt=(c0*x0 + c1*x1) + c2*x2;
      sd[n] = (cc + xx) - 2.0f*dt;
    }
  }
  __syncthreads();
  float dl[32];
  for(int s=0;s<32;s++) dl[s] = sd[s*256 + tid];
  unsigned int alive = 0xffffffffu;
  for(int r=0; r<NK; r++){
    float bv=1e30f; int bn=0x7fffffff;
    for(int s=0;s<32;s++){
      if(alive & (1u<<s)){
        float v = dl[s];
        if(v < bv){ bv=v; bn=s*256+tid; }
      }
    }
    for(int off=32;off;off>>=1){
      float ov=__shfl_down(bv,off); int on=__shfl_down(bn,off);
      if(ov<bv || (ov==bv && on<bn)){ bv=ov; bn=on; }
    }
    if((tid&63)==0){ rv[tid>>6]=bv; rn[tid>>6]=bn; }
    __syncthreads();
    if(tid==0){
      float v=rv[0]; int n=rn[0];
      for(int w=1;w<4;w++) if(rv[w]<v || (rv[w]==v && rn[w]<n)){ v=rv[w]; n=rn[w]; }
      n &= (NPTS-1);
      sseln=n; sel[r]=n;
    }
    __syncthreads();
    int n = sseln;
    if((n & 255) == tid) alive &= ~(1u << (n >> 8));
  }
  __syncthreads();
  if(tid < NK){
    int n = sel[tid] & (NPTS-1);
    float* P = patches + ((size_t)(b*NLK+j)*NK + tid)*3;
    P[0]=X[n*3  ]-c0;
    P[1]=X[n*3+1]-c1;
    P[2]=X[n*3+2]-c2;
  }
}

// ---------------------------------------------------------------- embed: f1,f2,maxpool + pos hidden -> bf16 planes
__global__ __launch_bounds__(256) void k_embed(
    const float* __restrict__ patches, const float* __restrict__ centers,
    const int* __restrict__ keep,
    const void* __restrict__ w1, const void* __restrict__ b1,
    const void* __restrict__ w2, const void* __restrict__ b2,
    const void* __restrict__ pw1, const void* __restrict__ pb1,
    u16* __restrict__ mfhi, u16* __restrict__ mflo,
    u16* __restrict__ phhi, u16* __restrict__ phlo,
    const int* __restrict__ flag)
{
  int blk=blockIdx.x; int b=blk>>6; int j=blk&63; int tid=threadIdx.x;
  const bool bf = flag[0] != 0;
  __shared__ float pat[NK*3];
  __shared__ __align__(16) float f1t[128*36];   // [jj][k], pitch 36
  int row = b*NLK + j;
  if(tid < NK*3) pat[tid] = patches[(size_t)row*NK*3 + tid];
  __syncthreads();
  for(int i=0;i<16;i++){
    int idx = tid + i*256;
    int k = idx>>7, m = idx&127;
    float v = ldf(b1,m,bf)
            + pat[k*3+0]*ldf(w1,        m,bf)
            + pat[k*3+1]*ldf(w1, 128 + m,bf)
            + pat[k*3+2]*ldf(w1, 256 + m,bf);
    f1t[m*36 + k] = fmaxf(v, 0.0f);
  }
  __syncthreads();
  float acc[NK];
  {
    float bv = ldf(b2, tid, bf);
#pragma unroll
    for(int k=0;k<NK;k++) acc[k]=bv;
  }
  for(int jj=0;jj<128;jj++){
    float wv = ldf(w2, (size_t)jj*256+tid, bf);
    const float* fr = &f1t[jj*36];
#pragma unroll
    for(int k8=0;k8<8;k8++){
      float4 fv = *reinterpret_cast<const float4*>(fr + k8*4);
      acc[k8*4+0] = fmaf(fv.x, wv, acc[k8*4+0]);
      acc[k8*4+1] = fmaf(fv.y, wv, acc[k8*4+1]);
      acc[k8*4+2] = fmaf(fv.z, wv, acc[k8*4+2]);
      acc[k8*4+3] = fmaf(fv.w, wv, acc[k8*4+3]);
    }
  }
  float mx = acc[0];
#pragma unroll
  for(int k=1;k<NK;k++) mx = fmaxf(mx, acc[k]);
  { u16 hi,lo; split2(mx,hi,lo);
    mfhi[(size_t)row*256 + tid]=hi; mflo[(size_t)row*256 + tid]=lo; }
  if(tid < 128){
    int g = keep[b*NLK + j] & (NG-1);
    const float* C = centers + ((size_t)b*NG + g)*3;
    float v = ldf(pb1,tid,bf)
            + C[0]*ldf(pw1,        tid,bf)
            + C[1]*ldf(pw1, 128 + tid,bf)
            + C[2]*ldf(pw1, 256 + tid,bf);
    v = fmaxf(v, 0.0f);
    u16 hi,lo; split2(v,hi,lo);
    phhi[(size_t)row*128 + tid]=hi; phlo[(size_t)row*128 + tid]=lo;
  }
}

// ---------------------------------------------------------------- weight transpose: [K][N] -> [N][K] hi/lo bf16 planes
__global__ __launch_bounds__(256) void k_transpose(const void* __restrict__ W, size_t woff,
    int Kd, int Nd, u16* __restrict__ dhi, u16* __restrict__ dlo, size_t doff,
    const int* __restrict__ flag){
  __shared__ float t[32][33];
  const bool bf = flag[0]!=0;
  int n0 = blockIdx.x*32, k0 = blockIdx.y*32;
  for(int i=0;i<4;i++){
    int idx = threadIdx.x + i*256; int kr = idx>>5, nc = idx&31;
    t[kr][nc] = ldf(W, woff + (size_t)(k0+kr)*Nd + n0+nc, bf);
  }
  __syncthreads();
  for(int i=0;i<4;i++){
    int idx = threadIdx.x + i*256; int nr = idx>>5, kc = idx&31;
    float v = t[kc][nr];
    u16 hi,lo; split2(v,hi,lo);
    size_t o = doff + (size_t)(n0+nr)*Kd + k0+kc;
    dhi[o]=hi; dlo[o]=lo;
  }
}

// ---------------------------------------------------------------- batched per-layer transpose: wqkv|wo|wi|wo2 in one launch
__global__ __launch_bounds__(256) void k_transpose4(
    const void* __restrict__ wqkv, const void* __restrict__ wo,
    const void* __restrict__ wi,   const void* __restrict__ wo2,
    int l, u16* __restrict__ dhi, u16* __restrict__ dlo,
    const int* __restrict__ flag){
  __shared__ float t[32][33];
  const bool bf = flag[0]!=0;
  int id = blockIdx.x;
  const void* W; int Kd, Nd; size_t woff, doff; int local;
  if(id < 432){        W=wqkv; Kd=384;  Nd=1152; woff=(size_t)l*442368; doff=0;       local=id; }
  else if(id < 576){   W=wo;   Kd=384;  Nd=384;  woff=(size_t)l*147456; doff=442368;  local=id-432; }
  else if(id < 1152){  W=wi;   Kd=384;  Nd=1536; woff=(size_t)l*589824; doff=589824;  local=id-576; }
  else {               W=wo2;  Kd=1536; Nd=384;  woff=(size_t)l*589824; doff=1179648; local=id-1152; }
  int ntiles = Nd >> 5;
  int n0 = (local % ntiles)*32, k0 = (local / ntiles)*32;
  for(int i=0;i<4;i++){
    int idx = threadIdx.x + i*256; int kr = idx>>5, nc = idx&31;
    t[kr][nc] = ldf(W, woff + (size_t)(k0+kr)*Nd + n0+nc, bf);
  }
  __syncthreads();
  for(int i=0;i<4;i++){
    int idx = threadIdx.x + i*256; int nr = idx>>5, kc = idx&31;
    float v = t[kc][nr];
    u16 hi,lo; split2(v,hi,lo);
    size_t o = doff + (size_t)(n0+nr)*Kd + k0+kc;
    dhi[o]=hi; dlo[o]=lo;
  }
}

// ---------------------------------------------------------------- LayerNorm -> bf16 hi/lo planes
__global__ __launch_bounds__(128) void k_ln_split(const float* __restrict__ X,
                                                  const void* __restrict__ gb, size_t go,
                                                  u16* __restrict__ Yhi, u16* __restrict__ Ylo,
                                                  const int* __restrict__ flag){
  int row=blockIdx.x, tid=threadIdx.x;
  const bool bf = flag[0] != 0;
  const float* x = X + (size_t)row*ND;
  __shared__ float sbuf[2];
  float v0=x[tid], v1=x[tid+128], v2=x[tid+256];
  float s = v0+v1+v2;
  for(int off=32;off;off>>=1) s += __shfl_down(s,off);
  if((tid&63)==0) sbuf[tid>>6]=s;
  __syncthreads();
  float mean = (sbuf[0]+sbuf[1]) * (1.0f/(float)ND);
  __syncthreads();
  float d0=v0-mean, d1=v1-mean, d2=v2-mean;
  s = d0*d0 + d1*d1 + d2*d2;
  for(int off=32;off;off>>=1) s += __shfl_down(s,off);
  if((tid&63)==0) sbuf[tid>>6]=s;
  __syncthreads();
  float var = (sbuf[0]+sbuf[1]) * (1.0f/(float)ND);
  float rstd = 1.0f / sqrtf(var + 1e-5f);
  float o0 = d0*rstd*ldf(gb,go+tid    ,bf) + ldf(gb,go+ND+tid    ,bf);
  float o1 = d1*rstd*ldf(gb,go+tid+128,bf) + ldf(gb,go+ND+tid+128,bf);
  float o2 = d2*rstd*ldf(gb,go+tid+256,bf) + ldf(gb,go+ND+tid+256,bf);
  u16 hi,lo; size_t rb = (size_t)row*ND;
  split2(o0,hi,lo); Yhi[rb+tid    ]=hi; Ylo[rb+tid    ]=lo;
  split2(o1,hi,lo); Yhi[rb+tid+128]=hi; Ylo[rb+tid+128]=lo;
  split2(o2,hi,lo); Yhi[rb+tid+256]=hi; Ylo[rb+tid+256]=lo;
}

// ---------------------------------------------------------------- MFMA GEMM, bf16x3 split precision, 32x32x16
// A planes MxK; W planes [N][K] at element offset wo. 64x64 block tile, 4 waves
// each computing one 32x32 via v_mfma_f32_32x32x16_bf16 (2 k-steps per K0=32).
// Frag layouts: A/B lane=m|n (lane&31), k=(lane>>5)*8+j; C/D col=lane&31,
// row=(reg&3)+8*(reg>>2)+4*(lane>>5)  [guide §3, m74/m101 verified].
template<int TM, int TN, int ACT, bool RES, bool OSPLIT>
__global__ __launch_bounds__(256) void k_gemm_mfma(
    const u16* __restrict__ Ahi, const u16* __restrict__ Alo,
    const u16* __restrict__ Whi, const u16* __restrict__ Wlo, size_t wo,
    const void* __restrict__ bias, size_t bo, const int* __restrict__ flag,
    const float* __restrict__ res, float* __restrict__ Cf,
    u16* __restrict__ Ohi, u16* __restrict__ Olo,
    int N, int K)
{
  __shared__ __align__(16) u16 sAh[TM*40];
  __shared__ __align__(16) u16 sAl[TM*40];
  __shared__ __align__(16) u16 sBh[TN*40];
  __shared__ __align__(16) u16 sBl[TN*40];
  int tid = threadIdx.x;
  int wave = tid >> 6, lane = tid & 63;
  int wm = wave >> 1, wn = wave & 1;
  int l31 = lane & 31, half = lane >> 5;
  int row0 = blockIdx.y*TM, col0 = blockIdx.x*TN;
  const bool bf = flag[0] != 0;
  f32x16 acc;
#pragma unroll
  for(int r=0;r<16;r++) acc[r]=0.f;

  for(int k0=0; k0<K; k0+=32){
#pragma unroll
    for(int i=0;i<TM/32;i++){
      int idx = tid + i*256; int r = idx>>3, c = (idx&7)*4;
      size_t ga = (size_t)(row0+r)*K + k0 + c;
      *reinterpret_cast<uint2*>(&sAh[r*40+c]) = *reinterpret_cast<const uint2*>(&Ahi[ga]);
      *reinterpret_cast<uint2*>(&sAl[r*40+c]) = *reinterpret_cast<const uint2*>(&Alo[ga]);
    }
#pragma unroll
    for(int i=0;i<TN/32;i++){
      int idx = tid + i*256; int r = idx>>3, c = (idx&7)*4;
      size_t ga = wo + (size_t)(col0+r)*K + k0 + c;
      *reinterpret_cast<uint2*>(&sBh[r*40+c]) = *reinterpret_cast<const uint2*>(&Whi[ga]);
      *reinterpret_cast<uint2*>(&sBl[r*40+c]) = *reinterpret_cast<const uint2*>(&Wlo[ga]);
    }
    __syncthreads();
#pragma unroll
    for(int ks=0; ks<2; ks++){
      int aoff = (wm*32 + l31)*40 + ks*16 + half*8;
      int boff = (wn*32 + l31)*40 + ks*16 + half*8;
      short8 ah = *reinterpret_cast<const short8*>(&sAh[aoff]);
      short8 al = *reinterpret_cast<const short8*>(&sAl[aoff]);
      short8 bh = *reinterpret_cast<const short8*>(&sBh[boff]);
      short8 bl = *reinterpret_cast<const short8*>(&sBl[boff]);
      acc = __builtin_amdgcn_mfma_f32_32x32x16_bf16(ah, bh, acc, 0,0,0);
      acc = __builtin_amdgcn_mfma_f32_32x32x16_bf16(ah, bl, acc, 0,0,0);
      acc = __builtin_amdgcn_mfma_f32_32x32x16_bf16(al, bh, acc, 0,0,0);
    }
    __syncthreads();
  }
  int col = col0 + wn*32 + l31;
  float bv = ldf(bias, bo+col, bf);
#pragma unroll
  for(int r=0;r<16;r++){
    int row = row0 + wm*32 + (r&3) + 8*(r>>2) + 4*half;
    float v = acc[r] + bv;
    if(ACT==1){
      float xx = v;
      v = 0.5f*xx*(1.0f + tanhf(0.7978845608028654f*(xx + 0.044715f*xx*xx*xx)));
    }
    if(RES) v += res[(size_t)row*N + col];
    if(OSPLIT){
      u16 hi,lo; split2(v,hi,lo);
      Ohi[(size_t)row*N + col]=hi; Olo[(size_t)row*N + col]=lo;
    }else{
      Cf[(size_t)row*N + col]=v;
    }
  }
}

// ---------------------------------------------------------------- attention (f32 math) -> bf16 planes
__global__ __launch_bounds__(256) void k_attn_pl(const float* __restrict__ qkv,
                                                 u16* __restrict__ ohi,
                                                 u16* __restrict__ olo){
  __shared__ float Q[64*65];
  __shared__ float Kb[64*65];
  __shared__ float V[64*65];
  int blk=blockIdx.x; int b=blk/NH, h=blk%NH;
  int tid=threadIdx.x;
  for(int idx=tid; idx<4096; idx+=256){
    int s=idx>>6, d=idx&63;
    const float* r = qkv + ((size_t)(b*NLK+s))*1152 + h*NHD + d;
    Q [s*65+d]=r[0];
    Kb[s*65+d]=r[384];
    V [s*65+d]=r[768];
  }
  __syncthreads();
  float sc[16];
  for(int t=0;t<16;t++){
    int idx=t*256+tid; int i=idx>>6, jj=idx&63;
    float acc=0.0f;
    for(int d=0;d<64;d++) acc = fmaf(Q[i*65+d], Kb[jj*65+d], acc);
    sc[t]=acc*0.125f;
  }
  __syncthreads();
  for(int t=0;t<16;t++){
    int idx=t*256+tid; int i=idx>>6, jj=idx&63;
    Q[i*65+jj]=sc[t];
  }
  __syncthreads();
  if(tid<64){
    float* rowp=&Q[tid*65];
    float m=rowp[0];
    for(int j=1;j<64;j++) m=fmaxf(m,rowp[j]);
    float sum=0.0f;
    for(int j=0;j<64;j++){ float e=__expf(rowp[j]-m); rowp[j]=e; sum+=e; }
    for(int j=0;j<64;j++) rowp[j]/=sum;
  }
  __syncthreads();
  for(int idx=tid; idx<4096; idx+=256){
    int s=idx>>6, d=idx&63;
    float acc=0.0f;
    for(int t=0;t<64;t++) acc=fmaf(Q[s*65+t], V[t*65+d], acc);
    size_t o = ((size_t)(b*NLK+s))*ND + h*NHD + d;
    u16 hi,lo; split2(acc,hi,lo);
    ohi[o]=hi; olo[o]=lo;
  }
}

// ---------------------------------------------------------------- final LayerNorm (output)
template<bool FINAL>
__global__ __launch_bounds__(128) void k_ln(const float* __restrict__ X,
                                            const void* __restrict__ gb, size_t go,
                                            void* __restrict__ Y,
                                            const int* __restrict__ flag){
  int row=blockIdx.x, tid=threadIdx.x;
  const bool bf = flag[0] != 0;
  const float* x = X + (size_t)row*ND;
  __shared__ float sbuf[2];
  float v0=x[tid], v1=x[tid+128], v2=x[tid+256];
  float s = v0+v1+v2;
  for(int off=32;off;off>>=1) s += __shfl_down(s,off);
  if((tid&63)==0) sbuf[tid>>6]=s;
  __syncthreads();
  float mean = (sbuf[0]+sbuf[1]) * (1.0f/(float)ND);
  __syncthreads();
  float d0=v0-mean, d1=v1-mean, d2=v2-mean;
  s = d0*d0 + d1*d1 + d2*d2;
  for(int off=32;off;off>>=1) s += __shfl_down(s,off);
  if((tid&63)==0) sbuf[tid>>6]=s;
  __syncthreads();
  float var = (sbuf[0]+sbuf[1]) * (1.0f/(float)ND);
  float rstd = 1.0f / sqrtf(var + 1e-5f);
  float o0 = d0*rstd*ldf(gb,go+tid    ,bf) + ldf(gb,go+ND+tid    ,bf);
  float o1 = d1*rstd*ldf(gb,go+tid+128,bf) + ldf(gb,go+ND+tid+128,bf);
  float o2 = d2*rstd*ldf(gb,go+tid+256,bf) + ldf(gb,go+ND+tid+256,bf);
  if(FINAL && bf){
    u16* yo = (u16*)Y + (size_t)row*ND;
    yo[tid]=f2bf(o0); yo[tid+128]=f2bf(o1); yo[tid+256]=f2bf(o2);
  }else{
    float* yo = (float*)Y + (size_t)row*ND;
    yo[tid]=o0; yo[tid+128]=o1; yo[tid+256]=o2;
  }
}

// ---------------------------------------------------------------- host
extern "C" void kernel_launch(void* const* d_in, const int* in_sizes, int n_in,
                              void* d_out, int out_size, void* d_ws, size_t ws_size,
                              hipStream_t stream){
  (void)in_sizes; (void)n_in; (void)out_size;
  const void* pts   = d_in[0];
  const void* noise = d_in[1];
  const void* pe_w1 = d_in[2];
  const void* pe_b1 = d_in[3];
  const void* pe_w2 = d_in[4];
  const void* pe_b2 = d_in[5];
  const void* pe_w3 = d_in[6];
  const void* pe_b3 = d_in[7];
  const void* pos_w1= d_in[8];
  const void* pos_b1= d_in[9];
  const void* pos_w2= d_in[10];
  const void* pos_b2= d_in[11];
  const void* ln1   = d_in[12];
  const void* wqkv  = d_in[13];
  const void* bqkv  = d_in[14];
  const void* wo    = d_in[15];
  const void* bo    = d_in[16];
  const void* ln2   = d_in[17];
  const void* wi    = d_in[18];
  const void* bi    = d_in[19];
  const void* wo2   = d_in[20];
  const void* bo2   = d_in[21];
  const void* lnf   = d_in[22];

  const size_t needed_new = (6711296ull + 16) * 4;   // ~26.9 MB
  if (ws_size < needed_new) return;

  float* ws   = (float*)d_ws;
  float* h    = ws;                                   // 786432
  u16*  yhi   = (u16*)(ws + 786432);                  // planes 2048x384
  u16*  ylo   = yhi + 786432;
  float* qkvb = ws + 1572864;                         // 2359296 f32
  u16*  athi  = (u16*)(ws + 3932160);                 // planes 2048x384
  u16*  atlo  = athi + 786432;
  u16*  ubhi  = (u16*)(ws + 1572864);                 // planes 2048x1536 (alias qkvb+attb)
  u16*  ublo  = ubhi + 3145728;
  float* xn   = ws + 1572864;                         // pre-loop alias
  u16*  wthi  = (u16*)(ws + 4718592);                 // 1769472 u16 per plane
  u16*  wtlo  = wthi + 1769472;
  float* patches = ws + 6488064;                      // 196608
  float* centers = ws + 6684672;                      // 24576
  int*   keep    = (int*)(ws + 6709248);              // 2048
  u16*  mfhi  = yhi;            u16* mflo = yhi + 2048*256;   // pre-loop alias
  u16*  phhi  = athi;           u16* phlo = athi + 2048*128;  // pre-loop alias
  int*   flag = (int*)(ws + 6711296);

  k_detect   <<<1, 256, 0, stream>>>((const u16*)pts, flag);
  k_normalize<<<NB, 256, 0, stream>>>(pts, xn, flag);
  k_keep     <<<NB, 256, 0, stream>>>(noise, keep, flag);
  k_fps      <<<NB, 512, 0, stream>>>(xn, centers);
  k_knn      <<<NB*NLK, 256, 0, stream>>>(xn, centers, keep, patches);
  k_embed    <<<NB*NLK, 256, 0, stream>>>(patches, centers, keep,
      pe_w1, pe_b1, pe_w2, pe_b2, pos_w1, pos_b1,
      mfhi, mflo, phhi, phlo, flag);
  k_transpose<<<dim3(12, 8), 256, 0, stream>>>(pe_w3, 0, 256, 384, wthi, wtlo, 0, flag);
  k_transpose<<<dim3(12, 4), 256, 0, stream>>>(pos_w2, 0, 128, 384, wthi, wtlo, 98304, flag);
  k_gemm_mfma<64,64,0,false,false><<<dim3(6,32), 256, 0, stream>>>(
      mfhi, mflo, wthi, wtlo, 0, pe_b3, 0, flag, nullptr, h, nullptr, nullptr, 384, 256);
  k_gemm_mfma<64,64,0,true ,false><<<dim3(6,32), 256, 0, stream>>>(
      phhi, phlo, wthi, wtlo, 98304, pos_b2, 0, flag, h, h, nullptr, nullptr, 384, 128);

  for(int l=0; l<NL; l++){
    k_transpose4<<<1728, 256, 0, stream>>>(wqkv, wo, wi, wo2, l, wthi, wtlo, flag);

    k_ln_split<<<MM, 128, 0, stream>>>(h, ln1, (size_t)l*2*ND, yhi, ylo, flag);
    k_gemm_mfma<64,64,0,false,false><<<dim3(18,32), 256, 0, stream>>>(
        yhi, ylo, wthi, wtlo, 0, bqkv, (size_t)l*1152, flag, nullptr, qkvb, nullptr, nullptr, 1152, 384);
    k_attn_pl<<<NB*NH, 256, 0, stream>>>(qkvb, athi, atlo);
    k_gemm_mfma<64,64,0,true ,false><<<dim3(6,32), 256, 0, stream>>>(
        athi, atlo, wthi, wtlo, 442368, bo, (size_t)l*384, flag, h, h, nullptr, nullptr, 384, 384);
    k_ln_split<<<MM, 128, 0, stream>>>(h, ln2, (size_t)l*2*ND, yhi, ylo, flag);
    k_gemm_mfma<64,64,1,false,true ><<<dim3(24,32), 256, 0, stream>>>(
        yhi, ylo, wthi, wtlo, 589824, bi, (size_t)l*1536, flag, nullptr, nullptr, ubhi, ublo, 1536, 384);
    k_gemm_mfma<64,64,0,true ,false><<<dim3(6,32), 256, 0, stream>>>(
        ubhi, ublo, wthi, wtlo, 1179648, bo2, (size_t)l*384, flag, h, h, nullptr, nullptr, 384, 1536);
  }
  k_ln<true><<<MM, 128, 0, stream>>>(h, lnf, 0, d_out, flag);
}